// Round 1
// baseline (1578.142 us; speedup 1.0000x reference)
//
#include <hip/hip_runtime.h>
#include <cstdint>

typedef unsigned short ushort_t;
typedef __bf16 bf16x8 __attribute__((ext_vector_type(8)));
typedef float f32x4 __attribute__((ext_vector_type(4)));

// ---------- helpers ----------
__device__ __forceinline__ ushort_t f2bf(float f) {
  union { float f; unsigned int u; } v; v.f = f;
  unsigned int u = v.u;
  unsigned int r = (u + 0x7fffu + ((u >> 16) & 1u)) >> 16;
  return (ushort_t)r;
}
__device__ __forceinline__ float bf2f(ushort_t u) {
  union { unsigned int u; float f; } v; v.u = ((unsigned int)u) << 16; return v.f;
}

// CK-style addrspace plumbing for global_load_lds (direct global->LDS, 16B/lane)
#define GLOAD16(gp, lp)                                                              \
  __builtin_amdgcn_global_load_lds(                                                  \
      reinterpret_cast<const __attribute__((address_space(1))) unsigned int*>(       \
          reinterpret_cast<uintptr_t>(gp)),                                          \
      reinterpret_cast<__attribute__((address_space(3))) unsigned int*>(             \
          reinterpret_cast<uintptr_t>(lp)),                                          \
      16, 0, 0)

// ---------- GEMM: C[M,N] = A[M,K] @ B[N,K]^T, bf16 in, f32 acc ----------
// m97 structure: 128x128 tile, BK=32, 4 waves (2x2), 4x4 16x16x32 MFMA frags/wave.
// EPI: 0 = outf = acc + bias(optional)          (H3, logits, G4, X3, out)
//      1 = outf = acc + bias; outb = bf16(relu(outf)^2)   (H1 + H2b)
//      2 = outb = bf16(acc * 2*sqrt(auxb))      (g1 from dh2, auxb=H2b)
//      3 = outb = (col<row) ? bf16(acc) : 0; skip upper tiles  (S1, S2)
//      4 = outb = bf16(relu(auxf - ss0*acc)^2); K-limit       (x2)
//      5 = outf = auxf - ss2*acc; K-limit                     (x3)
struct GemmP {
  const ushort_t* A; const ushort_t* B;
  int M, N, K;
  long long sA, sB;            // batch strides (elements)
  float* outf;   long long sOutF;
  ushort_t* outb; long long sOutB;
  const float* bias;
  const float* auxf; long long sAuxF;
  const ushort_t* auxb;
  const float* steps;
};

template <int EPI>
__global__ __launch_bounds__(256) void gemm_bt(GemmP p) {
  const int nt = blockIdx.x, mt = blockIdx.y, bz = blockIdx.z;
  const int m0 = mt * 128, n0 = nt * 128;
  if (EPI == 3 && n0 > m0) return;  // strictly-upper tiles of S are never read

  const ushort_t* A = p.A + (size_t)bz * p.sA;
  const ushort_t* B = p.B + (size_t)bz * p.sB;

  int kend = p.K;
  if (EPI == 4 || EPI == 5) kend = min(p.K, m0 + 128);  // S cols >= m0+128 are zero

  __shared__ ushort_t sA[128 * 32];
  __shared__ ushort_t sB[128 * 32];

  const int tid = threadIdx.x;
  const int wid = tid >> 6, lane = tid & 63;
  const int wm = wid >> 1, wn = wid & 1;

  f32x4 acc[4][4];
#pragma unroll
  for (int i = 0; i < 4; i++)
#pragma unroll
    for (int j = 0; j < 4; j++) acc[i][j] = f32x4{0.f, 0.f, 0.f, 0.f};

  // staging: tile = 8KB = 8 chunks of 1KB (64 lanes x 16B). chunk c rows [c*16,c*16+16)
  const int lr = lane >> 2;            // row within chunk
  const int lc = (lane & 3) * 8;       // col (bf16 elems)
  const int rA0 = wid * 16 + lr;
  const int rA1 = 64 + wid * 16 + lr;
  const ushort_t* gA0 = A + (size_t)(m0 + rA0) * p.K + lc;
  const ushort_t* gA1 = A + (size_t)(m0 + rA1) * p.K + lc;
  const ushort_t* gB0 = B + (size_t)(n0 + rA0) * p.K + lc;
  const ushort_t* gB1 = B + (size_t)(n0 + rA1) * p.K + lc;
  ushort_t* lA0 = &sA[wid * 512];      // wave-uniform LDS bases
  ushort_t* lA1 = &sA[(4 + wid) * 512];
  ushort_t* lB0 = &sB[wid * 512];
  ushort_t* lB1 = &sB[(4 + wid) * 512];

  const int fr = lane & 15;
  const int kb = (lane >> 4) * 8;

  for (int k = 0; k < kend; k += 32) {
    GLOAD16(gA0 + k, lA0);
    GLOAD16(gA1 + k, lA1);
    GLOAD16(gB0 + k, lB0);
    GLOAD16(gB1 + k, lB1);
    __syncthreads();  // compiler inserts vmcnt(0) drain before barrier
    bf16x8 av[4], bv[4];
#pragma unroll
    for (int i = 0; i < 4; i++) {
      av[i] = *reinterpret_cast<const bf16x8*>(&sA[(wm * 64 + i * 16 + fr) * 32 + kb]);
      bv[i] = *reinterpret_cast<const bf16x8*>(&sB[(wn * 64 + i * 16 + fr) * 32 + kb]);
    }
#pragma unroll
    for (int i = 0; i < 4; i++)
#pragma unroll
      for (int j = 0; j < 4; j++)
        acc[i][j] = __builtin_amdgcn_mfma_f32_16x16x32_bf16(av[i], bv[j], acc[i][j], 0, 0, 0);
    __syncthreads();
  }

  // epilogue; C/D layout (verified m89): col = lane&15, row = (lane>>4)*4 + reg
  const int fq = lane >> 4;
  float ss = 0.f;
  if (EPI == 4) ss = p.steps[0];
  else if (EPI == 5) ss = p.steps[2];
  float* outf = p.outf ? p.outf + (size_t)bz * p.sOutF : nullptr;
  ushort_t* outb = p.outb ? p.outb + (size_t)bz * p.sOutB : nullptr;
  const float* auxf = p.auxf ? p.auxf + (size_t)bz * p.sAuxF : nullptr;

#pragma unroll
  for (int i = 0; i < 4; i++) {
#pragma unroll
    for (int j = 0; j < 4; j++) {
#pragma unroll
      for (int r = 0; r < 4; r++) {
        int row = m0 + wm * 64 + i * 16 + fq * 4 + r;
        int col = n0 + wn * 64 + j * 16 + fr;
        size_t g = (size_t)row * p.N + col;
        float v = acc[i][j][r];
        if (EPI == 0) {
          outf[g] = v + (p.bias ? p.bias[col] : 0.f);
        } else if (EPI == 1) {
          v += p.bias[col];
          outf[g] = v;
          float rl = fmaxf(v, 0.f);
          outb[g] = f2bf(rl * rl);
        } else if (EPI == 2) {
          outb[g] = f2bf(v * 2.f * sqrtf(bf2f(p.auxb[g])));
        } else if (EPI == 3) {
          outb[g] = (col < row) ? f2bf(v) : (ushort_t)0;
        } else if (EPI == 4) {
          float x1 = auxf[g] - ss * v;
          float rl = fmaxf(x1, 0.f);
          outb[g] = f2bf(rl * rl);
        } else if (EPI == 5) {
          outf[g] = auxf[g] - ss * v;
        }
      }
    }
  }
}

// ---------- auxiliary kernels ----------
__global__ __launch_bounds__(256) void k_conv(const float* in, ushort_t* out, size_t n) {
  size_t i = ((size_t)blockIdx.x * 256 + threadIdx.x) * 4;
  if (i >= n) return;
  float4 v = *(const float4*)(in + i);
  out[i] = f2bf(v.x); out[i + 1] = f2bf(v.y); out[i + 2] = f2bf(v.z); out[i + 3] = f2bf(v.w);
}

// out[C][R] = bf16(in[R][C]) transposed
__global__ __launch_bounds__(256) void k_tconv(const float* in, ushort_t* out, int R, int C) {
  __shared__ float t[32][33];
  int c0 = blockIdx.x * 32, r0 = blockIdx.y * 32;
  int tx = threadIdx.x & 31, ty = threadIdx.x >> 5;
#pragma unroll
  for (int i = ty; i < 32; i += 8) t[i][tx] = in[(size_t)(r0 + i) * C + c0 + tx];
  __syncthreads();
#pragma unroll
  for (int i = ty; i < 32; i += 8) out[(size_t)(c0 + i) * R + r0 + tx] = f2bf(t[tx][i]);
}

// batched bf16 transpose: per z, in (L,C) -> out (C,L)
__global__ __launch_bounds__(256) void k_tb2b(const ushort_t* in, ushort_t* out, int L, int C) {
  __shared__ ushort_t t[32][33];
  int b = blockIdx.z;
  const ushort_t* ib = in + (size_t)b * L * C;
  ushort_t* ob = out + (size_t)b * C * L;
  int c0 = blockIdx.x * 32, l0 = blockIdx.y * 32;
  int tx = threadIdx.x & 31, ty = threadIdx.x >> 5;
#pragma unroll
  for (int i = ty; i < 32; i += 8) t[i][tx] = ib[(size_t)(l0 + i) * C + c0 + tx];
  __syncthreads();
#pragma unroll
  for (int i = ty; i < 32; i += 8) ob[(size_t)(c0 + i) * L + l0 + tx] = t[tx][i];
}

__device__ __forceinline__ void blockRed2(float& a, float& b, float* red) {
#pragma unroll
  for (int o = 32; o; o >>= 1) { a += __shfl_down(a, o); b += __shfl_down(b, o); }
  int w = threadIdx.x >> 6;
  if ((threadIdx.x & 63) == 0) { red[w] = a; red[4 + w] = b; }
  __syncthreads();
  a = red[0] + red[1] + red[2] + red[3];
  b = red[4] + red[5] + red[6] + red[7];
  __syncthreads();
}

// LN forward: n, rstd, h4b = bf16(n*scale+bias)
__global__ __launch_bounds__(256) void k_lnfwd(const float* X, const float* sc, const float* bi,
                                               float* nout, float* rstd, ushort_t* yb, int D) {
  __shared__ float red[8];
  int row = blockIdx.x;
  const float* x = X + (size_t)row * D;
  float s = 0.f, s2 = 0.f;
  for (int d = threadIdx.x; d < D; d += 256) { float v = x[d]; s += v; s2 += v * v; }
  blockRed2(s, s2, red);
  float mu = s / D;
  float var = s2 / D - mu * mu;
  float rs = rsqrtf(var + 1e-6f);
  for (int d = threadIdx.x; d < D; d += 256) {
    float nv = (x[d] - mu) * rs;
    nout[(size_t)row * D + d] = nv;
    yb[(size_t)row * D + d] = f2bf(nv * sc[d] + bi[d]);
  }
  if (threadIdx.x == 0) rstd[row] = rs;
}

// LN forward with per-token scale/bias rows (fast path): x4b
__global__ __launch_bounds__(256) void k_lnfwd2(const float* X, const float* fs, const float* fb,
                                                ushort_t* yb, int D) {
  __shared__ float red[8];
  int row = blockIdx.x;
  const float* x = X + (size_t)row * D;
  float s = 0.f, s2 = 0.f;
  for (int d = threadIdx.x; d < D; d += 256) { float v = x[d]; s += v; s2 += v * v; }
  blockRed2(s, s2, red);
  float mu = s / D;
  float var = s2 / D - mu * mu;
  float rs = rsqrtf(var + 1e-6f);
  for (int d = threadIdx.x; d < D; d += 256) {
    size_t g = (size_t)row * D + d;
    float nv = (x[d] - mu) * rs;
    yb[g] = f2bf(nv * fs[g] + fb[g]);
  }
}

// LN backward: g3b = bf16(rstd*(dn - mean(dn) - n*mean(dn*n))), gsc = G4*n
__global__ __launch_bounds__(256) void k_lnbwd(const float* G, const float* nn, const float* rstd,
                                               const float* sc, ushort_t* g3b, float* gsc, int D) {
  __shared__ float red[8];
  int row = blockIdx.x;
  const float* g = G + (size_t)row * D;
  const float* n_ = nn + (size_t)row * D;
  float sa = 0.f, sb = 0.f;
  for (int d = threadIdx.x; d < D; d += 256) {
    float dn = g[d] * sc[d];
    sa += dn; sb += dn * n_[d];
  }
  blockRed2(sa, sb, red);
  float a = sa / D, b = sb / D, rs = rstd[row];
  for (int d = threadIdx.x; d < D; d += 256) {
    size_t gi = (size_t)row * D + d;
    float dn = g[d] * sc[d];
    g3b[gi] = f2bf(rs * (dn - a - n_[d] * b));
    gsc[gi] = g[d] * n_[d];
  }
}

__global__ __launch_bounds__(256) void k_wsum(const float* w, float* o, int n) {
  __shared__ float red[4];
  float s = 0.f;
  for (int i = threadIdx.x; i < n; i += 256) s += w[i];
#pragma unroll
  for (int d = 32; d; d >>= 1) s += __shfl_down(s, d);
  if ((threadIdx.x & 63) == 0) red[threadIdx.x >> 6] = s;
  __syncthreads();
  if (threadIdx.x == 0) o[0] = fmaxf(red[0] + red[1] + red[2] + red[3], 1e-8f);
}

// per-row: max(logits), sum exp(logits-max), sum labels
__global__ __launch_bounds__(256) void k_rowstats(const float* logits, const float* labels,
                                                  float* rowm, float* rows, float* rowt, int V) {
  __shared__ float red[8];
  int row = blockIdx.x;
  const float* l = logits + (size_t)row * V;
  const float* y = labels + (size_t)row * V;
  float m = -3.4e38f, t = 0.f;
  for (int v = threadIdx.x; v < V; v += 256) { m = fmaxf(m, l[v]); t += y[v]; }
#pragma unroll
  for (int o = 32; o; o >>= 1) { m = fmaxf(m, __shfl_down(m, o)); t += __shfl_down(t, o); }
  int w = threadIdx.x >> 6;
  if ((threadIdx.x & 63) == 0) { red[w] = m; red[4 + w] = t; }
  __syncthreads();
  m = fmaxf(fmaxf(red[0], red[1]), fmaxf(red[2], red[3]));
  t = red[4] + red[5] + red[6] + red[7];
  __syncthreads();
  float s = 0.f;
  for (int v = threadIdx.x; v < V; v += 256) s += expf(l[v] - m);
#pragma unroll
  for (int o = 32; o; o >>= 1) s += __shfl_down(s, o);
  if ((threadIdx.x & 63) == 0) red[w] = s;
  __syncthreads();
  if (threadIdx.x == 0) { rowm[row] = m; rows[row] = red[0] + red[1] + red[2] + red[3]; rowt[row] = t; }
}

// dlogits = (w/Wsum) * (softmax * sum_labels - labels), bf16
__global__ __launch_bounds__(256) void k_dlogits(const float* logits, const float* labels,
                                                 const float* w, const float* rowm,
                                                 const float* rows, const float* rowt,
                                                 const float* wsum, ushort_t* dlb, int V) {
  int row = blockIdx.y;
  int v = blockIdx.x * 256 + threadIdx.x;
  size_t g = (size_t)row * V + v;
  float c = w[row] / wsum[0];
  float pr = expf(logits[g] - rowm[row]) / rows[row];
  dlb[g] = f2bf(c * (pr * rowt[row] - labels[g]));
}

// exclusive cumsum over L (16 segments of L/16), two-pass
__global__ __launch_bounds__(256) void k_scanpart(const float* gs, const float* gb, float* ps,
                                                  float* pb, int L, int D) {
  int d = blockIdx.x * 256 + threadIdx.x;
  int seg = blockIdx.y, b = blockIdx.z;
  const int SEGL = L / 16;
  size_t base = ((size_t)b * L + seg * SEGL) * D + d;
  float s1 = 0.f, s2 = 0.f;
  for (int i = 0; i < SEGL; i++) { s1 += gs[base + (size_t)i * D]; s2 += gb[base + (size_t)i * D]; }
  size_t pi = ((size_t)b * 16 + seg) * D + d;
  ps[pi] = s1; pb[pi] = s2;
}

__global__ __launch_bounds__(256) void k_scanapply(const float* gs, const float* gb,
                                                   const float* ps, const float* pb,
                                                   const float* sc, const float* bi,
                                                   const float* steps, float* fs, float* fb,
                                                   int L, int D) {
  int d = blockIdx.x * 256 + threadIdx.x;
  int seg = blockIdx.y, b = blockIdx.z;
  const int SEGL = L / 16;
  float ss = steps[3];
  float rs_ = 0.f, rb_ = 0.f;
  for (int s = 0; s < seg; s++) {
    size_t pi = ((size_t)b * 16 + s) * D + d;
    rs_ += ps[pi]; rb_ += pb[pi];
  }
  float s0 = sc[d], b0 = bi[d];
  size_t base = ((size_t)b * L + seg * SEGL) * D + d;
  for (int i = 0; i < SEGL; i++) {
    size_t g = base + (size_t)i * D;
    fs[g] = s0 - ss * rs_;           // exclusive: write before add
    fb[g] = b0 - ss * rb_;
    rs_ += gs[g]; rb_ += gb[g];
  }
}

// ---------- orchestration ----------
extern "C" void kernel_launch(void* const* d_in, const int* in_sizes, int n_in, void* d_out,
                              int out_size, void* d_ws, size_t ws_size, hipStream_t stream) {
  const float* x        = (const float*)d_in[0];
  const float* labels   = (const float*)d_in[1];
  const float* weights  = (const float*)d_in[2];
  const float* W1       = (const float*)d_in[3];
  const float* b1       = (const float*)d_in[4];
  const float* W2       = (const float*)d_in[5];
  const float* b2       = (const float*)d_in[6];
  const float* ln_scale = (const float*)d_in[7];
  const float* ln_bias  = (const float*)d_in[8];
  const float* Wu       = (const float*)d_in[9];
  const float* bu       = (const float*)d_in[10];
  const float* steps    = (const float*)d_in[11];

  const int BL = in_sizes[2];   // 4096
  const int D  = in_sizes[7];   // 1024
  const int F  = in_sizes[4];   // 4096
  const int V  = in_sizes[10];  // 8192
  const int Bb = 2, L = BL / Bb;

  char* ws = (char*)d_ws;
  size_t off = 0;
  auto take = [&](size_t b) { char* p = ws + off; off = (off + b + 255) & ~(size_t)255; return p; };

  ushort_t* xb   = (ushort_t*)take((size_t)BL * D * 2);
  ushort_t* w1t  = (ushort_t*)take((size_t)F * D * 2);
  ushort_t* w2t  = (ushort_t*)take((size_t)D * F * 2);
  ushort_t* w2b  = (ushort_t*)take((size_t)F * D * 2);
  ushort_t* wut  = (ushort_t*)take((size_t)V * D * 2);
  ushort_t* wub  = (ushort_t*)take((size_t)D * V * 2);
  float*    H1   = (float*)take((size_t)BL * F * 4);
  ushort_t* H2b  = (ushort_t*)take((size_t)BL * F * 2);
  float*    H3   = (float*)take((size_t)BL * D * 4);
  float*    nbuf = (float*)take((size_t)BL * D * 4);
  float*    rstd = (float*)take((size_t)BL * 4);
  ushort_t* h4b  = (ushort_t*)take((size_t)BL * D * 2);
  float*    rowm = (float*)take((size_t)BL * 4);
  float*    rows = (float*)take((size_t)BL * 4);
  float*    rowt = (float*)take((size_t)BL * 4);
  float*    wsumb= (float*)take(256);
  float*    G4   = (float*)take((size_t)BL * D * 4);   // also g_bias
  float*    gsc  = (float*)take((size_t)BL * D * 4);   // g_scale
  ushort_t* g3b  = (ushort_t*)take((size_t)BL * D * 2);
  ushort_t* g3t  = (ushort_t*)take((size_t)BL * D * 2);
  float*    fs   = (float*)take((size_t)BL * D * 4);
  float*    fb   = (float*)take((size_t)BL * D * 4);
  ushort_t* x4b  = (ushort_t*)take((size_t)BL * D * 2);
  float*    psc  = (float*)take((size_t)Bb * 16 * D * 4);
  float*    pbi  = (float*)take((size_t)Bb * 16 * D * 4);
  // poolA (128MB): logits f32, dead after dlogits -> {g1b, g1t, S1b, x2b} (112MB)
  char* poolA = take((size_t)BL * V * 4);
  float*    logits = (float*)poolA;
  ushort_t* g1b = (ushort_t*)poolA;
  ushort_t* g1t = (ushort_t*)(poolA + (size_t)BL * F * 2);
  ushort_t* S1b = (ushort_t*)(poolA + (size_t)BL * F * 4);
  ushort_t* x2b = (ushort_t*)(poolA + (size_t)BL * F * 4 + (size_t)Bb * L * L * 2);
  // poolB (64MB): dlb bf16, dead after G4 GEMM -> {S2b, X3, x3} (48MB)
  char* poolB = take((size_t)BL * V * 2);
  ushort_t* dlb = (ushort_t*)poolB;
  ushort_t* S2b = (ushort_t*)poolB;
  float*    X3  = (float*)(poolB + (size_t)Bb * L * L * 2);
  float*    x3  = (float*)(poolB + (size_t)Bb * L * L * 2 + (size_t)BL * D * 4);

  dim3 blk(256);

  // --- bf16 conversions / weight transposes ---
  k_conv<<<dim3((unsigned)((size_t)BL * D / 1024)), blk, 0, stream>>>(x, xb, (size_t)BL * D);
  k_tconv<<<dim3(F / 32, D / 32), blk, 0, stream>>>(W1, w1t, D, F);   // (F,D)
  k_tconv<<<dim3(D / 32, F / 32), blk, 0, stream>>>(W2, w2t, F, D);   // (D,F)
  k_conv<<<dim3((unsigned)((size_t)F * D / 1024)), blk, 0, stream>>>(W2, w2b, (size_t)F * D);
  k_tconv<<<dim3(V / 32, D / 32), blk, 0, stream>>>(Wu, wut, D, V);   // (V,D)
  k_conv<<<dim3((unsigned)((size_t)D * V / 1024)), blk, 0, stream>>>(Wu, wub, (size_t)D * V);

  GemmP p;
  auto clr = [&]() { p = GemmP{}; };

  // 1) H1 = x@W1+b1 ; H2 = relu(H1)^2
  clr(); p.A = xb; p.B = w1t; p.M = BL; p.N = F; p.K = D;
  p.outf = H1; p.outb = H2b; p.bias = b1;
  gemm_bt<1><<<dim3(F / 128, BL / 128, 1), blk, 0, stream>>>(p);
  // 2) H3 = H2@W2 + b2
  clr(); p.A = H2b; p.B = w2t; p.M = BL; p.N = D; p.K = F; p.outf = H3; p.bias = b2;
  gemm_bt<0><<<dim3(D / 128, BL / 128, 1), blk, 0, stream>>>(p);
  // 3) LN fwd
  k_lnfwd<<<dim3(BL), blk, 0, stream>>>(H3, ln_scale, ln_bias, nbuf, rstd, h4b, D);
  // 4) logits = h4@Wu + bu
  clr(); p.A = h4b; p.B = wut; p.M = BL; p.N = V; p.K = D; p.outf = logits; p.bias = bu;
  gemm_bt<0><<<dim3(V / 128, BL / 128, 1), blk, 0, stream>>>(p);
  // 5) softmax / label stats
  k_wsum<<<dim3(1), blk, 0, stream>>>(weights, wsumb, BL);
  k_rowstats<<<dim3(BL), blk, 0, stream>>>(logits, labels, rowm, rows, rowt, V);
  k_dlogits<<<dim3(V / 256, BL), blk, 0, stream>>>(logits, labels, weights, rowm, rows, rowt,
                                                   wsumb, dlb, V);
  // 6) G4 = dlogits @ Wu^T
  clr(); p.A = dlb; p.B = wub; p.M = BL; p.N = D; p.K = V; p.outf = G4;
  gemm_bt<0><<<dim3(D / 128, BL / 128, 1), blk, 0, stream>>>(p);
  // 7) LN bwd -> g3, g_scale
  k_lnbwd<<<dim3(BL), blk, 0, stream>>>(G4, nbuf, rstd, ln_scale, g3b, gsc, D);
  // 8) g1 = (g3 @ W2^T) * 2*sqrt(H2)
  clr(); p.A = g3b; p.B = w2b; p.M = BL; p.N = F; p.K = D; p.outb = g1b; p.auxb = H2b;
  gemm_bt<2><<<dim3(F / 128, BL / 128, 1), blk, 0, stream>>>(p);
  // 9) transposes for attention V-operands
  k_tb2b<<<dim3(F / 32, L / 32, Bb), blk, 0, stream>>>(g1b, g1t, L, F);
  k_tb2b<<<dim3(D / 32, L / 32, Bb), blk, 0, stream>>>(g3b, g3t, L, D);
  // 10) S1 = tril(x x^T, -1)  [batched]
  clr(); p.A = xb; p.B = xb; p.M = L; p.N = L; p.K = D;
  p.sA = (long long)L * D; p.sB = (long long)L * D; p.outb = S1b; p.sOutB = (long long)L * L;
  gemm_bt<3><<<dim3(L / 128, L / 128, Bb), blk, 0, stream>>>(p);
  // 11) x2 = relu(H1 - ss0 * S1@g1)^2  [batched, K-limited]
  clr(); p.A = S1b; p.B = g1t; p.M = L; p.N = F; p.K = L;
  p.sA = (long long)L * L; p.sB = (long long)F * L;
  p.outb = x2b; p.sOutB = (long long)L * F; p.auxf = H1; p.sAuxF = (long long)L * F; p.steps = steps;
  gemm_bt<4><<<dim3(F / 128, L / 128, Bb), blk, 0, stream>>>(p);
  // 12) X3 = x2@W2 + b2
  clr(); p.A = x2b; p.B = w2t; p.M = BL; p.N = D; p.K = F; p.outf = X3; p.bias = b2;
  gemm_bt<0><<<dim3(D / 128, BL / 128, 1), blk, 0, stream>>>(p);
  // 13) S2 = tril(x2 H2^T, -1)  [batched]
  clr(); p.A = x2b; p.B = H2b; p.M = L; p.N = L; p.K = F;
  p.sA = (long long)L * F; p.sB = (long long)L * F; p.outb = S2b; p.sOutB = (long long)L * L;
  gemm_bt<3><<<dim3(L / 128, L / 128, Bb), blk, 0, stream>>>(p);
  // 14) x3 = X3 - ss2 * S2@g3  [batched, K-limited]
  clr(); p.A = S2b; p.B = g3t; p.M = L; p.N = D; p.K = L;
  p.sA = (long long)L * L; p.sB = (long long)D * L;
  p.outf = x3; p.sOutF = (long long)L * D; p.auxf = X3; p.sAuxF = (long long)L * D; p.steps = steps;
  gemm_bt<5><<<dim3(D / 128, L / 128, Bb), blk, 0, stream>>>(p);
  // 15) exclusive cumsums -> fast_scale / fast_bias
  k_scanpart<<<dim3(D / 256, 16, Bb), blk, 0, stream>>>(gsc, G4, psc, pbi, L, D);
  k_scanapply<<<dim3(D / 256, 16, Bb), blk, 0, stream>>>(gsc, G4, psc, pbi, ln_scale, ln_bias,
                                                         steps, fs, fb, L, D);
  // 16) x4 = LN(x3)*fast_scale + fast_bias
  k_lnfwd2<<<dim3(BL), blk, 0, stream>>>(x3, fs, fb, x4b, D);
  // 17) out = x4@Wu + bu
  clr(); p.A = x4b; p.B = wut; p.M = BL; p.N = V; p.K = D; p.outf = (float*)d_out; p.bias = bu;
  gemm_bt<0><<<dim3(V / 128, BL / 128, 1), blk, 0, stream>>>(p);
}

// Round 2
// 1459.312 us; speedup vs baseline: 1.0814x; 1.0814x over previous
//
#include <hip/hip_runtime.h>
#include <cstdint>

typedef unsigned short ushort_t;
typedef __bf16 bf16x8 __attribute__((ext_vector_type(8)));
typedef float f32x4 __attribute__((ext_vector_type(4)));

// ---------- helpers ----------
__device__ __forceinline__ ushort_t f2bf(float f) {
  union { float f; unsigned int u; } v; v.f = f;
  unsigned int u = v.u;
  unsigned int r = (u + 0x7fffu + ((u >> 16) & 1u)) >> 16;
  return (ushort_t)r;
}
__device__ __forceinline__ float bf2f(ushort_t u) {
  union { unsigned int u; float f; } v; v.u = ((unsigned int)u) << 16; return v.f;
}

#define GLOAD16(gp, lp)                                                              \
  __builtin_amdgcn_global_load_lds(                                                  \
      reinterpret_cast<const __attribute__((address_space(1))) unsigned int*>(       \
          reinterpret_cast<uintptr_t>(gp)),                                          \
      reinterpret_cast<__attribute__((address_space(3))) unsigned int*>(             \
          reinterpret_cast<uintptr_t>(lp)),                                          \
      16, 0, 0)

// ---------- GEMM: C[M,N] = A[M,K] @ B[N,K]^T, bf16 in, f32 acc ----------
// EPI: 0 = outf = acc + bias                     (logits, out)
//      1 = outf = acc + bias; outb = bf16(relu(outf)^2)   (H1 + H2b)
//      2 = outb = bf16(acc * 2*sqrt(auxb))       (g1)
//      4 = outb = bf16(relu(auxf - ss0*acc)^2); K-limit   (x2)
//      5 = outf = auxf - ss2*acc; K-limit        (x3)
//      6 = split-K partial, full-matrix f32      (H3, G4, X3 stage 1)
//      7 = split-K partial, tri-skip, compact-tile f32    (S1, S2 stage 1)
struct GemmP {
  const ushort_t* A; const ushort_t* B;
  int M, N, K;
  long long sA, sB;
  float* outf;   long long sOutF;
  ushort_t* outb; long long sOutB;
  const float* bias;
  const float* auxf; long long sAuxF;
  const ushort_t* auxb;
  const float* steps;
  float* part; int ksplit, Kc, Tt;   // split-K partial buffer / params
};

template <int EPI>
__global__ __launch_bounds__(256) void gemm_bt(GemmP p) {
  // T1: bijective XCD swizzle (m204) over the xy tile plane; consecutive
  // same-XCD blocks share mt (A panel) for L2 reuse.
  const int nwg = gridDim.x * gridDim.y;
  const int orig = blockIdx.y * gridDim.x + blockIdx.x;
  const int xcd = orig & 7, loc = orig >> 3;
  const int q = nwg >> 3, r = nwg & 7;
  const int wg = (xcd < r) ? (xcd * (q + 1) + loc) : (r * (q + 1) + (xcd - r) * q + loc);
  const int nt = wg % gridDim.x, mt = wg / gridDim.x;
  const int m0 = mt * 128, n0 = nt * 128;
  if (EPI == 7 && n0 > m0) return;  // strictly-upper tiles never read downstream

  int bz = blockIdx.z, ks = 0;
  if (EPI == 6 || EPI == 7) { bz = blockIdx.z / p.ksplit; ks = blockIdx.z % p.ksplit; }

  const ushort_t* A = p.A + (size_t)bz * p.sA;
  const ushort_t* B = p.B + (size_t)bz * p.sB;

  int kbeg = 0, kend = p.K;
  if (EPI == 6 || EPI == 7) { kbeg = ks * p.Kc; kend = kbeg + p.Kc; }
  else if (EPI == 4 || EPI == 5) kend = min(p.K, m0 + 128);

  __shared__ ushort_t sA[128 * 32];
  __shared__ ushort_t sB[128 * 32];

  const int tid = threadIdx.x;
  const int wid = tid >> 6, lane = tid & 63;
  const int wm = wid >> 1, wn = wid & 1;

  f32x4 acc[4][4];
#pragma unroll
  for (int i = 0; i < 4; i++)
#pragma unroll
    for (int j = 0; j < 4; j++) acc[i][j] = f32x4{0.f, 0.f, 0.f, 0.f};

  const int lr = lane >> 2;
  const int lc = (lane & 3) * 8;
  const int rA0 = wid * 16 + lr;
  const int rA1 = 64 + wid * 16 + lr;
  const ushort_t* gA0 = A + (size_t)(m0 + rA0) * p.K + lc;
  const ushort_t* gA1 = A + (size_t)(m0 + rA1) * p.K + lc;
  const ushort_t* gB0 = B + (size_t)(n0 + rA0) * p.K + lc;
  const ushort_t* gB1 = B + (size_t)(n0 + rA1) * p.K + lc;
  ushort_t* lA0 = &sA[wid * 512];
  ushort_t* lA1 = &sA[(4 + wid) * 512];
  ushort_t* lB0 = &sB[wid * 512];
  ushort_t* lB1 = &sB[(4 + wid) * 512];

  const int fr = lane & 15;
  const int kb = (lane >> 4) * 8;

  for (int k = kbeg; k < kend; k += 32) {
    GLOAD16(gA0 + k, lA0);
    GLOAD16(gA1 + k, lA1);
    GLOAD16(gB0 + k, lB0);
    GLOAD16(gB1 + k, lB1);
    __syncthreads();
    bf16x8 av[4], bv[4];
#pragma unroll
    for (int i = 0; i < 4; i++) {
      av[i] = *reinterpret_cast<const bf16x8*>(&sA[(wm * 64 + i * 16 + fr) * 32 + kb]);
      bv[i] = *reinterpret_cast<const bf16x8*>(&sB[(wn * 64 + i * 16 + fr) * 32 + kb]);
    }
#pragma unroll
    for (int i = 0; i < 4; i++)
#pragma unroll
      for (int j = 0; j < 4; j++)
        acc[i][j] = __builtin_amdgcn_mfma_f32_16x16x32_bf16(av[i], bv[j], acc[i][j], 0, 0, 0);
    __syncthreads();
  }

  const int fq = lane >> 4;
  float ss = 0.f;
  if (EPI == 4) ss = p.steps[0];
  else if (EPI == 5) ss = p.steps[2];
  float* outf = p.outf ? p.outf + (size_t)bz * p.sOutF : nullptr;
  ushort_t* outb = p.outb ? p.outb + (size_t)bz * p.sOutB : nullptr;
  const float* auxf = p.auxf ? p.auxf + (size_t)bz * p.sAuxF : nullptr;
  float* partT = nullptr;
  if (EPI == 6) partT = p.part + (size_t)blockIdx.z * p.M * p.N;
  if (EPI == 7) partT = p.part + ((size_t)blockIdx.z * p.Tt + (size_t)mt * (mt + 1) / 2 + nt) * 16384;

#pragma unroll
  for (int i = 0; i < 4; i++) {
#pragma unroll
    for (int j = 0; j < 4; j++) {
#pragma unroll
      for (int r2 = 0; r2 < 4; r2++) {
        int lrow = wm * 64 + i * 16 + fq * 4 + r2;
        int lcol = wn * 64 + j * 16 + fr;
        int row = m0 + lrow, col = n0 + lcol;
        size_t g = (size_t)row * p.N + col;
        float v = acc[i][j][r2];
        if (EPI == 0) {
          outf[g] = v + (p.bias ? p.bias[col] : 0.f);
        } else if (EPI == 1) {
          v += p.bias[col];
          outf[g] = v;
          float rl = fmaxf(v, 0.f);
          outb[g] = f2bf(rl * rl);
        } else if (EPI == 2) {
          outb[g] = f2bf(v * 2.f * sqrtf(bf2f(p.auxb[g])));
        } else if (EPI == 4) {
          float x1 = auxf[g] - ss * v;
          float rl = fmaxf(x1, 0.f);
          outb[g] = f2bf(rl * rl);
        } else if (EPI == 5) {
          outf[g] = auxf[g] - ss * v;
        } else if (EPI == 6) {
          partT[g] = v;
        } else if (EPI == 7) {
          partT[lrow * 128 + lcol] = v;
        }
      }
    }
  }
}

// ---------- split-K combines ----------
// out_f32 = sum_s part[s] (+ bias)
__global__ __launch_bounds__(256) void k_comb(const float* part, const float* bias, float* out,
                                              int N, size_t MN, int S) {
  size_t e = ((size_t)blockIdx.x * 256 + threadIdx.x) * 4;
  if (e >= MN) return;
  float4 s = *(const float4*)(part + e);
  for (int p_ = 1; p_ < S; p_++) {
    float4 v = *(const float4*)(part + (size_t)p_ * MN + e);
    s.x += v.x; s.y += v.y; s.z += v.z; s.w += v.w;
  }
  if (bias) {
    int col = (int)(e % (size_t)N);
    s.x += bias[col]; s.y += bias[col + 1]; s.z += bias[col + 2]; s.w += bias[col + 3];
  }
  *(float4*)(out + e) = s;
}

// S_bf16 = tril(sum_s part_compact[s], -1); grid (Tt, Bb)
__global__ __launch_bounds__(256) void k_combtri(const float* part, ushort_t* out, int Tt, int S,
                                                 int L) {
  int t = blockIdx.x, bz = blockIdx.y;
  int mt = (int)((sqrtf(8.f * t + 1.f) - 1.f) * 0.5f);
  while ((mt + 1) * (mt + 2) / 2 <= t) mt++;
  while (mt * (mt + 1) / 2 > t) mt--;
  int nt = t - mt * (mt + 1) / 2;
  const float* pb = part + ((size_t)bz * S * Tt + t) * 16384;
  ushort_t* ob = out + (size_t)bz * L * L;
  for (int e4 = threadIdx.x; e4 < 4096; e4 += 256) {
    int e = e4 * 4;
    float4 s = *(const float4*)(pb + e);
    for (int p_ = 1; p_ < S; p_++) {
      float4 v = *(const float4*)(pb + (size_t)p_ * Tt * 16384 + e);
      s.x += v.x; s.y += v.y; s.z += v.z; s.w += v.w;
    }
    int lr = e >> 7, lc2 = e & 127;
    int row = mt * 128 + lr, col = nt * 128 + lc2;
    ushort4 o;
    o.x = (col < row) ? f2bf(s.x) : (ushort_t)0;
    o.y = (col + 1 < row) ? f2bf(s.y) : (ushort_t)0;
    o.z = (col + 2 < row) ? f2bf(s.z) : (ushort_t)0;
    o.w = (col + 3 < row) ? f2bf(s.w) : (ushort_t)0;
    *(ushort4*)(&ob[(size_t)row * L + col]) = o;
  }
}

// ---------- auxiliary kernels ----------
__global__ __launch_bounds__(256) void k_conv(const float* in, ushort_t* out, size_t n) {
  size_t i = ((size_t)blockIdx.x * 256 + threadIdx.x) * 4;
  if (i >= n) return;
  float4 v = *(const float4*)(in + i);
  out[i] = f2bf(v.x); out[i + 1] = f2bf(v.y); out[i + 2] = f2bf(v.z); out[i + 3] = f2bf(v.w);
}

__global__ __launch_bounds__(256) void k_tconv(const float* in, ushort_t* out, int R, int C) {
  __shared__ float t[32][33];
  int c0 = blockIdx.x * 32, r0 = blockIdx.y * 32;
  int tx = threadIdx.x & 31, ty = threadIdx.x >> 5;
#pragma unroll
  for (int i = ty; i < 32; i += 8) t[i][tx] = in[(size_t)(r0 + i) * C + c0 + tx];
  __syncthreads();
#pragma unroll
  for (int i = ty; i < 32; i += 8) out[(size_t)(c0 + i) * R + r0 + tx] = f2bf(t[tx][i]);
}

__global__ __launch_bounds__(256) void k_tb2b(const ushort_t* in, ushort_t* out, int L, int C) {
  __shared__ ushort_t t[32][33];
  int b = blockIdx.z;
  const ushort_t* ib = in + (size_t)b * L * C;
  ushort_t* ob = out + (size_t)b * C * L;
  int c0 = blockIdx.x * 32, l0 = blockIdx.y * 32;
  int tx = threadIdx.x & 31, ty = threadIdx.x >> 5;
#pragma unroll
  for (int i = ty; i < 32; i += 8) t[i][tx] = ib[(size_t)(l0 + i) * C + c0 + tx];
  __syncthreads();
#pragma unroll
  for (int i = ty; i < 32; i += 8) ob[(size_t)(c0 + i) * L + l0 + tx] = t[tx][i];
}

__device__ __forceinline__ void blockRed2(float& a, float& b, float* red) {
#pragma unroll
  for (int o = 32; o; o >>= 1) { a += __shfl_down(a, o); b += __shfl_down(b, o); }
  int w = threadIdx.x >> 6;
  if ((threadIdx.x & 63) == 0) { red[w] = a; red[4 + w] = b; }
  __syncthreads();
  a = red[0] + red[1] + red[2] + red[3];
  b = red[4] + red[5] + red[6] + red[7];
  __syncthreads();
}

__global__ __launch_bounds__(256) void k_lnfwd(const float* X, const float* sc, const float* bi,
                                               float* nout, float* rstd, ushort_t* yb, int D) {
  __shared__ float red[8];
  int row = blockIdx.x;
  const float* x = X + (size_t)row * D;
  float s = 0.f, s2 = 0.f;
  for (int d = threadIdx.x; d < D; d += 256) { float v = x[d]; s += v; s2 += v * v; }
  blockRed2(s, s2, red);
  float mu = s / D;
  float var = s2 / D - mu * mu;
  float rs = rsqrtf(var + 1e-6f);
  for (int d = threadIdx.x; d < D; d += 256) {
    float nv = (x[d] - mu) * rs;
    nout[(size_t)row * D + d] = nv;
    yb[(size_t)row * D + d] = f2bf(nv * sc[d] + bi[d]);
  }
  if (threadIdx.x == 0) rstd[row] = rs;
}

__global__ __launch_bounds__(256) void k_lnfwd2(const float* X, const float* fs, const float* fb,
                                                ushort_t* yb, int D) {
  __shared__ float red[8];
  int row = blockIdx.x;
  const float* x = X + (size_t)row * D;
  float s = 0.f, s2 = 0.f;
  for (int d = threadIdx.x; d < D; d += 256) { float v = x[d]; s += v; s2 += v * v; }
  blockRed2(s, s2, red);
  float mu = s / D;
  float var = s2 / D - mu * mu;
  float rs = rsqrtf(var + 1e-6f);
  for (int d = threadIdx.x; d < D; d += 256) {
    size_t g = (size_t)row * D + d;
    float nv = (x[d] - mu) * rs;
    yb[g] = f2bf(nv * fs[g] + fb[g]);
  }
}

__global__ __launch_bounds__(256) void k_lnbwd(const float* G, const float* nn, const float* rstd,
                                               const float* sc, ushort_t* g3b, float* gsc, int D) {
  __shared__ float red[8];
  int row = blockIdx.x;
  const float* g = G + (size_t)row * D;
  const float* n_ = nn + (size_t)row * D;
  float sa = 0.f, sb = 0.f;
  for (int d = threadIdx.x; d < D; d += 256) {
    float dn = g[d] * sc[d];
    sa += dn; sb += dn * n_[d];
  }
  blockRed2(sa, sb, red);
  float a = sa / D, b = sb / D, rs = rstd[row];
  for (int d = threadIdx.x; d < D; d += 256) {
    size_t gi = (size_t)row * D + d;
    float dn = g[d] * sc[d];
    g3b[gi] = f2bf(rs * (dn - a - n_[d] * b));
    gsc[gi] = g[d] * n_[d];
  }
}

__global__ __launch_bounds__(256) void k_wsum(const float* w, float* o, int n) {
  __shared__ float red[4];
  float s = 0.f;
  for (int i = threadIdx.x; i < n; i += 256) s += w[i];
#pragma unroll
  for (int d = 32; d; d >>= 1) s += __shfl_down(s, d);
  if ((threadIdx.x & 63) == 0) red[threadIdx.x >> 6] = s;
  __syncthreads();
  if (threadIdx.x == 0) o[0] = fmaxf(red[0] + red[1] + red[2] + red[3], 1e-8f);
}

// fused softmax-grad: per row stage logits in LDS, compute max/sumexp/sumlabels,
// write dlogits = (w/Wsum)*(softmax*sum_labels - labels) in one logits pass.
__global__ __launch_bounds__(256) void k_softgrad(const float* logits, const float* labels,
                                                  const float* w, const float* wsum,
                                                  ushort_t* dlb, int V) {
  __shared__ float lrow[8192];
  __shared__ float red[8];
  int row = blockIdx.x;
  const float* l = logits + (size_t)row * V;
  const float* y = labels + (size_t)row * V;
  float m = -3.4e38f, t = 0.f;
  for (int v = threadIdx.x; v < V; v += 256) {
    float lv = l[v];
    lrow[v] = lv;
    m = fmaxf(m, lv);
    t += y[v];
  }
#pragma unroll
  for (int o = 32; o; o >>= 1) { m = fmaxf(m, __shfl_down(m, o)); t += __shfl_down(t, o); }
  int wv = threadIdx.x >> 6;
  if ((threadIdx.x & 63) == 0) { red[wv] = m; red[4 + wv] = t; }
  __syncthreads();
  m = fmaxf(fmaxf(red[0], red[1]), fmaxf(red[2], red[3]));
  t = red[4] + red[5] + red[6] + red[7];
  __syncthreads();
  float s = 0.f;
  for (int v = threadIdx.x; v < V; v += 256) s += expf(lrow[v] - m);
#pragma unroll
  for (int o = 32; o; o >>= 1) s += __shfl_down(s, o);
  if ((threadIdx.x & 63) == 0) red[wv] = s;
  __syncthreads();
  s = red[0] + red[1] + red[2] + red[3];
  float c = w[row] / wsum[0];
  float invs = 1.f / s;
  for (int v = threadIdx.x; v < V; v += 256) {
    size_t g = (size_t)row * V + v;
    dlb[g] = f2bf(c * (expf(lrow[v] - m) * invs * t - y[v]));
  }
}

__global__ __launch_bounds__(256) void k_scanpart(const float* gs, const float* gb, float* ps,
                                                  float* pb, int L, int D) {
  int d = blockIdx.x * 256 + threadIdx.x;
  int seg = blockIdx.y, b = blockIdx.z;
  const int SEGL = L / 16;
  size_t base = ((size_t)b * L + seg * SEGL) * D + d;
  float s1 = 0.f, s2 = 0.f;
  for (int i = 0; i < SEGL; i++) { s1 += gs[base + (size_t)i * D]; s2 += gb[base + (size_t)i * D]; }
  size_t pi = ((size_t)b * 16 + seg) * D + d;
  ps[pi] = s1; pb[pi] = s2;
}

__global__ __launch_bounds__(256) void k_scanapply(const float* gs, const float* gb,
                                                   const float* ps, const float* pb,
                                                   const float* sc, const float* bi,
                                                   const float* steps, float* fs, float* fb,
                                                   int L, int D) {
  int d = blockIdx.x * 256 + threadIdx.x;
  int seg = blockIdx.y, b = blockIdx.z;
  const int SEGL = L / 16;
  float ss = steps[3];
  float rs_ = 0.f, rb_ = 0.f;
  for (int s = 0; s < seg; s++) {
    size_t pi = ((size_t)b * 16 + s) * D + d;
    rs_ += ps[pi]; rb_ += pb[pi];
  }
  float s0 = sc[d], b0 = bi[d];
  size_t base = ((size_t)b * L + seg * SEGL) * D + d;
  for (int i = 0; i < SEGL; i++) {
    size_t g = base + (size_t)i * D;
    fs[g] = s0 - ss * rs_;
    fb[g] = b0 - ss * rb_;
    rs_ += gs[g]; rb_ += gb[g];
  }
}

// ---------- orchestration ----------
extern "C" void kernel_launch(void* const* d_in, const int* in_sizes, int n_in, void* d_out,
                              int out_size, void* d_ws, size_t ws_size, hipStream_t stream) {
  const float* x        = (const float*)d_in[0];
  const float* labels   = (const float*)d_in[1];
  const float* weights  = (const float*)d_in[2];
  const float* W1       = (const float*)d_in[3];
  const float* b1       = (const float*)d_in[4];
  const float* W2       = (const float*)d_in[5];
  const float* b2       = (const float*)d_in[6];
  const float* ln_scale = (const float*)d_in[7];
  const float* ln_bias  = (const float*)d_in[8];
  const float* Wu       = (const float*)d_in[9];
  const float* bu       = (const float*)d_in[10];
  const float* steps    = (const float*)d_in[11];

  const int BL = in_sizes[2];   // 4096
  const int D  = in_sizes[7];   // 1024
  const int F  = in_sizes[4];   // 4096
  const int V  = in_sizes[10];  // 8192
  const int Bb = 2, L = BL / Bb;
  const int Tt = (L / 128) * (L / 128 + 1) / 2;  // 136 compact lower-tri tiles

  char* ws = (char*)d_ws;
  size_t off = 0;
  auto take = [&](size_t b) { char* p = ws + off; off = (off + b + 255) & ~(size_t)255; return p; };

  ushort_t* xb   = (ushort_t*)take((size_t)BL * D * 2);
  ushort_t* w1t  = (ushort_t*)take((size_t)F * D * 2);
  ushort_t* w2t  = (ushort_t*)take((size_t)D * F * 2);
  ushort_t* w2b  = (ushort_t*)take((size_t)F * D * 2);
  ushort_t* wut  = (ushort_t*)take((size_t)V * D * 2);
  ushort_t* wub  = (ushort_t*)take((size_t)D * V * 2);
  float*    H1   = (float*)take((size_t)BL * F * 4);
  ushort_t* H2b  = (ushort_t*)take((size_t)BL * F * 2);
  float*    H3   = (float*)take((size_t)BL * D * 4);
  float*    nbuf = (float*)take((size_t)BL * D * 4);
  float*    rstd = (float*)take((size_t)BL * 4);
  ushort_t* h4b  = (ushort_t*)take((size_t)BL * D * 2);
  float*    wsumb= (float*)take(256);
  float*    G4   = (float*)take((size_t)BL * D * 4);   // also g_bias
  float*    gsc  = (float*)take((size_t)BL * D * 4);   // g_scale
  ushort_t* g3b  = (ushort_t*)take((size_t)BL * D * 2);
  ushort_t* g3t  = (ushort_t*)take((size_t)BL * D * 2);
  float*    fs   = (float*)take((size_t)BL * D * 4);
  float*    fb   = (float*)take((size_t)BL * D * 4);
  ushort_t* x4b  = (ushort_t*)take((size_t)BL * D * 2);
  float*    psc  = (float*)take((size_t)Bb * 16 * D * 4);
  float*    pbi  = (float*)take((size_t)Bb * 16 * D * 4);
  // poolA (134MB): logits f32 -> later {g1b, g1t, S1b, x2b}; head [0..67MB) also
  // hosts split-K partials (H3/G4/X3: 4x16.8MB full; S2: 2x2x8.9MB compact-tri)
  char* poolA = take((size_t)BL * V * 4);
  float*    logits = (float*)poolA;
  float*    partA  = (float*)poolA;
  ushort_t* g1b = (ushort_t*)poolA;
  ushort_t* g1t = (ushort_t*)(poolA + (size_t)BL * F * 2);
  ushort_t* S1b = (ushort_t*)(poolA + (size_t)BL * F * 4);
  ushort_t* x2b = (ushort_t*)(poolA + (size_t)BL * F * 4 + (size_t)Bb * L * L * 2);
  // poolB (64MB): dlb bf16 -> later {S2b, X3, x3}; head also hosts S1 partials (35.7MB)
  char* poolB = take((size_t)BL * V * 2);
  ushort_t* dlb = (ushort_t*)poolB;
  float*    partS1 = (float*)poolB;
  ushort_t* S2b = (ushort_t*)poolB;
  float*    X3  = (float*)(poolB + (size_t)Bb * L * L * 2);
  float*    x3  = (float*)(poolB + (size_t)Bb * L * L * 2 + (size_t)BL * D * 4);

  dim3 blk(256);
  const size_t MN_D = (size_t)BL * D;

  // --- bf16 conversions / weight transposes ---
  k_conv<<<dim3((unsigned)((size_t)BL * D / 1024)), blk, 0, stream>>>(x, xb, (size_t)BL * D);
  k_tconv<<<dim3(F / 32, D / 32), blk, 0, stream>>>(W1, w1t, D, F);
  k_tconv<<<dim3(D / 32, F / 32), blk, 0, stream>>>(W2, w2t, F, D);
  k_conv<<<dim3((unsigned)((size_t)F * D / 1024)), blk, 0, stream>>>(W2, w2b, (size_t)F * D);
  k_tconv<<<dim3(V / 32, D / 32), blk, 0, stream>>>(Wu, wut, D, V);
  k_conv<<<dim3((unsigned)((size_t)D * V / 1024)), blk, 0, stream>>>(Wu, wub, (size_t)D * V);

  GemmP p;
  auto clr = [&]() { p = GemmP{}; };

  // 1) H1 = x@W1+b1 ; H2 = relu(H1)^2
  clr(); p.A = xb; p.B = w1t; p.M = BL; p.N = F; p.K = D;
  p.outf = H1; p.outb = H2b; p.bias = b1;
  gemm_bt<1><<<dim3(F / 128, BL / 128, 1), blk, 0, stream>>>(p);
  // 2) H3 = H2@W2 + b2   [split-K 4]
  clr(); p.A = H2b; p.B = w2t; p.M = BL; p.N = D; p.K = F;
  p.part = partA; p.ksplit = 4; p.Kc = F / 4;
  gemm_bt<6><<<dim3(D / 128, BL / 128, 4), blk, 0, stream>>>(p);
  k_comb<<<dim3((unsigned)(MN_D / 1024)), blk, 0, stream>>>(partA, b2, H3, D, MN_D, 4);
  // 3) LN fwd
  k_lnfwd<<<dim3(BL), blk, 0, stream>>>(H3, ln_scale, ln_bias, nbuf, rstd, h4b, D);
  // 4) logits = h4@Wu + bu
  clr(); p.A = h4b; p.B = wut; p.M = BL; p.N = V; p.K = D; p.outf = logits; p.bias = bu;
  gemm_bt<0><<<dim3(V / 128, BL / 128, 1), blk, 0, stream>>>(p);
  // 5) fused softmax grad
  k_wsum<<<dim3(1), blk, 0, stream>>>(weights, wsumb, BL);
  k_softgrad<<<dim3(BL), blk, 0, stream>>>(logits, labels, weights, wsumb, dlb, V);
  // 6) G4 = dlogits @ Wu^T   [split-K 4]
  clr(); p.A = dlb; p.B = wub; p.M = BL; p.N = D; p.K = V;
  p.part = partA; p.ksplit = 4; p.Kc = V / 4;
  gemm_bt<6><<<dim3(D / 128, BL / 128, 4), blk, 0, stream>>>(p);
  k_comb<<<dim3((unsigned)(MN_D / 1024)), blk, 0, stream>>>(partA, nullptr, G4, D, MN_D, 4);
  // 7) LN bwd -> g3, g_scale
  k_lnbwd<<<dim3(BL), blk, 0, stream>>>(G4, nbuf, rstd, ln_scale, g3b, gsc, D);
  // 8) g1 = (g3 @ W2^T) * 2*sqrt(H2)
  clr(); p.A = g3b; p.B = w2b; p.M = BL; p.N = F; p.K = D; p.outb = g1b; p.auxb = H2b;
  gemm_bt<2><<<dim3(F / 128, BL / 128, 1), blk, 0, stream>>>(p);
  // 9) transposes for attention V-operands
  k_tb2b<<<dim3(F / 32, L / 32, Bb), blk, 0, stream>>>(g1b, g1t, L, F);
  k_tb2b<<<dim3(D / 32, L / 32, Bb), blk, 0, stream>>>(g3b, g3t, L, D);
  // 10) S1 = tril(x x^T, -1)   [split-K 2, compact-tri partials in poolB]
  clr(); p.A = xb; p.B = xb; p.M = L; p.N = L; p.K = D;
  p.sA = (long long)L * D; p.sB = (long long)L * D;
  p.part = partS1; p.ksplit = 2; p.Kc = D / 2; p.Tt = Tt;
  gemm_bt<7><<<dim3(L / 128, L / 128, Bb * 2), blk, 0, stream>>>(p);
  k_combtri<<<dim3(Tt, Bb), blk, 0, stream>>>(partS1, S1b, Tt, 2, L);
  // 11) x2 = relu(H1 - ss0 * S1@g1)^2   [K-limited]
  clr(); p.A = S1b; p.B = g1t; p.M = L; p.N = F; p.K = L;
  p.sA = (long long)L * L; p.sB = (long long)F * L;
  p.outb = x2b; p.sOutB = (long long)L * F; p.auxf = H1; p.sAuxF = (long long)L * F; p.steps = steps;
  gemm_bt<4><<<dim3(F / 128, L / 128, Bb), blk, 0, stream>>>(p);
  // 12) X3 = x2@W2 + b2   [split-K 4]
  clr(); p.A = x2b; p.B = w2t; p.M = BL; p.N = D; p.K = F;
  p.part = partA; p.ksplit = 4; p.Kc = F / 4;
  gemm_bt<6><<<dim3(D / 128, BL / 128, 4), blk, 0, stream>>>(p);
  k_comb<<<dim3((unsigned)(MN_D / 1024)), blk, 0, stream>>>(partA, b2, X3, D, MN_D, 4);
  // 13) S2 = tril(x2 H2^T, -1)   [split-K 2, compact-tri partials in poolA head]
  clr(); p.A = x2b; p.B = H2b; p.M = L; p.N = L; p.K = F;
  p.sA = (long long)L * F; p.sB = (long long)L * F;
  p.part = partA; p.ksplit = 2; p.Kc = F / 2; p.Tt = Tt;
  gemm_bt<7><<<dim3(L / 128, L / 128, Bb * 2), blk, 0, stream>>>(p);
  k_combtri<<<dim3(Tt, Bb), blk, 0, stream>>>(partA, S2b, Tt, 2, L);
  // 14) x3 = X3 - ss2 * S2@g3   [K-limited]
  clr(); p.A = S2b; p.B = g3t; p.M = L; p.N = D; p.K = L;
  p.sA = (long long)L * L; p.sB = (long long)D * L;
  p.outf = x3; p.sOutF = (long long)L * D; p.auxf = X3; p.sAuxF = (long long)L * D; p.steps = steps;
  gemm_bt<5><<<dim3(D / 128, L / 128, Bb), blk, 0, stream>>>(p);
  // 15) exclusive cumsums -> fast_scale / fast_bias
  k_scanpart<<<dim3(D / 256, 16, Bb), blk, 0, stream>>>(gsc, G4, psc, pbi, L, D);
  k_scanapply<<<dim3(D / 256, 16, Bb), blk, 0, stream>>>(gsc, G4, psc, pbi, ln_scale, ln_bias,
                                                         steps, fs, fb, L, D);
  // 16) x4 = LN(x3)*fast_scale + fast_bias
  k_lnfwd2<<<dim3(BL), blk, 0, stream>>>(x3, fs, fb, x4b, D);
  // 17) out = x4@Wu + bu
  clr(); p.A = x4b; p.B = wut; p.M = BL; p.N = V; p.K = D; p.outf = (float*)d_out; p.bias = bu;
  gemm_bt<0><<<dim3(V / 128, BL / 128, 1), blk, 0, stream>>>(p);
}

// Round 3
// 1276.696 us; speedup vs baseline: 1.2361x; 1.1430x over previous
//
#include <hip/hip_runtime.h>
#include <cstdint>

typedef unsigned short ushort_t;
typedef __bf16 bf16x8 __attribute__((ext_vector_type(8)));
typedef float f32x4 __attribute__((ext_vector_type(4)));

// ---------- helpers ----------
__device__ __forceinline__ ushort_t f2bf(float f) {
  union { float f; unsigned int u; } v; v.f = f;
  unsigned int u = v.u;
  unsigned int r = (u + 0x7fffu + ((u >> 16) & 1u)) >> 16;
  return (ushort_t)r;
}
__device__ __forceinline__ float bf2f(ushort_t u) {
  union { unsigned int u; float f; } v; v.u = ((unsigned int)u) << 16; return v.f;
}

#define GLOAD16(gp, lp)                                                              \
  __builtin_amdgcn_global_load_lds(                                                  \
      reinterpret_cast<const __attribute__((address_space(1))) unsigned int*>(       \
          reinterpret_cast<uintptr_t>(gp)),                                          \
      reinterpret_cast<__attribute__((address_space(3))) unsigned int*>(             \
          reinterpret_cast<uintptr_t>(lp)),                                          \
      16, 0, 0)

// ---------- GEMM: C[M,N] = A[M,K] @ B[N,K]^T, bf16 in, f32 acc ----------
// 2-phase double-buffered K-loop: stage(t+1) issued BEFORE compute(t); single
// barrier per iter after MFMA (drains next-tile loads that overlapped compute).
// EPI: 0 = outf = acc + bias                     (out)
//      8 = outb = bf16(acc + bias)               (logits)
//      1 = outb = bf16(acc+bias); outb2 = bf16(relu^2)    (H1b + H2b)
//      2 = outb = bf16(acc * 2*sqrt(auxb))       (g1)
//      4 = outb = bf16(relu(bf2f(auxb) - ss0*acc)^2); K-limit  (x2)
//      5 = outf = auxf - ss2*acc; K-limit        (x3)
//      6 = split-K partial, full-matrix f32      (H3, G4, X3 stage 1)
//      7 = split-K partial, tri-skip, compact-tile f32    (S1, S2 stage 1)
struct GemmP {
  const ushort_t* A; const ushort_t* B;
  int M, N, K;
  long long sA, sB;
  float* outf;   long long sOutF;
  ushort_t* outb; long long sOutB;
  ushort_t* outb2;
  const float* bias;
  const float* auxf; long long sAuxF;   // sAuxF doubles as aux (f32 or bf16) stride
  const ushort_t* auxb;
  const float* steps;
  float* part; int ksplit, Kc, Tt;
};

template <int EPI>
__global__ __launch_bounds__(256) void gemm_bt(GemmP p) {
  // T1: bijective XCD swizzle (m204) over the xy tile plane.
  const int nwg = gridDim.x * gridDim.y;
  const int orig = blockIdx.y * gridDim.x + blockIdx.x;
  const int xcd = orig & 7, loc = orig >> 3;
  const int q = nwg >> 3, r = nwg & 7;
  const int wg = (xcd < r) ? (xcd * (q + 1) + loc) : (r * (q + 1) + (xcd - r) * q + loc);
  const int nt = wg % gridDim.x, mt = wg / gridDim.x;
  const int m0 = mt * 128, n0 = nt * 128;
  if (EPI == 7 && n0 > m0) return;

  int bz = blockIdx.z, ks = 0;
  if (EPI == 6 || EPI == 7) { bz = blockIdx.z / p.ksplit; ks = blockIdx.z % p.ksplit; }

  const ushort_t* A = p.A + (size_t)bz * p.sA;
  const ushort_t* B = p.B + (size_t)bz * p.sB;

  int kbeg = 0, kend = p.K;
  if (EPI == 6 || EPI == 7) { kbeg = ks * p.Kc; kend = kbeg + p.Kc; }
  else if (EPI == 4 || EPI == 5) kend = min(p.K, m0 + 128);

  __shared__ ushort_t sA[2 * 128 * 32];
  __shared__ ushort_t sB[2 * 128 * 32];

  const int tid = threadIdx.x;
  const int wid = tid >> 6, lane = tid & 63;
  const int wm = wid >> 1, wn = wid & 1;

  f32x4 acc[4][4];
#pragma unroll
  for (int i = 0; i < 4; i++)
#pragma unroll
    for (int j = 0; j < 4; j++) acc[i][j] = f32x4{0.f, 0.f, 0.f, 0.f};

  const int lr = lane >> 2;
  const int lc = (lane & 3) * 8;
  const int rA0 = wid * 16 + lr;
  const int rA1 = 64 + wid * 16 + lr;
  const ushort_t* gA0 = A + (size_t)(m0 + rA0) * p.K + lc;
  const ushort_t* gA1 = A + (size_t)(m0 + rA1) * p.K + lc;
  const ushort_t* gB0 = B + (size_t)(n0 + rA0) * p.K + lc;
  const ushort_t* gB1 = B + (size_t)(n0 + rA1) * p.K + lc;
  ushort_t* lA0 = &sA[wid * 512];
  ushort_t* lA1 = &sA[(4 + wid) * 512];
  ushort_t* lB0 = &sB[wid * 512];
  ushort_t* lB1 = &sB[(4 + wid) * 512];

  const int fr = lane & 15;
  const int kb = (lane >> 4) * 8;

  const int nIter = (kend - kbeg) >> 5;
  // prologue: stage tile 0 into buf 0
  GLOAD16(gA0 + kbeg, lA0);
  GLOAD16(gA1 + kbeg, lA1);
  GLOAD16(gB0 + kbeg, lB0);
  GLOAD16(gB1 + kbeg, lB1);
  __syncthreads();

  int cur = 0;
  for (int t = 0; t < nIter; ++t) {
    if (t + 1 < nIter) {                 // issue next-tile loads BEFORE compute
      const int kn = kbeg + (t + 1) * 32;
      const int o = (cur ^ 1) * 4096;
      GLOAD16(gA0 + kn, lA0 + o);
      GLOAD16(gA1 + kn, lA1 + o);
      GLOAD16(gB0 + kn, lB0 + o);
      GLOAD16(gB1 + kn, lB1 + o);
    }
    const int co = cur * 4096;
    bf16x8 av[4], bv[4];
#pragma unroll
    for (int i = 0; i < 4; i++) {
      av[i] = *reinterpret_cast<const bf16x8*>(&sA[co + (wm * 64 + i * 16 + fr) * 32 + kb]);
      bv[i] = *reinterpret_cast<const bf16x8*>(&sB[co + (wn * 64 + i * 16 + fr) * 32 + kb]);
    }
#pragma unroll
    for (int i = 0; i < 4; i++)
#pragma unroll
      for (int j = 0; j < 4; j++)
        acc[i][j] = __builtin_amdgcn_mfma_f32_16x16x32_bf16(av[i], bv[j], acc[i][j], 0, 0, 0);
    __syncthreads();   // drains next-tile loads (overlapped MFMA) + releases cur buf
    cur ^= 1;
  }

  const int fq = lane >> 4;
  float ss = 0.f;
  if (EPI == 4) ss = p.steps[0];
  else if (EPI == 5) ss = p.steps[2];
  float* outf = p.outf ? p.outf + (size_t)bz * p.sOutF : nullptr;
  ushort_t* outb = p.outb ? p.outb + (size_t)bz * p.sOutB : nullptr;
  ushort_t* outb2 = p.outb2;
  const float* auxf = p.auxf ? p.auxf + (size_t)bz * p.sAuxF : nullptr;
  const ushort_t* auxb = p.auxb ? p.auxb + (size_t)bz * p.sAuxF : nullptr;
  float* partT = nullptr;
  if (EPI == 6) partT = p.part + (size_t)blockIdx.z * p.M * p.N;
  if (EPI == 7) partT = p.part + ((size_t)blockIdx.z * p.Tt + (size_t)mt * (mt + 1) / 2 + nt) * 16384;

#pragma unroll
  for (int i = 0; i < 4; i++) {
#pragma unroll
    for (int j = 0; j < 4; j++) {
#pragma unroll
      for (int r2 = 0; r2 < 4; r2++) {
        int lrow = wm * 64 + i * 16 + fq * 4 + r2;
        int lcol = wn * 64 + j * 16 + fr;
        int row = m0 + lrow, col = n0 + lcol;
        size_t g = (size_t)row * p.N + col;
        float v = acc[i][j][r2];
        if (EPI == 0) {
          outf[g] = v + (p.bias ? p.bias[col] : 0.f);
        } else if (EPI == 8) {
          outb[g] = f2bf(v + p.bias[col]);
        } else if (EPI == 1) {
          v += p.bias[col];
          outb[g] = f2bf(v);
          float rl = fmaxf(v, 0.f);
          outb2[g] = f2bf(rl * rl);
        } else if (EPI == 2) {
          outb[g] = f2bf(v * 2.f * sqrtf(bf2f(p.auxb[g])));
        } else if (EPI == 4) {
          float x1 = bf2f(auxb[g]) - ss * v;
          float rl = fmaxf(x1, 0.f);
          outb[g] = f2bf(rl * rl);
        } else if (EPI == 5) {
          outf[g] = auxf[g] - ss * v;
        } else if (EPI == 6) {
          partT[g] = v;
        } else if (EPI == 7) {
          partT[lrow * 128 + lcol] = v;
        }
      }
    }
  }
}

// ---------- split-K combines ----------
__global__ __launch_bounds__(256) void k_comb(const float* part, const float* bias, float* out,
                                              int N, size_t MN, int S) {
  size_t e = ((size_t)blockIdx.x * 256 + threadIdx.x) * 4;
  if (e >= MN) return;
  float4 s = *(const float4*)(part + e);
  for (int p_ = 1; p_ < S; p_++) {
    float4 v = *(const float4*)(part + (size_t)p_ * MN + e);
    s.x += v.x; s.y += v.y; s.z += v.z; s.w += v.w;
  }
  if (bias) {
    int col = (int)(e % (size_t)N);
    s.x += bias[col]; s.y += bias[col + 1]; s.z += bias[col + 2]; s.w += bias[col + 3];
  }
  *(float4*)(out + e) = s;
}

__global__ __launch_bounds__(256) void k_combtri(const float* part, ushort_t* out, int Tt, int S,
                                                 int L) {
  int t = blockIdx.x, bz = blockIdx.y;
  int mt = (int)((sqrtf(8.f * t + 1.f) - 1.f) * 0.5f);
  while ((mt + 1) * (mt + 2) / 2 <= t) mt++;
  while (mt * (mt + 1) / 2 > t) mt--;
  int nt = t - mt * (mt + 1) / 2;
  const float* pb = part + ((size_t)bz * S * Tt + t) * 16384;
  ushort_t* ob = out + (size_t)bz * L * L;
  for (int e4 = threadIdx.x; e4 < 4096; e4 += 256) {
    int e = e4 * 4;
    float4 s = *(const float4*)(pb + e);
    for (int p_ = 1; p_ < S; p_++) {
      float4 v = *(const float4*)(pb + (size_t)p_ * Tt * 16384 + e);
      s.x += v.x; s.y += v.y; s.z += v.z; s.w += v.w;
    }
    int lr = e >> 7, lc2 = e & 127;
    int row = mt * 128 + lr, col = nt * 128 + lc2;
    ushort4 o;
    o.x = (col < row) ? f2bf(s.x) : (ushort_t)0;
    o.y = (col + 1 < row) ? f2bf(s.y) : (ushort_t)0;
    o.z = (col + 2 < row) ? f2bf(s.z) : (ushort_t)0;
    o.w = (col + 3 < row) ? f2bf(s.w) : (ushort_t)0;
    *(ushort4*)(&ob[(size_t)row * L + col]) = o;
  }
}

// ---------- auxiliary kernels ----------
__global__ __launch_bounds__(256) void k_conv(const float* in, ushort_t* out, size_t n) {
  size_t i = ((size_t)blockIdx.x * 256 + threadIdx.x) * 4;
  if (i >= n) return;
  float4 v = *(const float4*)(in + i);
  out[i] = f2bf(v.x); out[i + 1] = f2bf(v.y); out[i + 2] = f2bf(v.z); out[i + 3] = f2bf(v.w);
}

__global__ __launch_bounds__(256) void k_tconv(const float* in, ushort_t* out, int R, int C) {
  __shared__ float t[32][33];
  int c0 = blockIdx.x * 32, r0 = blockIdx.y * 32;
  int tx = threadIdx.x & 31, ty = threadIdx.x >> 5;
#pragma unroll
  for (int i = ty; i < 32; i += 8) t[i][tx] = in[(size_t)(r0 + i) * C + c0 + tx];
  __syncthreads();
#pragma unroll
  for (int i = ty; i < 32; i += 8) out[(size_t)(c0 + i) * R + r0 + tx] = f2bf(t[tx][i]);
}

__global__ __launch_bounds__(256) void k_tb2b(const ushort_t* in, ushort_t* out, int L, int C) {
  __shared__ ushort_t t[32][33];
  int b = blockIdx.z;
  const ushort_t* ib = in + (size_t)b * L * C;
  ushort_t* ob = out + (size_t)b * C * L;
  int c0 = blockIdx.x * 32, l0 = blockIdx.y * 32;
  int tx = threadIdx.x & 31, ty = threadIdx.x >> 5;
#pragma unroll
  for (int i = ty; i < 32; i += 8) t[i][tx] = ib[(size_t)(l0 + i) * C + c0 + tx];
  __syncthreads();
#pragma unroll
  for (int i = ty; i < 32; i += 8) ob[(size_t)(c0 + i) * L + l0 + tx] = t[tx][i];
}

__device__ __forceinline__ void blockRed2(float& a, float& b, float* red) {
#pragma unroll
  for (int o = 32; o; o >>= 1) { a += __shfl_down(a, o); b += __shfl_down(b, o); }
  int w = threadIdx.x >> 6;
  if ((threadIdx.x & 63) == 0) { red[w] = a; red[4 + w] = b; }
  __syncthreads();
  a = red[0] + red[1] + red[2] + red[3];
  b = red[4] + red[5] + red[6] + red[7];
  __syncthreads();
}

__global__ __launch_bounds__(256) void k_lnfwd(const float* X, const float* sc, const float* bi,
                                               float* nout, float* rstd, ushort_t* yb, int D) {
  __shared__ float red[8];
  int row = blockIdx.x;
  const float* x = X + (size_t)row * D;
  float s = 0.f, s2 = 0.f;
  for (int d = threadIdx.x; d < D; d += 256) { float v = x[d]; s += v; s2 += v * v; }
  blockRed2(s, s2, red);
  float mu = s / D;
  float var = s2 / D - mu * mu;
  float rs = rsqrtf(var + 1e-6f);
  for (int d = threadIdx.x; d < D; d += 256) {
    float nv = (x[d] - mu) * rs;
    nout[(size_t)row * D + d] = nv;
    yb[(size_t)row * D + d] = f2bf(nv * sc[d] + bi[d]);
  }
  if (threadIdx.x == 0) rstd[row] = rs;
}

__global__ __launch_bounds__(256) void k_lnfwd2(const float* X, const float* fs, const float* fb,
                                                ushort_t* yb, int D) {
  __shared__ float red[8];
  int row = blockIdx.x;
  const float* x = X + (size_t)row * D;
  float s = 0.f, s2 = 0.f;
  for (int d = threadIdx.x; d < D; d += 256) { float v = x[d]; s += v; s2 += v * v; }
  blockRed2(s, s2, red);
  float mu = s / D;
  float var = s2 / D - mu * mu;
  float rs = rsqrtf(var + 1e-6f);
  for (int d = threadIdx.x; d < D; d += 256) {
    size_t g = (size_t)row * D + d;
    float nv = (x[d] - mu) * rs;
    yb[g] = f2bf(nv * fs[g] + fb[g]);
  }
}

__global__ __launch_bounds__(256) void k_lnbwd(const float* G, const float* nn, const float* rstd,
                                               const float* sc, ushort_t* g3b, float* gsc, int D) {
  __shared__ float red[8];
  int row = blockIdx.x;
  const float* g = G + (size_t)row * D;
  const float* n_ = nn + (size_t)row * D;
  float sa = 0.f, sb = 0.f;
  for (int d = threadIdx.x; d < D; d += 256) {
    float dn = g[d] * sc[d];
    sa += dn; sb += dn * n_[d];
  }
  blockRed2(sa, sb, red);
  float a = sa / D, b = sb / D, rs = rstd[row];
  for (int d = threadIdx.x; d < D; d += 256) {
    size_t gi = (size_t)row * D + d;
    float dn = g[d] * sc[d];
    g3b[gi] = f2bf(rs * (dn - a - n_[d] * b));
    gsc[gi] = g[d] * n_[d];
  }
}

__global__ __launch_bounds__(256) void k_wsum(const float* w, float* o, int n) {
  __shared__ float red[4];
  float s = 0.f;
  for (int i = threadIdx.x; i < n; i += 256) s += w[i];
#pragma unroll
  for (int d = 32; d; d >>= 1) s += __shfl_down(s, d);
  if ((threadIdx.x & 63) == 0) red[threadIdx.x >> 6] = s;
  __syncthreads();
  if (threadIdx.x == 0) o[0] = fmaxf(red[0] + red[1] + red[2] + red[3], 1e-8f);
}

// fused softmax-grad over bf16 logits
__global__ __launch_bounds__(256) void k_softgrad(const ushort_t* logits, const float* labels,
                                                  const float* w, const float* wsum,
                                                  ushort_t* dlb, int V) {
  __shared__ float lrow[8192];
  __shared__ float red[8];
  int row = blockIdx.x;
  const ushort_t* l = logits + (size_t)row * V;
  const float* y = labels + (size_t)row * V;
  float m = -3.4e38f, t = 0.f;
  for (int v = threadIdx.x; v < V; v += 256) {
    float lv = bf2f(l[v]);
    lrow[v] = lv;
    m = fmaxf(m, lv);
    t += y[v];
  }
#pragma unroll
  for (int o = 32; o; o >>= 1) { m = fmaxf(m, __shfl_down(m, o)); t += __shfl_down(t, o); }
  int wv = threadIdx.x >> 6;
  if ((threadIdx.x & 63) == 0) { red[wv] = m; red[4 + wv] = t; }
  __syncthreads();
  m = fmaxf(fmaxf(red[0], red[1]), fmaxf(red[2], red[3]));
  t = red[4] + red[5] + red[6] + red[7];
  __syncthreads();
  float s = 0.f;
  for (int v = threadIdx.x; v < V; v += 256) s += expf(lrow[v] - m);
#pragma unroll
  for (int o = 32; o; o >>= 1) s += __shfl_down(s, o);
  if ((threadIdx.x & 63) == 0) red[wv] = s;
  __syncthreads();
  s = red[0] + red[1] + red[2] + red[3];
  float c = w[row] / wsum[0];
  float invs = 1.f / s;
  for (int v = threadIdx.x; v < V; v += 256) {
    size_t g = (size_t)row * V + v;
    dlb[g] = f2bf(c * (expf(lrow[v] - m) * invs * t - y[v]));
  }
}

__global__ __launch_bounds__(256) void k_scanpart(const float* gs, const float* gb, float* ps,
                                                  float* pb, int L, int D) {
  int d = blockIdx.x * 256 + threadIdx.x;
  int seg = blockIdx.y, b = blockIdx.z;
  const int SEGL = L / 16;
  size_t base = ((size_t)b * L + seg * SEGL) * D + d;
  float s1 = 0.f, s2 = 0.f;
  for (int i = 0; i < SEGL; i++) { s1 += gs[base + (size_t)i * D]; s2 += gb[base + (size_t)i * D]; }
  size_t pi = ((size_t)b * 16 + seg) * D + d;
  ps[pi] = s1; pb[pi] = s2;
}

__global__ __launch_bounds__(256) void k_scanapply(const float* gs, const float* gb,
                                                   const float* ps, const float* pb,
                                                   const float* sc, const float* bi,
                                                   const float* steps, float* fs, float* fb,
                                                   int L, int D) {
  int d = blockIdx.x * 256 + threadIdx.x;
  int seg = blockIdx.y, b = blockIdx.z;
  const int SEGL = L / 16;
  float ss = steps[3];
  float rs_ = 0.f, rb_ = 0.f;
  for (int s = 0; s < seg; s++) {
    size_t pi = ((size_t)b * 16 + s) * D + d;
    rs_ += ps[pi]; rb_ += pb[pi];
  }
  float s0 = sc[d], b0 = bi[d];
  size_t base = ((size_t)b * L + seg * SEGL) * D + d;
  for (int i = 0; i < SEGL; i++) {
    size_t g = base + (size_t)i * D;
    fs[g] = s0 - ss * rs_;
    fb[g] = b0 - ss * rb_;
    rs_ += gs[g]; rb_ += gb[g];
  }
}

// ---------- orchestration ----------
extern "C" void kernel_launch(void* const* d_in, const int* in_sizes, int n_in, void* d_out,
                              int out_size, void* d_ws, size_t ws_size, hipStream_t stream) {
  const float* x        = (const float*)d_in[0];
  const float* labels   = (const float*)d_in[1];
  const float* weights  = (const float*)d_in[2];
  const float* W1       = (const float*)d_in[3];
  const float* b1       = (const float*)d_in[4];
  const float* W2       = (const float*)d_in[5];
  const float* b2       = (const float*)d_in[6];
  const float* ln_scale = (const float*)d_in[7];
  const float* ln_bias  = (const float*)d_in[8];
  const float* Wu       = (const float*)d_in[9];
  const float* bu       = (const float*)d_in[10];
  const float* steps    = (const float*)d_in[11];

  const int BL = in_sizes[2];   // 4096
  const int D  = in_sizes[7];   // 1024
  const int F  = in_sizes[4];   // 4096
  const int V  = in_sizes[10];  // 8192
  const int Bb = 2, L = BL / Bb;
  const int Tt = (L / 128) * (L / 128 + 1) / 2;

  char* ws = (char*)d_ws;
  size_t off = 0;
  auto take = [&](size_t b) { char* p = ws + off; off = (off + b + 255) & ~(size_t)255; return p; };

  ushort_t* xb   = (ushort_t*)take((size_t)BL * D * 2);
  ushort_t* w1t  = (ushort_t*)take((size_t)F * D * 2);
  ushort_t* w2t  = (ushort_t*)take((size_t)D * F * 2);
  ushort_t* w2b  = (ushort_t*)take((size_t)F * D * 2);
  ushort_t* wut  = (ushort_t*)take((size_t)V * D * 2);
  ushort_t* wub  = (ushort_t*)take((size_t)D * V * 2);
  ushort_t* H1b  = (ushort_t*)take((size_t)BL * F * 2);
  ushort_t* H2b  = (ushort_t*)take((size_t)BL * F * 2);
  float*    H3   = (float*)take((size_t)BL * D * 4);
  float*    nbuf = (float*)take((size_t)BL * D * 4);
  float*    rstd = (float*)take((size_t)BL * 4);
  ushort_t* h4b  = (ushort_t*)take((size_t)BL * D * 2);
  float*    wsumb= (float*)take(256);
  float*    G4   = (float*)take((size_t)BL * D * 4);   // also g_bias
  float*    gsc  = (float*)take((size_t)BL * D * 4);   // g_scale
  ushort_t* g3b  = (ushort_t*)take((size_t)BL * D * 2);
  ushort_t* g3t  = (ushort_t*)take((size_t)BL * D * 2);
  float*    fs   = (float*)take((size_t)BL * D * 4);
  float*    fb   = (float*)take((size_t)BL * D * 4);
  ushort_t* x4b  = (ushort_t*)take((size_t)BL * D * 2);
  float*    psc  = (float*)take((size_t)Bb * 16 * D * 4);
  float*    pbi  = (float*)take((size_t)Bb * 16 * D * 4);
  // poolA (134MB): split-K partials (up to 64MB) / logitsb bf16 (64MB) ->
  // later {g1b, g1t, S1b, x2b}
  char* poolA = take((size_t)BL * V * 4);
  ushort_t* logitsb = (ushort_t*)poolA;
  float*    partA  = (float*)poolA;
  ushort_t* g1b = (ushort_t*)poolA;
  ushort_t* g1t = (ushort_t*)(poolA + (size_t)BL * F * 2);
  ushort_t* S1b = (ushort_t*)(poolA + (size_t)BL * F * 4);
  ushort_t* x2b = (ushort_t*)(poolA + (size_t)BL * F * 4 + (size_t)Bb * L * L * 2);
  // poolB (64MB): dlb bf16 -> later {S2b, X3, x3}; head also hosts S1 partials
  char* poolB = take((size_t)BL * V * 2);
  ushort_t* dlb = (ushort_t*)poolB;
  float*    partS1 = (float*)poolB;
  ushort_t* S2b = (ushort_t*)poolB;
  float*    X3  = (float*)(poolB + (size_t)Bb * L * L * 2);
  float*    x3  = (float*)(poolB + (size_t)Bb * L * L * 2 + (size_t)BL * D * 4);

  dim3 blk(256);
  const size_t MN_D = (size_t)BL * D;

  k_conv<<<dim3((unsigned)((size_t)BL * D / 1024)), blk, 0, stream>>>(x, xb, (size_t)BL * D);
  k_tconv<<<dim3(F / 32, D / 32), blk, 0, stream>>>(W1, w1t, D, F);
  k_tconv<<<dim3(D / 32, F / 32), blk, 0, stream>>>(W2, w2t, F, D);
  k_conv<<<dim3((unsigned)((size_t)F * D / 1024)), blk, 0, stream>>>(W2, w2b, (size_t)F * D);
  k_tconv<<<dim3(V / 32, D / 32), blk, 0, stream>>>(Wu, wut, D, V);
  k_conv<<<dim3((unsigned)((size_t)D * V / 1024)), blk, 0, stream>>>(Wu, wub, (size_t)D * V);

  GemmP p;
  auto clr = [&]() { p = GemmP{}; };

  // 1) H1b = bf16(x@W1+b1) ; H2b = bf16(relu^2)
  clr(); p.A = xb; p.B = w1t; p.M = BL; p.N = F; p.K = D;
  p.outb = H1b; p.outb2 = H2b; p.bias = b1;
  gemm_bt<1><<<dim3(F / 128, BL / 128, 1), blk, 0, stream>>>(p);
  // 2) H3 = H2@W2 + b2   [split-K 4]
  clr(); p.A = H2b; p.B = w2t; p.M = BL; p.N = D; p.K = F;
  p.part = partA; p.ksplit = 4; p.Kc = F / 4;
  gemm_bt<6><<<dim3(D / 128, BL / 128, 4), blk, 0, stream>>>(p);
  k_comb<<<dim3((unsigned)(MN_D / 1024)), blk, 0, stream>>>(partA, b2, H3, D, MN_D, 4);
  // 3) LN fwd
  k_lnfwd<<<dim3(BL), blk, 0, stream>>>(H3, ln_scale, ln_bias, nbuf, rstd, h4b, D);
  // 4) logits = bf16(h4@Wu + bu)
  clr(); p.A = h4b; p.B = wut; p.M = BL; p.N = V; p.K = D; p.outb = logitsb; p.bias = bu;
  gemm_bt<8><<<dim3(V / 128, BL / 128, 1), blk, 0, stream>>>(p);
  // 5) fused softmax grad
  k_wsum<<<dim3(1), blk, 0, stream>>>(weights, wsumb, BL);
  k_softgrad<<<dim3(BL), blk, 0, stream>>>(logitsb, labels, weights, wsumb, dlb, V);
  // 6) G4 = dlogits @ Wu^T   [split-K 4]
  clr(); p.A = dlb; p.B = wub; p.M = BL; p.N = D; p.K = V;
  p.part = partA; p.ksplit = 4; p.Kc = V / 4;
  gemm_bt<6><<<dim3(D / 128, BL / 128, 4), blk, 0, stream>>>(p);
  k_comb<<<dim3((unsigned)(MN_D / 1024)), blk, 0, stream>>>(partA, nullptr, G4, D, MN_D, 4);
  // 7) LN bwd -> g3, g_scale
  k_lnbwd<<<dim3(BL), blk, 0, stream>>>(G4, nbuf, rstd, ln_scale, g3b, gsc, D);
  // 8) g1 = (g3 @ W2^T) * 2*sqrt(H2)
  clr(); p.A = g3b; p.B = w2b; p.M = BL; p.N = F; p.K = D; p.outb = g1b; p.auxb = H2b;
  gemm_bt<2><<<dim3(F / 128, BL / 128, 1), blk, 0, stream>>>(p);
  // 9) transposes for attention V-operands
  k_tb2b<<<dim3(F / 32, L / 32, Bb), blk, 0, stream>>>(g1b, g1t, L, F);
  k_tb2b<<<dim3(D / 32, L / 32, Bb), blk, 0, stream>>>(g3b, g3t, L, D);
  // 10) S1 = tril(x x^T, -1)   [split-K 2]
  clr(); p.A = xb; p.B = xb; p.M = L; p.N = L; p.K = D;
  p.sA = (long long)L * D; p.sB = (long long)L * D;
  p.part = partS1; p.ksplit = 2; p.Kc = D / 2; p.Tt = Tt;
  gemm_bt<7><<<dim3(L / 128, L / 128, Bb * 2), blk, 0, stream>>>(p);
  k_combtri<<<dim3(Tt, Bb), blk, 0, stream>>>(partS1, S1b, Tt, 2, L);
  // 11) x2 = relu(H1 - ss0 * S1@g1)^2   [K-limited, aux = bf16 H1b]
  clr(); p.A = S1b; p.B = g1t; p.M = L; p.N = F; p.K = L;
  p.sA = (long long)L * L; p.sB = (long long)F * L;
  p.outb = x2b; p.sOutB = (long long)L * F; p.auxb = H1b; p.sAuxF = (long long)L * F;
  p.steps = steps;
  gemm_bt<4><<<dim3(F / 128, L / 128, Bb), blk, 0, stream>>>(p);
  // 12) X3 = x2@W2 + b2   [split-K 4]
  clr(); p.A = x2b; p.B = w2t; p.M = BL; p.N = D; p.K = F;
  p.part = partA; p.ksplit = 4; p.Kc = F / 4;
  gemm_bt<6><<<dim3(D / 128, BL / 128, 4), blk, 0, stream>>>(p);
  k_comb<<<dim3((unsigned)(MN_D / 1024)), blk, 0, stream>>>(partA, b2, X3, D, MN_D, 4);
  // 13) S2 = tril(x2 H2^T, -1)   [split-K 2]
  clr(); p.A = x2b; p.B = H2b; p.M = L; p.N = L; p.K = F;
  p.sA = (long long)L * F; p.sB = (long long)L * F;
  p.part = partA; p.ksplit = 2; p.Kc = F / 2; p.Tt = Tt;
  gemm_bt<7><<<dim3(L / 128, L / 128, Bb * 2), blk, 0, stream>>>(p);
  k_combtri<<<dim3(Tt, Bb), blk, 0, stream>>>(partA, S2b, Tt, 2, L);
  // 14) x3 = X3 - ss2 * S2@g3   [K-limited]
  clr(); p.A = S2b; p.B = g3t; p.M = L; p.N = D; p.K = L;
  p.sA = (long long)L * L; p.sB = (long long)D * L;
  p.outf = x3; p.sOutF = (long long)L * D; p.auxf = X3; p.sAuxF = (long long)L * D; p.steps = steps;
  gemm_bt<5><<<dim3(D / 128, L / 128, Bb), blk, 0, stream>>>(p);
  // 15) exclusive cumsums -> fast_scale / fast_bias
  k_scanpart<<<dim3(D / 256, 16, Bb), blk, 0, stream>>>(gsc, G4, psc, pbi, L, D);
  k_scanapply<<<dim3(D / 256, 16, Bb), blk, 0, stream>>>(gsc, G4, psc, pbi, ln_scale, ln_bias,
                                                         steps, fs, fb, L, D);
  // 16) x4 = LN(x3)*fast_scale + fast_bias
  k_lnfwd2<<<dim3(BL), blk, 0, stream>>>(x3, fs, fb, x4b, D);
  // 17) out = x4@Wu + bu
  clr(); p.A = x4b; p.B = wut; p.M = BL; p.N = V; p.K = D; p.outf = (float*)d_out; p.bias = bu;
  gemm_bt<0><<<dim3(V / 128, BL / 128, 1), blk, 0, stream>>>(p);
}

// Round 4
// 1187.994 us; speedup vs baseline: 1.3284x; 1.0747x over previous
//
#include <hip/hip_runtime.h>
#include <cstdint>

typedef unsigned short ushort_t;
typedef __bf16 bf16x8 __attribute__((ext_vector_type(8)));
typedef float f32x4 __attribute__((ext_vector_type(4)));

// ---------- helpers ----------
__device__ __forceinline__ ushort_t f2bf(float f) {
  union { float f; unsigned int u; } v; v.f = f;
  unsigned int u = v.u;
  unsigned int r = (u + 0x7fffu + ((u >> 16) & 1u)) >> 16;
  return (ushort_t)r;
}
__device__ __forceinline__ float bf2f(ushort_t u) {
  union { unsigned int u; float f; } v; v.u = ((unsigned int)u) << 16; return v.f;
}

#define GLOAD16(gp, lp)                                                              \
  __builtin_amdgcn_global_load_lds(                                                  \
      reinterpret_cast<const __attribute__((address_space(1))) unsigned int*>(       \
          reinterpret_cast<uintptr_t>(gp)),                                          \
      reinterpret_cast<__attribute__((address_space(3))) unsigned int*>(             \
          reinterpret_cast<uintptr_t>(lp)),                                          \
      16, 0, 0)

// ---------- GEMM: C[M,N] = A[M,K] @ B[N,K]^T, bf16 in, f32 acc ----------
// Distance-2 software pipeline (T3/T4 minimum): 3 LDS buffers; per iter
//   waitcnt vmcnt(4)  -> own tile-t loads resident
//   s_barrier         -> all waves' tile-t resident; buf[(t+2)%3] reusable
//   stage(t+2)        -> loads stay in flight ACROSS barriers (never drain)
//   ds_read(t); MFMA
// EPI: 0 = outf = acc + bias                     (out)
//      8 = outb = bf16(acc + bias)               (logits)
//      1 = outb = bf16(acc+bias); outb2 = bf16(relu^2)    (H1b + H2b)
//      2 = outb = bf16(acc * 2*sqrt(auxb))       (g1)
//      4 = outb = bf16(relu(bf2f(auxb) - ss0*acc)^2); K-limit  (x2)
//      5 = outf = auxf - ss2*acc; K-limit        (x3)
//      6 = split-K partial, full-matrix f32      (H3, G4, X3 stage 1)
//      7 = split-K partial, compact-tri grid+tiles f32    (S1, S2 stage 1)
struct GemmP {
  const ushort_t* A; const ushort_t* B;
  int M, N, K;
  long long sA, sB;
  float* outf;   long long sOutF;
  ushort_t* outb; long long sOutB;
  ushort_t* outb2;
  const float* bias;
  const float* auxf; long long sAuxF;   // sAuxF doubles as aux (f32 or bf16) stride
  const ushort_t* auxb;
  const float* steps;
  float* part; int ksplit, Kc, Tt;
};

template <int EPI>
__global__ __launch_bounds__(256) void gemm_bt(GemmP p) {
  // T1: bijective XCD swizzle (m204); consecutive same-XCD wg share the A panel.
  const int nwg = gridDim.x * gridDim.y;
  const int orig = blockIdx.y * gridDim.x + blockIdx.x;
  const int xcd = orig & 7, loc = orig >> 3;
  const int q = nwg >> 3, r = nwg & 7;
  const int wg = (xcd < r) ? (xcd * (q + 1) + loc) : (r * (q + 1) + (xcd - r) * q + loc);
  int mt, nt;
  if (EPI == 7) {           // compact lower-tri tile index -> (mt, nt)
    int t_ = wg;
    mt = (int)((sqrtf(8.f * t_ + 1.f) - 1.f) * 0.5f);
    while ((mt + 1) * (mt + 2) / 2 <= t_) mt++;
    while (mt * (mt + 1) / 2 > t_) mt--;
    nt = t_ - mt * (mt + 1) / 2;
  } else {
    nt = wg % gridDim.x; mt = wg / gridDim.x;
  }
  const int m0 = mt * 128, n0 = nt * 128;

  int bz = blockIdx.z, ks = 0;
  if (EPI == 6 || EPI == 7) { bz = blockIdx.z / p.ksplit; ks = blockIdx.z % p.ksplit; }

  const ushort_t* A = p.A + (size_t)bz * p.sA;
  const ushort_t* B = p.B + (size_t)bz * p.sB;

  int kbeg = 0, kend = p.K;
  if (EPI == 6 || EPI == 7) { kbeg = ks * p.Kc; kend = kbeg + p.Kc; }
  else if (EPI == 4 || EPI == 5) kend = min(p.K, m0 + 128);

  __shared__ ushort_t sA[3 * 128 * 32];
  __shared__ ushort_t sB[3 * 128 * 32];

  const int tid = threadIdx.x;
  const int wid = tid >> 6, lane = tid & 63;
  const int wm = wid >> 1, wn = wid & 1;

  f32x4 acc[4][4];
#pragma unroll
  for (int i = 0; i < 4; i++)
#pragma unroll
    for (int j = 0; j < 4; j++) acc[i][j] = f32x4{0.f, 0.f, 0.f, 0.f};

  const int lr = lane >> 2;
  const int lc = (lane & 3) * 8;
  const int rA0 = wid * 16 + lr;
  const int rA1 = 64 + wid * 16 + lr;
  const ushort_t* gA0 = A + (size_t)(m0 + rA0) * p.K + lc;
  const ushort_t* gA1 = A + (size_t)(m0 + rA1) * p.K + lc;
  const ushort_t* gB0 = B + (size_t)(n0 + rA0) * p.K + lc;
  const ushort_t* gB1 = B + (size_t)(n0 + rA1) * p.K + lc;
  ushort_t* lA0 = &sA[wid * 512];
  ushort_t* lA1 = &sA[(4 + wid) * 512];
  ushort_t* lB0 = &sB[wid * 512];
  ushort_t* lB1 = &sB[(4 + wid) * 512];

  const int fr = lane & 15;
  const int kb = (lane >> 4) * 8;

  const int nIter = (kend - kbeg) >> 5;
  auto stage = [&](int t, int buf) {
    const int kk = kbeg + t * 32;
    const int o = buf * 4096;
    GLOAD16(gA0 + kk, lA0 + o);
    GLOAD16(gA1 + kk, lA1 + o);
    GLOAD16(gB0 + kk, lB0 + o);
    GLOAD16(gB1 + kk, lB1 + o);
  };
  stage(0, 0);
  if (nIter > 1) stage(1, 1);

  for (int t = 0; t < nIter; ++t) {
    if (t + 1 < nIter) { asm volatile("s_waitcnt vmcnt(4)" ::: "memory"); }
    else               { asm volatile("s_waitcnt vmcnt(0)" ::: "memory"); }
    __builtin_amdgcn_s_barrier();
    __builtin_amdgcn_sched_barrier(0);     // keep stage/ds_read after the barrier
    if (t + 2 < nIter) stage(t + 2, (t + 2) % 3);
    const int co = (t % 3) * 4096;
    bf16x8 av[4], bv[4];
#pragma unroll
    for (int i = 0; i < 4; i++) {
      av[i] = *reinterpret_cast<const bf16x8*>(&sA[co + (wm * 64 + i * 16 + fr) * 32 + kb]);
      bv[i] = *reinterpret_cast<const bf16x8*>(&sB[co + (wn * 64 + i * 16 + fr) * 32 + kb]);
    }
#pragma unroll
    for (int i = 0; i < 4; i++)
#pragma unroll
      for (int j = 0; j < 4; j++)
        acc[i][j] = __builtin_amdgcn_mfma_f32_16x16x32_bf16(av[i], bv[j], acc[i][j], 0, 0, 0);
  }

  const int fq = lane >> 4;
  float ss = 0.f;
  if (EPI == 4) ss = p.steps[0];
  else if (EPI == 5) ss = p.steps[2];
  float* outf = p.outf ? p.outf + (size_t)bz * p.sOutF : nullptr;
  ushort_t* outb = p.outb ? p.outb + (size_t)bz * p.sOutB : nullptr;
  ushort_t* outb2 = p.outb2;
  const float* auxf = p.auxf ? p.auxf + (size_t)bz * p.sAuxF : nullptr;
  const ushort_t* auxb = p.auxb ? p.auxb + (size_t)bz * p.sAuxF : nullptr;
  float* partT = nullptr;
  if (EPI == 6) partT = p.part + (size_t)blockIdx.z * p.M * p.N;
  if (EPI == 7) partT = p.part + ((size_t)blockIdx.z * p.Tt + wg) * 16384;

#pragma unroll
  for (int i = 0; i < 4; i++) {
#pragma unroll
    for (int j = 0; j < 4; j++) {
#pragma unroll
      for (int r2 = 0; r2 < 4; r2++) {
        int lrow = wm * 64 + i * 16 + fq * 4 + r2;
        int lcol = wn * 64 + j * 16 + fr;
        int row = m0 + lrow, col = n0 + lcol;
        size_t g = (size_t)row * p.N + col;
        float v = acc[i][j][r2];
        if (EPI == 0) {
          outf[g] = v + (p.bias ? p.bias[col] : 0.f);
        } else if (EPI == 8) {
          outb[g] = f2bf(v + p.bias[col]);
        } else if (EPI == 1) {
          v += p.bias[col];
          outb[g] = f2bf(v);
          float rl = fmaxf(v, 0.f);
          outb2[g] = f2bf(rl * rl);
        } else if (EPI == 2) {
          outb[g] = f2bf(v * 2.f * sqrtf(bf2f(p.auxb[g])));
        } else if (EPI == 4) {
          float x1 = bf2f(auxb[g]) - ss * v;
          float rl = fmaxf(x1, 0.f);
          outb[g] = f2bf(rl * rl);
        } else if (EPI == 5) {
          outf[g] = auxf[g] - ss * v;
        } else if (EPI == 6) {
          partT[g] = v;
        } else if (EPI == 7) {
          partT[lrow * 128 + lcol] = v;
        }
      }
    }
  }
}

// ---------- split-K combines ----------
__global__ __launch_bounds__(256) void k_comb(const float* part, const float* bias, float* out,
                                              int N, size_t MN, int S) {
  size_t e = ((size_t)blockIdx.x * 256 + threadIdx.x) * 4;
  if (e >= MN) return;
  float4 s = *(const float4*)(part + e);
  for (int p_ = 1; p_ < S; p_++) {
    float4 v = *(const float4*)(part + (size_t)p_ * MN + e);
    s.x += v.x; s.y += v.y; s.z += v.z; s.w += v.w;
  }
  if (bias) {
    int col = (int)(e % (size_t)N);
    s.x += bias[col]; s.y += bias[col + 1]; s.z += bias[col + 2]; s.w += bias[col + 3];
  }
  *(float4*)(out + e) = s;
}

__global__ __launch_bounds__(256) void k_combtri(const float* part, ushort_t* out, int Tt, int S,
                                                 int L) {
  int t = blockIdx.x, bz = blockIdx.y;
  int mt = (int)((sqrtf(8.f * t + 1.f) - 1.f) * 0.5f);
  while ((mt + 1) * (mt + 2) / 2 <= t) mt++;
  while (mt * (mt + 1) / 2 > t) mt--;
  int nt = t - mt * (mt + 1) / 2;
  const float* pb = part + ((size_t)bz * S * Tt + t) * 16384;
  ushort_t* ob = out + (size_t)bz * L * L;
  for (int e4 = threadIdx.x; e4 < 4096; e4 += 256) {
    int e = e4 * 4;
    float4 s = *(const float4*)(pb + e);
    for (int p_ = 1; p_ < S; p_++) {
      float4 v = *(const float4*)(pb + (size_t)p_ * Tt * 16384 + e);
      s.x += v.x; s.y += v.y; s.z += v.z; s.w += v.w;
    }
    int lr = e >> 7, lc2 = e & 127;
    int row = mt * 128 + lr, col = nt * 128 + lc2;
    ushort4 o;
    o.x = (col < row) ? f2bf(s.x) : (ushort_t)0;
    o.y = (col + 1 < row) ? f2bf(s.y) : (ushort_t)0;
    o.z = (col + 2 < row) ? f2bf(s.z) : (ushort_t)0;
    o.w = (col + 3 < row) ? f2bf(s.w) : (ushort_t)0;
    *(ushort4*)(&ob[(size_t)row * L + col]) = o;
  }
}

// ---------- auxiliary kernels ----------
__global__ __launch_bounds__(256) void k_conv(const float* in, ushort_t* out, size_t n) {
  size_t i = ((size_t)blockIdx.x * 256 + threadIdx.x) * 4;
  if (i >= n) return;
  float4 v = *(const float4*)(in + i);
  out[i] = f2bf(v.x); out[i + 1] = f2bf(v.y); out[i + 2] = f2bf(v.z); out[i + 3] = f2bf(v.w);
}

__global__ __launch_bounds__(256) void k_tconv(const float* in, ushort_t* out, int R, int C) {
  __shared__ float t[32][33];
  int c0 = blockIdx.x * 32, r0 = blockIdx.y * 32;
  int tx = threadIdx.x & 31, ty = threadIdx.x >> 5;
#pragma unroll
  for (int i = ty; i < 32; i += 8) t[i][tx] = in[(size_t)(r0 + i) * C + c0 + tx];
  __syncthreads();
#pragma unroll
  for (int i = ty; i < 32; i += 8) out[(size_t)(c0 + i) * R + r0 + tx] = f2bf(t[tx][i]);
}

__global__ __launch_bounds__(256) void k_tb2b(const ushort_t* in, ushort_t* out, int L, int C) {
  __shared__ ushort_t t[32][33];
  int b = blockIdx.z;
  const ushort_t* ib = in + (size_t)b * L * C;
  ushort_t* ob = out + (size_t)b * C * L;
  int c0 = blockIdx.x * 32, l0 = blockIdx.y * 32;
  int tx = threadIdx.x & 31, ty = threadIdx.x >> 5;
#pragma unroll
  for (int i = ty; i < 32; i += 8) t[i][tx] = ib[(size_t)(l0 + i) * C + c0 + tx];
  __syncthreads();
#pragma unroll
  for (int i = ty; i < 32; i += 8) ob[(size_t)(c0 + i) * L + l0 + tx] = t[tx][i];
}

__device__ __forceinline__ void blockRed2(float& a, float& b, float* red) {
#pragma unroll
  for (int o = 32; o; o >>= 1) { a += __shfl_down(a, o); b += __shfl_down(b, o); }
  int w = threadIdx.x >> 6;
  if ((threadIdx.x & 63) == 0) { red[w] = a; red[4 + w] = b; }
  __syncthreads();
  a = red[0] + red[1] + red[2] + red[3];
  b = red[4] + red[5] + red[6] + red[7];
  __syncthreads();
}

__global__ __launch_bounds__(256) void k_lnfwd(const float* X, const float* sc, const float* bi,
                                               float* nout, float* rstd, ushort_t* yb, int D) {
  __shared__ float red[8];
  int row = blockIdx.x;
  const float* x = X + (size_t)row * D;
  float s = 0.f, s2 = 0.f;
  for (int d = threadIdx.x; d < D; d += 256) { float v = x[d]; s += v; s2 += v * v; }
  blockRed2(s, s2, red);
  float mu = s / D;
  float var = s2 / D - mu * mu;
  float rs = rsqrtf(var + 1e-6f);
  for (int d = threadIdx.x; d < D; d += 256) {
    float nv = (x[d] - mu) * rs;
    nout[(size_t)row * D + d] = nv;
    yb[(size_t)row * D + d] = f2bf(nv * sc[d] + bi[d]);
  }
  if (threadIdx.x == 0) rstd[row] = rs;
}

__global__ __launch_bounds__(256) void k_lnfwd2(const float* X, const float* fs, const float* fb,
                                                ushort_t* yb, int D) {
  __shared__ float red[8];
  int row = blockIdx.x;
  const float* x = X + (size_t)row * D;
  float s = 0.f, s2 = 0.f;
  for (int d = threadIdx.x; d < D; d += 256) { float v = x[d]; s += v; s2 += v * v; }
  blockRed2(s, s2, red);
  float mu = s / D;
  float var = s2 / D - mu * mu;
  float rs = rsqrtf(var + 1e-6f);
  for (int d = threadIdx.x; d < D; d += 256) {
    size_t g = (size_t)row * D + d;
    float nv = (x[d] - mu) * rs;
    yb[g] = f2bf(nv * fs[g] + fb[g]);
  }
}

__global__ __launch_bounds__(256) void k_lnbwd(const float* G, const float* nn, const float* rstd,
                                               const float* sc, ushort_t* g3b, float* gsc, int D) {
  __shared__ float red[8];
  int row = blockIdx.x;
  const float* g = G + (size_t)row * D;
  const float* n_ = nn + (size_t)row * D;
  float sa = 0.f, sb = 0.f;
  for (int d = threadIdx.x; d < D; d += 256) {
    float dn = g[d] * sc[d];
    sa += dn; sb += dn * n_[d];
  }
  blockRed2(sa, sb, red);
  float a = sa / D, b = sb / D, rs = rstd[row];
  for (int d = threadIdx.x; d < D; d += 256) {
    size_t gi = (size_t)row * D + d;
    float dn = g[d] * sc[d];
    g3b[gi] = f2bf(rs * (dn - a - n_[d] * b));
    gsc[gi] = g[d] * n_[d];
  }
}

__global__ __launch_bounds__(256) void k_wsum(const float* w, float* o, int n) {
  __shared__ float red[4];
  float s = 0.f;
  for (int i = threadIdx.x; i < n; i += 256) s += w[i];
#pragma unroll
  for (int d = 32; d; d >>= 1) s += __shfl_down(s, d);
  if ((threadIdx.x & 63) == 0) red[threadIdx.x >> 6] = s;
  __syncthreads();
  if (threadIdx.x == 0) o[0] = fmaxf(red[0] + red[1] + red[2] + red[3], 1e-8f);
}

// fused softmax-grad over bf16 logits
__global__ __launch_bounds__(256) void k_softgrad(const ushort_t* logits, const float* labels,
                                                  const float* w, const float* wsum,
                                                  ushort_t* dlb, int V) {
  __shared__ float lrow[8192];
  __shared__ float red[8];
  int row = blockIdx.x;
  const ushort_t* l = logits + (size_t)row * V;
  const float* y = labels + (size_t)row * V;
  float m = -3.4e38f, t = 0.f;
  for (int v = threadIdx.x; v < V; v += 256) {
    float lv = bf2f(l[v]);
    lrow[v] = lv;
    m = fmaxf(m, lv);
    t += y[v];
  }
#pragma unroll
  for (int o = 32; o; o >>= 1) { m = fmaxf(m, __shfl_down(m, o)); t += __shfl_down(t, o); }
  int wv = threadIdx.x >> 6;
  if ((threadIdx.x & 63) == 0) { red[wv] = m; red[4 + wv] = t; }
  __syncthreads();
  m = fmaxf(fmaxf(red[0], red[1]), fmaxf(red[2], red[3]));
  t = red[4] + red[5] + red[6] + red[7];
  __syncthreads();
  float s = 0.f;
  for (int v = threadIdx.x; v < V; v += 256) s += expf(lrow[v] - m);
#pragma unroll
  for (int o = 32; o; o >>= 1) s += __shfl_down(s, o);
  if ((threadIdx.x & 63) == 0) red[wv] = s;
  __syncthreads();
  s = red[0] + red[1] + red[2] + red[3];
  float c = w[row] / wsum[0];
  float invs = 1.f / s;
  for (int v = threadIdx.x; v < V; v += 256) {
    size_t g = (size_t)row * V + v;
    dlb[g] = f2bf(c * (expf(lrow[v] - m) * invs * t - y[v]));
  }
}

__global__ __launch_bounds__(256) void k_scanpart(const float* gs, const float* gb, float* ps,
                                                  float* pb, int L, int D) {
  int d = blockIdx.x * 256 + threadIdx.x;
  int seg = blockIdx.y, b = blockIdx.z;
  const int SEGL = L / 16;
  size_t base = ((size_t)b * L + seg * SEGL) * D + d;
  float s1 = 0.f, s2 = 0.f;
  for (int i = 0; i < SEGL; i++) { s1 += gs[base + (size_t)i * D]; s2 += gb[base + (size_t)i * D]; }
  size_t pi = ((size_t)b * 16 + seg) * D + d;
  ps[pi] = s1; pb[pi] = s2;
}

__global__ __launch_bounds__(256) void k_scanapply(const float* gs, const float* gb,
                                                   const float* ps, const float* pb,
                                                   const float* sc, const float* bi,
                                                   const float* steps, float* fs, float* fb,
                                                   int L, int D) {
  int d = blockIdx.x * 256 + threadIdx.x;
  int seg = blockIdx.y, b = blockIdx.z;
  const int SEGL = L / 16;
  float ss = steps[3];
  float rs_ = 0.f, rb_ = 0.f;
  for (int s = 0; s < seg; s++) {
    size_t pi = ((size_t)b * 16 + s) * D + d;
    rs_ += ps[pi]; rb_ += pb[pi];
  }
  float s0 = sc[d], b0 = bi[d];
  size_t base = ((size_t)b * L + seg * SEGL) * D + d;
  for (int i = 0; i < SEGL; i++) {
    size_t g = base + (size_t)i * D;
    fs[g] = s0 - ss * rs_;
    fb[g] = b0 - ss * rb_;
    rs_ += gs[g]; rb_ += gb[g];
  }
}

// ---------- orchestration ----------
extern "C" void kernel_launch(void* const* d_in, const int* in_sizes, int n_in, void* d_out,
                              int out_size, void* d_ws, size_t ws_size, hipStream_t stream) {
  const float* x        = (const float*)d_in[0];
  const float* labels   = (const float*)d_in[1];
  const float* weights  = (const float*)d_in[2];
  const float* W1       = (const float*)d_in[3];
  const float* b1       = (const float*)d_in[4];
  const float* W2       = (const float*)d_in[5];
  const float* b2       = (const float*)d_in[6];
  const float* ln_scale = (const float*)d_in[7];
  const float* ln_bias  = (const float*)d_in[8];
  const float* Wu       = (const float*)d_in[9];
  const float* bu       = (const float*)d_in[10];
  const float* steps    = (const float*)d_in[11];

  const int BL = in_sizes[2];   // 4096
  const int D  = in_sizes[7];   // 1024
  const int F  = in_sizes[4];   // 4096
  const int V  = in_sizes[10];  // 8192
  const int Bb = 2, L = BL / Bb;
  const int Tt = (L / 128) * (L / 128 + 1) / 2;   // 136 live lower-tri tiles

  char* ws = (char*)d_ws;
  size_t off = 0;
  auto take = [&](size_t b) { char* p = ws + off; off = (off + b + 255) & ~(size_t)255; return p; };

  ushort_t* xb   = (ushort_t*)take((size_t)BL * D * 2);
  ushort_t* w1t  = (ushort_t*)take((size_t)F * D * 2);
  ushort_t* w2t  = (ushort_t*)take((size_t)D * F * 2);
  ushort_t* w2b  = (ushort_t*)take((size_t)F * D * 2);
  ushort_t* wut  = (ushort_t*)take((size_t)V * D * 2);
  ushort_t* wub  = (ushort_t*)take((size_t)D * V * 2);
  ushort_t* H1b  = (ushort_t*)take((size_t)BL * F * 2);
  ushort_t* H2b  = (ushort_t*)take((size_t)BL * F * 2);
  float*    H3   = (float*)take((size_t)BL * D * 4);
  float*    nbuf = (float*)take((size_t)BL * D * 4);
  float*    rstd = (float*)take((size_t)BL * 4);
  ushort_t* h4b  = (ushort_t*)take((size_t)BL * D * 2);
  float*    wsumb= (float*)take(256);
  float*    G4   = (float*)take((size_t)BL * D * 4);   // also g_bias
  float*    gsc  = (float*)take((size_t)BL * D * 4);   // g_scale
  ushort_t* g3b  = (ushort_t*)take((size_t)BL * D * 2);
  ushort_t* g3t  = (ushort_t*)take((size_t)BL * D * 2);
  float*    fs   = (float*)take((size_t)BL * D * 4);
  float*    fb   = (float*)take((size_t)BL * D * 4);
  ushort_t* x4b  = (ushort_t*)take((size_t)BL * D * 2);
  float*    psc  = (float*)take((size_t)Bb * 16 * D * 4);
  float*    pbi  = (float*)take((size_t)Bb * 16 * D * 4);
  // poolA (134MB): split-K partials (up to 67MB) / logitsb bf16 (64MB) ->
  // later {g1b, g1t, S1b, x2b}
  char* poolA = take((size_t)BL * V * 4);
  ushort_t* logitsb = (ushort_t*)poolA;
  float*    partA  = (float*)poolA;
  ushort_t* g1b = (ushort_t*)poolA;
  ushort_t* g1t = (ushort_t*)(poolA + (size_t)BL * F * 2);
  ushort_t* S1b = (ushort_t*)(poolA + (size_t)BL * F * 4);
  ushort_t* x2b = (ushort_t*)(poolA + (size_t)BL * F * 4 + (size_t)Bb * L * L * 2);
  // poolB (64MB): dlb bf16 -> later {S2b, X3, x3}; head also hosts S1 partials
  char* poolB = take((size_t)BL * V * 2);
  ushort_t* dlb = (ushort_t*)poolB;
  float*    partS1 = (float*)poolB;
  ushort_t* S2b = (ushort_t*)poolB;
  float*    X3  = (float*)(poolB + (size_t)Bb * L * L * 2);
  float*    x3  = (float*)(poolB + (size_t)Bb * L * L * 2 + (size_t)BL * D * 4);

  dim3 blk(256);
  const size_t MN_D = (size_t)BL * D;

  k_conv<<<dim3((unsigned)((size_t)BL * D / 1024)), blk, 0, stream>>>(x, xb, (size_t)BL * D);
  k_tconv<<<dim3(F / 32, D / 32), blk, 0, stream>>>(W1, w1t, D, F);
  k_tconv<<<dim3(D / 32, F / 32), blk, 0, stream>>>(W2, w2t, F, D);
  k_conv<<<dim3((unsigned)((size_t)F * D / 1024)), blk, 0, stream>>>(W2, w2b, (size_t)F * D);
  k_tconv<<<dim3(V / 32, D / 32), blk, 0, stream>>>(Wu, wut, D, V);
  k_conv<<<dim3((unsigned)((size_t)D * V / 1024)), blk, 0, stream>>>(Wu, wub, (size_t)D * V);

  GemmP p;
  auto clr = [&]() { p = GemmP{}; };

  // 1) H1b = bf16(x@W1+b1) ; H2b = bf16(relu^2)
  clr(); p.A = xb; p.B = w1t; p.M = BL; p.N = F; p.K = D;
  p.outb = H1b; p.outb2 = H2b; p.bias = b1;
  gemm_bt<1><<<dim3(F / 128, BL / 128, 1), blk, 0, stream>>>(p);
  // 2) H3 = H2@W2 + b2   [split-K 4]
  clr(); p.A = H2b; p.B = w2t; p.M = BL; p.N = D; p.K = F;
  p.part = partA; p.ksplit = 4; p.Kc = F / 4;
  gemm_bt<6><<<dim3(D / 128, BL / 128, 4), blk, 0, stream>>>(p);
  k_comb<<<dim3((unsigned)(MN_D / 1024)), blk, 0, stream>>>(partA, b2, H3, D, MN_D, 4);
  // 3) LN fwd
  k_lnfwd<<<dim3(BL), blk, 0, stream>>>(H3, ln_scale, ln_bias, nbuf, rstd, h4b, D);
  // 4) logits = bf16(h4@Wu + bu)
  clr(); p.A = h4b; p.B = wut; p.M = BL; p.N = V; p.K = D; p.outb = logitsb; p.bias = bu;
  gemm_bt<8><<<dim3(V / 128, BL / 128, 1), blk, 0, stream>>>(p);
  // 5) fused softmax grad
  k_wsum<<<dim3(1), blk, 0, stream>>>(weights, wsumb, BL);
  k_softgrad<<<dim3(BL), blk, 0, stream>>>(logitsb, labels, weights, wsumb, dlb, V);
  // 6) G4 = dlogits @ Wu^T   [split-K 4]
  clr(); p.A = dlb; p.B = wub; p.M = BL; p.N = D; p.K = V;
  p.part = partA; p.ksplit = 4; p.Kc = V / 4;
  gemm_bt<6><<<dim3(D / 128, BL / 128, 4), blk, 0, stream>>>(p);
  k_comb<<<dim3((unsigned)(MN_D / 1024)), blk, 0, stream>>>(partA, nullptr, G4, D, MN_D, 4);
  // 7) LN bwd -> g3, g_scale
  k_lnbwd<<<dim3(BL), blk, 0, stream>>>(G4, nbuf, rstd, ln_scale, g3b, gsc, D);
  // 8) g1 = (g3 @ W2^T) * 2*sqrt(H2)
  clr(); p.A = g3b; p.B = w2b; p.M = BL; p.N = F; p.K = D; p.outb = g1b; p.auxb = H2b;
  gemm_bt<2><<<dim3(F / 128, BL / 128, 1), blk, 0, stream>>>(p);
  // 9) transposes for attention V-operands
  k_tb2b<<<dim3(F / 32, L / 32, Bb), blk, 0, stream>>>(g1b, g1t, L, F);
  k_tb2b<<<dim3(D / 32, L / 32, Bb), blk, 0, stream>>>(g3b, g3t, L, D);
  // 10) S1 = tril(x x^T, -1)   [split-K 2, compact-tri grid]
  clr(); p.A = xb; p.B = xb; p.M = L; p.N = L; p.K = D;
  p.sA = (long long)L * D; p.sB = (long long)L * D;
  p.part = partS1; p.ksplit = 2; p.Kc = D / 2; p.Tt = Tt;
  gemm_bt<7><<<dim3(Tt, 1, Bb * 2), blk, 0, stream>>>(p);
  k_combtri<<<dim3(Tt, Bb), blk, 0, stream>>>(partS1, S1b, Tt, 2, L);
  // 11) x2 = relu(H1 - ss0 * S1@g1)^2   [K-limited, aux = bf16 H1b]
  clr(); p.A = S1b; p.B = g1t; p.M = L; p.N = F; p.K = L;
  p.sA = (long long)L * L; p.sB = (long long)F * L;
  p.outb = x2b; p.sOutB = (long long)L * F; p.auxb = H1b; p.sAuxF = (long long)L * F;
  p.steps = steps;
  gemm_bt<4><<<dim3(F / 128, L / 128, Bb), blk, 0, stream>>>(p);
  // 12) X3 = x2@W2 + b2   [split-K 4]
  clr(); p.A = x2b; p.B = w2t; p.M = BL; p.N = D; p.K = F;
  p.part = partA; p.ksplit = 4; p.Kc = F / 4;
  gemm_bt<6><<<dim3(D / 128, BL / 128, 4), blk, 0, stream>>>(p);
  k_comb<<<dim3((unsigned)(MN_D / 1024)), blk, 0, stream>>>(partA, b2, X3, D, MN_D, 4);
  // 13) S2 = tril(x2 H2^T, -1)   [split-K 2, compact-tri grid]
  clr(); p.A = x2b; p.B = H2b; p.M = L; p.N = L; p.K = F;
  p.sA = (long long)L * F; p.sB = (long long)L * F;
  p.part = partA; p.ksplit = 2; p.Kc = F / 2; p.Tt = Tt;
  gemm_bt<7><<<dim3(Tt, 1, Bb * 2), blk, 0, stream>>>(p);
  k_combtri<<<dim3(Tt, Bb), blk, 0, stream>>>(partA, S2b, Tt, 2, L);
  // 14) x3 = X3 - ss2 * S2@g3   [K-limited]
  clr(); p.A = S2b; p.B = g3t; p.M = L; p.N = D; p.K = L;
  p.sA = (long long)L * L; p.sB = (long long)D * L;
  p.outf = x3; p.sOutF = (long long)L * D; p.auxf = X3; p.sAuxF = (long long)L * D; p.steps = steps;
  gemm_bt<5><<<dim3(D / 128, L / 128, Bb), blk, 0, stream>>>(p);
  // 15) exclusive cumsums -> fast_scale / fast_bias
  k_scanpart<<<dim3(D / 256, 16, Bb), blk, 0, stream>>>(gsc, G4, psc, pbi, L, D);
  k_scanapply<<<dim3(D / 256, 16, Bb), blk, 0, stream>>>(gsc, G4, psc, pbi, ln_scale, ln_bias,
                                                         steps, fs, fb, L, D);
  // 16) x4 = LN(x3)*fast_scale + fast_bias
  k_lnfwd2<<<dim3(BL), blk, 0, stream>>>(x3, fs, fb, x4b, D);
  // 17) out = x4@Wu + bu
  clr(); p.A = x4b; p.B = wut; p.M = BL; p.N = V; p.K = D; p.outf = (float*)d_out; p.bias = bu;
  gemm_bt<0><<<dim3(V / 128, BL / 128, 1), blk, 0, stream>>>(p);
}

// Round 5
// 1157.326 us; speedup vs baseline: 1.3636x; 1.0265x over previous
//
#include <hip/hip_runtime.h>
#include <cstdint>

typedef unsigned short ushort_t;
typedef __bf16 bf16x8 __attribute__((ext_vector_type(8)));
typedef float f32x4 __attribute__((ext_vector_type(4)));

// ---------- helpers ----------
__device__ __forceinline__ ushort_t f2bf(float f) {
  union { float f; unsigned int u; } v; v.f = f;
  unsigned int u = v.u;
  unsigned int r = (u + 0x7fffu + ((u >> 16) & 1u)) >> 16;
  return (ushort_t)r;
}
__device__ __forceinline__ float bf2f(ushort_t u) {
  union { unsigned int u; float f; } v; v.u = ((unsigned int)u) << 16; return v.f;
}

#define GLOAD16(gp, lp)                                                              \
  __builtin_amdgcn_global_load_lds(                                                  \
      reinterpret_cast<const __attribute__((address_space(1))) unsigned int*>(       \
          reinterpret_cast<uintptr_t>(gp)),                                          \
      reinterpret_cast<__attribute__((address_space(3))) unsigned int*>(             \
          reinterpret_cast<uintptr_t>(lp)),                                          \
      16, 0, 0)

// EPI: 0 = outf = acc + bias                     (out)
//      8 = outb = bf16(acc + bias)               (logits)
//      1 = outb = bf16(acc+bias); outb2 = bf16(relu^2)    (H1b + H2b)
//      2 = outb = bf16(acc * 2*sqrt(auxb))       (g1)
//      4 = outb = bf16(relu(bf2f(auxb) - ss0*acc)^2); K-limit  (x2)
//      5 = outf = auxf - ss2*acc; K-limit        (x3)
//      6 = split-K partial, full-matrix f32      (H3, G4, X3 stage 1)
//      7 = split-K partial, compact-tri grid, 256x256 tiles   (S1, S2 stage 1)
struct GemmP {
  const ushort_t* A; const ushort_t* B;
  int M, N, K;
  long long sA, sB;
  float* outf;   long long sOutF;
  ushort_t* outb; long long sOutB;
  ushort_t* outb2;
  const float* bias;
  const float* auxf; long long sAuxF;   // sAuxF doubles as aux (f32 or bf16) stride
  const ushort_t* auxb;
  const float* steps;
  float* part; int ksplit, Kc, Tt;
};

// ---------- 256x256 GEMM: 8 waves, BK=32, 3-buffer counted-vmcnt pipeline ----------
// LDS slot-XOR swizzle (T2, rule #21): within each 16-row x 32-col (1KB) chunk,
// 16B slot s' in LDS holds global slot s' ^ sigma(row), sigma(r) = (r>>1)&3.
// Applied via pre-swizzled GLOBAL source (linear gload_lds dest) + swizzled ds_read.
template <int EPI>
__global__ __launch_bounds__(512, 2) void gemm256(GemmP p) {
  const int nwg = gridDim.x * gridDim.y;
  const int orig = blockIdx.y * gridDim.x + blockIdx.x;
  const int xcd = orig & 7, loc = orig >> 3;
  const int q8 = nwg >> 3, r8 = nwg & 7;
  const int wg = (xcd < r8) ? (xcd * (q8 + 1) + loc) : (r8 * (q8 + 1) + (xcd - r8) * q8 + loc);
  int mt, nt;
  if (EPI == 7) {            // compact lower-tri tile index -> (mt, nt)
    int t_ = wg;
    mt = (int)((sqrtf(8.f * t_ + 1.f) - 1.f) * 0.5f);
    while ((mt + 1) * (mt + 2) / 2 <= t_) mt++;
    while (mt * (mt + 1) / 2 > t_) mt--;
    nt = t_ - mt * (mt + 1) / 2;
  } else {
    nt = wg % gridDim.x; mt = wg / gridDim.x;
  }
  const int m0 = mt * 256, n0 = nt * 256;

  int bz = blockIdx.z, ks = 0;
  if (EPI == 6 || EPI == 7) { bz = blockIdx.z / p.ksplit; ks = blockIdx.z % p.ksplit; }

  const ushort_t* A = p.A + (size_t)bz * p.sA;
  const ushort_t* B = p.B + (size_t)bz * p.sB;

  int kbeg = 0, kend = p.K;
  if (EPI == 6 || EPI == 7) { kbeg = ks * p.Kc; kend = kbeg + p.Kc; }
  else if (EPI == 4) kend = min(p.K, m0 + 256);

  extern __shared__ ushort_t smem[];      // 3*(8K+8K) elems = 96KB
  ushort_t* sA = smem;
  ushort_t* sB = smem + 3 * 8192;

  const int tid = threadIdx.x;
  const int wid = tid >> 6, lane = tid & 63;
  const int wm = wid >> 2, wn = wid & 3;

  f32x4 acc[8][4];
#pragma unroll
  for (int i = 0; i < 8; i++)
#pragma unroll
    for (int j = 0; j < 4; j++) acc[i][j] = f32x4{0.f, 0.f, 0.f, 0.f};

  // staging: chunk = 16 rows x 32 cols = 1KB. Wave w stages A-chunks {w, w+8},
  // B-chunks {w, w+8}. Source col pre-swizzled so linear LDS dest lands swizzled.
  const int lr = lane >> 2;
  const int lcsw = (((lane & 3) ^ ((lr >> 1) & 3)) * 8);
  const int rT0 = wid * 16 + lr;
  const int rT1 = 128 + wid * 16 + lr;
  const ushort_t* gA0 = A + (size_t)(m0 + rT0) * p.K + lcsw;
  const ushort_t* gA1 = A + (size_t)(m0 + rT1) * p.K + lcsw;
  const ushort_t* gB0 = B + (size_t)(n0 + rT0) * p.K + lcsw;
  const ushort_t* gB1 = B + (size_t)(n0 + rT1) * p.K + lcsw;
  ushort_t* lA0 = &sA[wid * 512];
  ushort_t* lA1 = &sA[(8 + wid) * 512];
  ushort_t* lB0 = &sB[wid * 512];
  ushort_t* lB1 = &sB[(8 + wid) * 512];

  // ds_read offsets (loop-invariant): frag i of A at chunk (wm*8+i), row fr,
  // swizzled 16B slot (q ^ sigma(fr)).
  const int fr = lane & 15;
  const int q = lane >> 4;
  const int slot = (q ^ ((fr >> 1) & 3)) * 8;
  int offA[8], offB[4];
#pragma unroll
  for (int i = 0; i < 8; i++) offA[i] = (wm * 8 + i) * 512 + fr * 32 + slot;
#pragma unroll
  for (int j = 0; j < 4; j++) offB[j] = (wn * 4 + j) * 512 + fr * 32 + slot;

  const int nIter = (kend - kbeg) >> 5;
  auto stage = [&](int t, int buf) {
    const int kk = kbeg + t * 32;
    const int o = buf * 8192;
    GLOAD16(gA0 + kk, lA0 + o);
    GLOAD16(gA1 + kk, lA1 + o);
    GLOAD16(gB0 + kk, lB0 + o);
    GLOAD16(gB1 + kk, lB1 + o);
  };
  stage(0, 0);
  if (nIter > 1) stage(1, 1);

  for (int t = 0; t < nIter; ++t) {
    if (t + 1 < nIter) { asm volatile("s_waitcnt vmcnt(4)" ::: "memory"); }
    else               { asm volatile("s_waitcnt vmcnt(0)" ::: "memory"); }
    __builtin_amdgcn_s_barrier();
    __builtin_amdgcn_sched_barrier(0);
    if (t + 2 < nIter) stage(t + 2, (t + 2) % 3);
    const int co = (t % 3) * 8192;
    bf16x8 av[8], bv[4];
#pragma unroll
    for (int j = 0; j < 4; j++) bv[j] = *reinterpret_cast<const bf16x8*>(&sB[co + offB[j]]);
#pragma unroll
    for (int i = 0; i < 8; i++) {
      av[i] = *reinterpret_cast<const bf16x8*>(&sA[co + offA[i]]);
#pragma unroll
      for (int j = 0; j < 4; j++)
        acc[i][j] = __builtin_amdgcn_mfma_f32_16x16x32_bf16(av[i], bv[j], acc[i][j], 0, 0, 0);
    }
  }

  const int fq = q;
  float ss = 0.f;
  if (EPI == 4) ss = p.steps[0];
  float* outf = p.outf ? p.outf + (size_t)bz * p.sOutF : nullptr;
  ushort_t* outb = p.outb ? p.outb + (size_t)bz * p.sOutB : nullptr;
  ushort_t* outb2 = p.outb2;
  const ushort_t* auxb = p.auxb ? p.auxb + (size_t)bz * p.sAuxF : nullptr;
  float* partT = nullptr;
  if (EPI == 6) partT = p.part + (size_t)blockIdx.z * p.M * p.N;
  if (EPI == 7) partT = p.part + ((size_t)blockIdx.z * p.Tt + wg) * 65536;

#pragma unroll
  for (int i = 0; i < 8; i++) {
#pragma unroll
    for (int j = 0; j < 4; j++) {
#pragma unroll
      for (int r2 = 0; r2 < 4; r2++) {
        int lrow = wm * 128 + i * 16 + fq * 4 + r2;
        int lcol = wn * 64 + j * 16 + fr;
        int row = m0 + lrow, col = n0 + lcol;
        size_t g = (size_t)row * p.N + col;
        float v = acc[i][j][r2];
        if (EPI == 0) {
          outf[g] = v + (p.bias ? p.bias[col] : 0.f);
        } else if (EPI == 8) {
          outb[g] = f2bf(v + p.bias[col]);
        } else if (EPI == 1) {
          v += p.bias[col];
          outb[g] = f2bf(v);
          float rl = fmaxf(v, 0.f);
          outb2[g] = f2bf(rl * rl);
        } else if (EPI == 2) {
          outb[g] = f2bf(v * 2.f * sqrtf(bf2f(auxb[g])));
        } else if (EPI == 4) {
          float x1 = bf2f(auxb[g]) - ss * v;
          float rl = fmaxf(x1, 0.f);
          outb[g] = f2bf(rl * rl);
        } else if (EPI == 6) {
          partT[g] = v;
        } else if (EPI == 7) {
          partT[lrow * 256 + lcol] = v;
        }
      }
    }
  }
}

// ---------- 128x128 GEMM (proven R4 pipeline) -- kept for x3 (EPI 5) ----------
template <int EPI>
__global__ __launch_bounds__(256) void gemm_bt(GemmP p) {
  const int nwg = gridDim.x * gridDim.y;
  const int orig = blockIdx.y * gridDim.x + blockIdx.x;
  const int xcd = orig & 7, loc = orig >> 3;
  const int q = nwg >> 3, r = nwg & 7;
  const int wg = (xcd < r) ? (xcd * (q + 1) + loc) : (r * (q + 1) + (xcd - r) * q + loc);
  const int nt = wg % gridDim.x, mt = wg / gridDim.x;
  const int m0 = mt * 128, n0 = nt * 128;
  const int bz = blockIdx.z;

  const ushort_t* A = p.A + (size_t)bz * p.sA;
  const ushort_t* B = p.B + (size_t)bz * p.sB;

  int kend = p.K;
  if (EPI == 5) kend = min(p.K, m0 + 128);

  __shared__ ushort_t sA[3 * 128 * 32];
  __shared__ ushort_t sB[3 * 128 * 32];

  const int tid = threadIdx.x;
  const int wid = tid >> 6, lane = tid & 63;
  const int wm = wid >> 1, wn = wid & 1;

  f32x4 acc[4][4];
#pragma unroll
  for (int i = 0; i < 4; i++)
#pragma unroll
    for (int j = 0; j < 4; j++) acc[i][j] = f32x4{0.f, 0.f, 0.f, 0.f};

  const int lr = lane >> 2;
  const int lc = (lane & 3) * 8;
  const int rA0 = wid * 16 + lr;
  const int rA1 = 64 + wid * 16 + lr;
  const ushort_t* gA0 = A + (size_t)(m0 + rA0) * p.K + lc;
  const ushort_t* gA1 = A + (size_t)(m0 + rA1) * p.K + lc;
  const ushort_t* gB0 = B + (size_t)(n0 + rA0) * p.K + lc;
  const ushort_t* gB1 = B + (size_t)(n0 + rA1) * p.K + lc;
  ushort_t* lA0 = &sA[wid * 512];
  ushort_t* lA1 = &sA[(4 + wid) * 512];
  ushort_t* lB0 = &sB[wid * 512];
  ushort_t* lB1 = &sB[(4 + wid) * 512];

  const int fr = lane & 15;
  const int kb = (lane >> 4) * 8;

  const int nIter = kend >> 5;
  auto stage = [&](int t, int buf) {
    const int kk = t * 32;
    const int o = buf * 4096;
    GLOAD16(gA0 + kk, lA0 + o);
    GLOAD16(gA1 + kk, lA1 + o);
    GLOAD16(gB0 + kk, lB0 + o);
    GLOAD16(gB1 + kk, lB1 + o);
  };
  stage(0, 0);
  if (nIter > 1) stage(1, 1);

  for (int t = 0; t < nIter; ++t) {
    if (t + 1 < nIter) { asm volatile("s_waitcnt vmcnt(4)" ::: "memory"); }
    else               { asm volatile("s_waitcnt vmcnt(0)" ::: "memory"); }
    __builtin_amdgcn_s_barrier();
    __builtin_amdgcn_sched_barrier(0);
    if (t + 2 < nIter) stage(t + 2, (t + 2) % 3);
    const int co = (t % 3) * 4096;
    bf16x8 av[4], bv[4];
#pragma unroll
    for (int i = 0; i < 4; i++) {
      av[i] = *reinterpret_cast<const bf16x8*>(&sA[co + (wm * 64 + i * 16 + fr) * 32 + kb]);
      bv[i] = *reinterpret_cast<const bf16x8*>(&sB[co + (wn * 64 + i * 16 + fr) * 32 + kb]);
    }
#pragma unroll
    for (int i = 0; i < 4; i++)
#pragma unroll
      for (int j = 0; j < 4; j++)
        acc[i][j] = __builtin_amdgcn_mfma_f32_16x16x32_bf16(av[i], bv[j], acc[i][j], 0, 0, 0);
  }

  const int fq = lane >> 4;
  float ss = (EPI == 5) ? p.steps[2] : 0.f;
  float* outf = p.outf ? p.outf + (size_t)bz * p.sOutF : nullptr;
  const float* auxf = p.auxf ? p.auxf + (size_t)bz * p.sAuxF : nullptr;

#pragma unroll
  for (int i = 0; i < 4; i++) {
#pragma unroll
    for (int j = 0; j < 4; j++) {
#pragma unroll
      for (int r2 = 0; r2 < 4; r2++) {
        int row = m0 + wm * 64 + i * 16 + fq * 4 + r2;
        int col = n0 + wn * 64 + j * 16 + fr;
        size_t g = (size_t)row * p.N + col;
        float v = acc[i][j][r2];
        if (EPI == 5) {
          outf[g] = auxf[g] - ss * v;
        } else {
          outf[g] = v + (p.bias ? p.bias[col] : 0.f);
        }
      }
    }
  }
}

// ---------- split-K combines ----------
__global__ __launch_bounds__(256) void k_comb(const float* part, const float* bias, float* out,
                                              int N, size_t MN, int S) {
  size_t e = ((size_t)blockIdx.x * 256 + threadIdx.x) * 4;
  if (e >= MN) return;
  float4 s = *(const float4*)(part + e);
  for (int p_ = 1; p_ < S; p_++) {
    float4 v = *(const float4*)(part + (size_t)p_ * MN + e);
    s.x += v.x; s.y += v.y; s.z += v.z; s.w += v.w;
  }
  if (bias) {
    int col = (int)(e % (size_t)N);
    s.x += bias[col]; s.y += bias[col + 1]; s.z += bias[col + 2]; s.w += bias[col + 3];
  }
  *(float4*)(out + e) = s;
}

// 256x256 compact-tri combine: S_bf16 = tril(sum_s part[s], -1)
__global__ __launch_bounds__(256) void k_combtri(const float* part, ushort_t* out, int Tt, int S,
                                                 int L) {
  int t = blockIdx.x, bz = blockIdx.y;
  int mt = (int)((sqrtf(8.f * t + 1.f) - 1.f) * 0.5f);
  while ((mt + 1) * (mt + 2) / 2 <= t) mt++;
  while (mt * (mt + 1) / 2 > t) mt--;
  int nt = t - mt * (mt + 1) / 2;
  const float* pb = part + ((size_t)bz * S * Tt + t) * 65536;
  ushort_t* ob = out + (size_t)bz * L * L;
  for (int e4 = threadIdx.x; e4 < 16384; e4 += 256) {
    int e = e4 * 4;
    float4 s = *(const float4*)(pb + e);
    for (int p_ = 1; p_ < S; p_++) {
      float4 v = *(const float4*)(pb + (size_t)p_ * Tt * 65536 + e);
      s.x += v.x; s.y += v.y; s.z += v.z; s.w += v.w;
    }
    int lr = e >> 8, lc2 = e & 255;
    int row = mt * 256 + lr, col = nt * 256 + lc2;
    ushort4 o;
    o.x = (col < row) ? f2bf(s.x) : (ushort_t)0;
    o.y = (col + 1 < row) ? f2bf(s.y) : (ushort_t)0;
    o.z = (col + 2 < row) ? f2bf(s.z) : (ushort_t)0;
    o.w = (col + 3 < row) ? f2bf(s.w) : (ushort_t)0;
    *(ushort4*)(&ob[(size_t)row * L + col]) = o;
  }
}

// ---------- auxiliary kernels ----------
__global__ __launch_bounds__(256) void k_conv(const float* in, ushort_t* out, size_t n) {
  size_t i = ((size_t)blockIdx.x * 256 + threadIdx.x) * 4;
  if (i >= n) return;
  float4 v = *(const float4*)(in + i);
  out[i] = f2bf(v.x); out[i + 1] = f2bf(v.y); out[i + 2] = f2bf(v.z); out[i + 3] = f2bf(v.w);
}

__global__ __launch_bounds__(256) void k_tconv(const float* in, ushort_t* out, int R, int C) {
  __shared__ float t[32][33];
  int c0 = blockIdx.x * 32, r0 = blockIdx.y * 32;
  int tx = threadIdx.x & 31, ty = threadIdx.x >> 5;
#pragma unroll
  for (int i = ty; i < 32; i += 8) t[i][tx] = in[(size_t)(r0 + i) * C + c0 + tx];
  __syncthreads();
#pragma unroll
  for (int i = ty; i < 32; i += 8) out[(size_t)(c0 + i) * R + r0 + tx] = f2bf(t[tx][i]);
}

__global__ __launch_bounds__(256) void k_tb2b(const ushort_t* in, ushort_t* out, int L, int C) {
  __shared__ ushort_t t[32][33];
  int b = blockIdx.z;
  const ushort_t* ib = in + (size_t)b * L * C;
  ushort_t* ob = out + (size_t)b * C * L;
  int c0 = blockIdx.x * 32, l0 = blockIdx.y * 32;
  int tx = threadIdx.x & 31, ty = threadIdx.x >> 5;
#pragma unroll
  for (int i = ty; i < 32; i += 8) t[i][tx] = ib[(size_t)(l0 + i) * C + c0 + tx];
  __syncthreads();
#pragma unroll
  for (int i = ty; i < 32; i += 8) ob[(size_t)(c0 + i) * L + l0 + tx] = t[tx][i];
}

__device__ __forceinline__ void blockRed2(float& a, float& b, float* red) {
#pragma unroll
  for (int o = 32; o; o >>= 1) { a += __shfl_down(a, o); b += __shfl_down(b, o); }
  int w = threadIdx.x >> 6;
  if ((threadIdx.x & 63) == 0) { red[w] = a; red[4 + w] = b; }
  __syncthreads();
  a = red[0] + red[1] + red[2] + red[3];
  b = red[4] + red[5] + red[6] + red[7];
  __syncthreads();
}

__global__ __launch_bounds__(256) void k_lnfwd(const float* X, const float* sc, const float* bi,
                                               float* nout, float* rstd, ushort_t* yb, int D) {
  __shared__ float red[8];
  int row = blockIdx.x;
  const float* x = X + (size_t)row * D;
  float s = 0.f, s2 = 0.f;
  for (int d = threadIdx.x; d < D; d += 256) { float v = x[d]; s += v; s2 += v * v; }
  blockRed2(s, s2, red);
  float mu = s / D;
  float var = s2 / D - mu * mu;
  float rs = rsqrtf(var + 1e-6f);
  for (int d = threadIdx.x; d < D; d += 256) {
    float nv = (x[d] - mu) * rs;
    nout[(size_t)row * D + d] = nv;
    yb[(size_t)row * D + d] = f2bf(nv * sc[d] + bi[d]);
  }
  if (threadIdx.x == 0) rstd[row] = rs;
}

__global__ __launch_bounds__(256) void k_lnfwd2(const float* X, const float* fs, const float* fb,
                                                ushort_t* yb, int D) {
  __shared__ float red[8];
  int row = blockIdx.x;
  const float* x = X + (size_t)row * D;
  float s = 0.f, s2 = 0.f;
  for (int d = threadIdx.x; d < D; d += 256) { float v = x[d]; s += v; s2 += v * v; }
  blockRed2(s, s2, red);
  float mu = s / D;
  float var = s2 / D - mu * mu;
  float rs = rsqrtf(var + 1e-6f);
  for (int d = threadIdx.x; d < D; d += 256) {
    size_t g = (size_t)row * D + d;
    float nv = (x[d] - mu) * rs;
    yb[g] = f2bf(nv * fs[g] + fb[g]);
  }
}

__global__ __launch_bounds__(256) void k_lnbwd(const float* G, const float* nn, const float* rstd,
                                               const float* sc, ushort_t* g3b, float* gsc, int D) {
  __shared__ float red[8];
  int row = blockIdx.x;
  const float* g = G + (size_t)row * D;
  const float* n_ = nn + (size_t)row * D;
  float sa = 0.f, sb = 0.f;
  for (int d = threadIdx.x; d < D; d += 256) {
    float dn = g[d] * sc[d];
    sa += dn; sb += dn * n_[d];
  }
  blockRed2(sa, sb, red);
  float a = sa / D, b = sb / D, rs = rstd[row];
  for (int d = threadIdx.x; d < D; d += 256) {
    size_t gi = (size_t)row * D + d;
    float dn = g[d] * sc[d];
    g3b[gi] = f2bf(rs * (dn - a - n_[d] * b));
    gsc[gi] = g[d] * n_[d];
  }
}

__global__ __launch_bounds__(256) void k_wsum(const float* w, float* o, int n) {
  __shared__ float red[4];
  float s = 0.f;
  for (int i = threadIdx.x; i < n; i += 256) s += w[i];
#pragma unroll
  for (int d = 32; d; d >>= 1) s += __shfl_down(s, d);
  if ((threadIdx.x & 63) == 0) red[threadIdx.x >> 6] = s;
  __syncthreads();
  if (threadIdx.x == 0) o[0] = fmaxf(red[0] + red[1] + red[2] + red[3], 1e-8f);
}

// fused softmax-grad over bf16 logits
__global__ __launch_bounds__(256) void k_softgrad(const ushort_t* logits, const float* labels,
                                                  const float* w, const float* wsum,
                                                  ushort_t* dlb, int V) {
  __shared__ float lrow[8192];
  __shared__ float red[8];
  int row = blockIdx.x;
  const ushort_t* l = logits + (size_t)row * V;
  const float* y = labels + (size_t)row * V;
  float m = -3.4e38f, t = 0.f;
  for (int v = threadIdx.x; v < V; v += 256) {
    float lv = bf2f(l[v]);
    lrow[v] = lv;
    m = fmaxf(m, lv);
    t += y[v];
  }
#pragma unroll
  for (int o = 32; o; o >>= 1) { m = fmaxf(m, __shfl_down(m, o)); t += __shfl_down(t, o); }
  int wv = threadIdx.x >> 6;
  if ((threadIdx.x & 63) == 0) { red[wv] = m; red[4 + wv] = t; }
  __syncthreads();
  m = fmaxf(fmaxf(red[0], red[1]), fmaxf(red[2], red[3]));
  t = red[4] + red[5] + red[6] + red[7];
  __syncthreads();
  float s = 0.f;
  for (int v = threadIdx.x; v < V; v += 256) s += expf(lrow[v] - m);
#pragma unroll
  for (int o = 32; o; o >>= 1) s += __shfl_down(s, o);
  if ((threadIdx.x & 63) == 0) red[wv] = s;
  __syncthreads();
  s = red[0] + red[1] + red[2] + red[3];
  float c = w[row] / wsum[0];
  float invs = 1.f / s;
  for (int v = threadIdx.x; v < V; v += 256) {
    size_t g = (size_t)row * V + v;
    dlb[g] = f2bf(c * (expf(lrow[v] - m) * invs * t - y[v]));
  }
}

__global__ __launch_bounds__(256) void k_scanpart(const float* gs, const float* gb, float* ps,
                                                  float* pb, int L, int D) {
  int d = blockIdx.x * 256 + threadIdx.x;
  int seg = blockIdx.y, b = blockIdx.z;
  const int SEGL = L / 16;
  size_t base = ((size_t)b * L + seg * SEGL) * D + d;
  float s1 = 0.f, s2 = 0.f;
  for (int i = 0; i < SEGL; i++) { s1 += gs[base + (size_t)i * D]; s2 += gb[base + (size_t)i * D]; }
  size_t pi = ((size_t)b * 16 + seg) * D + d;
  ps[pi] = s1; pb[pi] = s2;
}

__global__ __launch_bounds__(256) void k_scanapply(const float* gs, const float* gb,
                                                   const float* ps, const float* pb,
                                                   const float* sc, const float* bi,
                                                   const float* steps, float* fs, float* fb,
                                                   int L, int D) {
  int d = blockIdx.x * 256 + threadIdx.x;
  int seg = blockIdx.y, b = blockIdx.z;
  const int SEGL = L / 16;
  float ss = steps[3];
  float rs_ = 0.f, rb_ = 0.f;
  for (int s = 0; s < seg; s++) {
    size_t pi = ((size_t)b * 16 + s) * D + d;
    rs_ += ps[pi]; rb_ += pb[pi];
  }
  float s0 = sc[d], b0 = bi[d];
  size_t base = ((size_t)b * L + seg * SEGL) * D + d;
  for (int i = 0; i < SEGL; i++) {
    size_t g = base + (size_t)i * D;
    fs[g] = s0 - ss * rs_;
    fb[g] = b0 - ss * rb_;
    rs_ += gs[g]; rb_ += gb[g];
  }
}

// ---------- orchestration ----------
extern "C" void kernel_launch(void* const* d_in, const int* in_sizes, int n_in, void* d_out,
                              int out_size, void* d_ws, size_t ws_size, hipStream_t stream) {
  const float* x        = (const float*)d_in[0];
  const float* labels   = (const float*)d_in[1];
  const float* weights  = (const float*)d_in[2];
  const float* W1       = (const float*)d_in[3];
  const float* b1       = (const float*)d_in[4];
  const float* W2       = (const float*)d_in[5];
  const float* b2       = (const float*)d_in[6];
  const float* ln_scale = (const float*)d_in[7];
  const float* ln_bias  = (const float*)d_in[8];
  const float* Wu       = (const float*)d_in[9];
  const float* bu       = (const float*)d_in[10];
  const float* steps    = (const float*)d_in[11];

  const int BL = in_sizes[2];   // 4096
  const int D  = in_sizes[7];   // 1024
  const int F  = in_sizes[4];   // 4096
  const int V  = in_sizes[10];  // 8192
  const int Bb = 2, L = BL / Bb;
  const int T2t = (L / 256) * (L / 256 + 1) / 2;   // 36 live 256-tri tiles
  const unsigned SMEM = 3 * 8192 * 2 * 2;          // 96 KB dynamic LDS

  char* ws = (char*)d_ws;
  size_t off = 0;
  auto take = [&](size_t b) { char* p = ws + off; off = (off + b + 255) & ~(size_t)255; return p; };

  ushort_t* xb   = (ushort_t*)take((size_t)BL * D * 2);
  ushort_t* w1t  = (ushort_t*)take((size_t)F * D * 2);
  ushort_t* w2t  = (ushort_t*)take((size_t)D * F * 2);
  ushort_t* w2b  = (ushort_t*)take((size_t)F * D * 2);
  ushort_t* wut  = (ushort_t*)take((size_t)V * D * 2);
  ushort_t* wub  = (ushort_t*)take((size_t)D * V * 2);
  ushort_t* H1b  = (ushort_t*)take((size_t)BL * F * 2);
  ushort_t* H2b  = (ushort_t*)take((size_t)BL * F * 2);
  float*    H3   = (float*)take((size_t)BL * D * 4);
  float*    nbuf = (float*)take((size_t)BL * D * 4);
  float*    rstd = (float*)take((size_t)BL * 4);
  ushort_t* h4b  = (ushort_t*)take((size_t)BL * D * 2);
  float*    wsumb= (float*)take(256);
  float*    G4   = (float*)take((size_t)BL * D * 4);   // also g_bias
  float*    gsc  = (float*)take((size_t)BL * D * 4);   // g_scale
  ushort_t* g3b  = (ushort_t*)take((size_t)BL * D * 2);
  ushort_t* g3t  = (ushort_t*)take((size_t)BL * D * 2);
  float*    fs   = (float*)take((size_t)BL * D * 4);
  float*    fb   = (float*)take((size_t)BL * D * 4);
  ushort_t* x4b  = (ushort_t*)take((size_t)BL * D * 2);
  float*    psc  = (float*)take((size_t)Bb * 16 * D * 4);
  float*    pbi  = (float*)take((size_t)Bb * 16 * D * 4);
  // poolA (134MB): logitsb bf16 / split-K partials -> later {g1b, g1t, S1b, x2b}
  char* poolA = take((size_t)BL * V * 4);
  ushort_t* logitsb = (ushort_t*)poolA;
  float*    partA  = (float*)poolA;
  ushort_t* g1b = (ushort_t*)poolA;
  ushort_t* g1t = (ushort_t*)(poolA + (size_t)BL * F * 2);
  ushort_t* S1b = (ushort_t*)(poolA + (size_t)BL * F * 4);
  ushort_t* x2b = (ushort_t*)(poolA + (size_t)BL * F * 4 + (size_t)Bb * L * L * 2);
  // poolB (64MB): dlb bf16 -> later {S2b, X3, x3}; head hosts S1 partials (36MB)
  char* poolB = take((size_t)BL * V * 2);
  ushort_t* dlb = (ushort_t*)poolB;
  float*    partS1 = (float*)poolB;
  ushort_t* S2b = (ushort_t*)poolB;
  float*    X3  = (float*)(poolB + (size_t)Bb * L * L * 2);
  float*    x3  = (float*)(poolB + (size_t)Bb * L * L * 2 + (size_t)BL * D * 4);

  dim3 blk(256), blk5(512);
  const size_t MN_D = (size_t)BL * D;

  k_conv<<<dim3((unsigned)((size_t)BL * D / 1024)), blk, 0, stream>>>(x, xb, (size_t)BL * D);
  k_tconv<<<dim3(F / 32, D / 32), blk, 0, stream>>>(W1, w1t, D, F);
  k_tconv<<<dim3(D / 32, F / 32), blk, 0, stream>>>(W2, w2t, F, D);
  k_conv<<<dim3((unsigned)((size_t)F * D / 1024)), blk, 0, stream>>>(W2, w2b, (size_t)F * D);
  k_tconv<<<dim3(V / 32, D / 32), blk, 0, stream>>>(Wu, wut, D, V);
  k_conv<<<dim3((unsigned)((size_t)D * V / 1024)), blk, 0, stream>>>(Wu, wub, (size_t)D * V);

  GemmP p;
  auto clr = [&]() { p = GemmP{}; };

  // 1) H1b = bf16(x@W1+b1) ; H2b = bf16(relu^2)
  clr(); p.A = xb; p.B = w1t; p.M = BL; p.N = F; p.K = D;
  p.outb = H1b; p.outb2 = H2b; p.bias = b1;
  gemm256<1><<<dim3(F / 256, BL / 256, 1), blk5, SMEM, stream>>>(p);
  // 2) H3 = H2@W2 + b2   [split-K 4]
  clr(); p.A = H2b; p.B = w2t; p.M = BL; p.N = D; p.K = F;
  p.part = partA; p.ksplit = 4; p.Kc = F / 4;
  gemm256<6><<<dim3(D / 256, BL / 256, 4), blk5, SMEM, stream>>>(p);
  k_comb<<<dim3((unsigned)(MN_D / 1024)), blk, 0, stream>>>(partA, b2, H3, D, MN_D, 4);
  // 3) LN fwd
  k_lnfwd<<<dim3(BL), blk, 0, stream>>>(H3, ln_scale, ln_bias, nbuf, rstd, h4b, D);
  // 4) logits = bf16(h4@Wu + bu)
  clr(); p.A = h4b; p.B = wut; p.M = BL; p.N = V; p.K = D; p.outb = logitsb; p.bias = bu;
  gemm256<8><<<dim3(V / 256, BL / 256, 1), blk5, SMEM, stream>>>(p);
  // 5) fused softmax grad
  k_wsum<<<dim3(1), blk, 0, stream>>>(weights, wsumb, BL);
  k_softgrad<<<dim3(BL), blk, 0, stream>>>(logitsb, labels, weights, wsumb, dlb, V);
  // 6) G4 = dlogits @ Wu^T   [split-K 4]
  clr(); p.A = dlb; p.B = wub; p.M = BL; p.N = D; p.K = V;
  p.part = partA; p.ksplit = 4; p.Kc = V / 4;
  gemm256<6><<<dim3(D / 256, BL / 256, 4), blk5, SMEM, stream>>>(p);
  k_comb<<<dim3((unsigned)(MN_D / 1024)), blk, 0, stream>>>(partA, nullptr, G4, D, MN_D, 4);
  // 7) LN bwd -> g3, g_scale
  k_lnbwd<<<dim3(BL), blk, 0, stream>>>(G4, nbuf, rstd, ln_scale, g3b, gsc, D);
  // 8) g1 = (g3 @ W2^T) * 2*sqrt(H2)
  clr(); p.A = g3b; p.B = w2b; p.M = BL; p.N = F; p.K = D; p.outb = g1b; p.auxb = H2b;
  gemm256<2><<<dim3(F / 256, BL / 256, 1), blk5, SMEM, stream>>>(p);
  // 9) transposes for attention V-operands
  k_tb2b<<<dim3(F / 32, L / 32, Bb), blk, 0, stream>>>(g1b, g1t, L, F);
  k_tb2b<<<dim3(D / 32, L / 32, Bb), blk, 0, stream>>>(g3b, g3t, L, D);
  // 10) S1 = tril(x x^T, -1)   [split-K 2, compact-tri, partials in poolB]
  clr(); p.A = xb; p.B = xb; p.M = L; p.N = L; p.K = D;
  p.sA = (long long)L * D; p.sB = (long long)L * D;
  p.part = partS1; p.ksplit = 2; p.Kc = D / 2; p.Tt = T2t;
  gemm256<7><<<dim3(T2t, 1, Bb * 2), blk5, SMEM, stream>>>(p);
  k_combtri<<<dim3(T2t, Bb), blk, 0, stream>>>(partS1, S1b, T2t, 2, L);
  // 11) x2 = relu(H1 - ss0 * S1@g1)^2   [K-limited, aux = bf16 H1b]
  clr(); p.A = S1b; p.B = g1t; p.M = L; p.N = F; p.K = L;
  p.sA = (long long)L * L; p.sB = (long long)F * L;
  p.outb = x2b; p.sOutB = (long long)L * F; p.auxb = H1b; p.sAuxF = (long long)L * F;
  p.steps = steps;
  gemm256<4><<<dim3(F / 256, L / 256, Bb), blk5, SMEM, stream>>>(p);
  // 12) X3 = x2@W2 + b2   [split-K 4, partials in poolA head (x2b lives at +80MB)]
  clr(); p.A = x2b; p.B = w2t; p.M = BL; p.N = D; p.K = F;
  p.part = partA; p.ksplit = 4; p.Kc = F / 4;
  gemm256<6><<<dim3(D / 256, BL / 256, 4), blk5, SMEM, stream>>>(p);
  k_comb<<<dim3((unsigned)(MN_D / 1024)), blk, 0, stream>>>(partA, b2, X3, D, MN_D, 4);
  // 13) S2 = tril(x2 H2^T, -1)   [split-K 4, compact-tri, partials poolA head 72MB]
  clr(); p.A = x2b; p.B = H2b; p.M = L; p.N = L; p.K = F;
  p.sA = (long long)L * F; p.sB = (long long)L * F;
  p.part = partA; p.ksplit = 4; p.Kc = F / 4; p.Tt = T2t;
  gemm256<7><<<dim3(T2t, 1, Bb * 4), blk5, SMEM, stream>>>(p);
  k_combtri<<<dim3(T2t, Bb), blk, 0, stream>>>(partA, S2b, T2t, 4, L);
  // 14) x3 = X3 - ss2 * S2@g3   [K-limited, 128^2 kernel for grid size]
  clr(); p.A = S2b; p.B = g3t; p.M = L; p.N = D; p.K = L;
  p.sA = (long long)L * L; p.sB = (long long)D * L;
  p.outf = x3; p.sOutF = (long long)L * D; p.auxf = X3; p.sAuxF = (long long)L * D; p.steps = steps;
  gemm_bt<5><<<dim3(D / 128, L / 128, Bb), blk, 0, stream>>>(p);
  // 15) exclusive cumsums -> fast_scale / fast_bias
  k_scanpart<<<dim3(D / 256, 16, Bb), blk, 0, stream>>>(gsc, G4, psc, pbi, L, D);
  k_scanapply<<<dim3(D / 256, 16, Bb), blk, 0, stream>>>(gsc, G4, psc, pbi, ln_scale, ln_bias,
                                                         steps, fs, fb, L, D);
  // 16) x4 = LN(x3)*fast_scale + fast_bias
  k_lnfwd2<<<dim3(BL), blk, 0, stream>>>(x3, fs, fb, x4b, D);
  // 17) out = x4@Wu + bu
  clr(); p.A = x4b; p.B = wut; p.M = BL; p.N = V; p.K = D; p.outf = (float*)d_out; p.bias = bu;
  gemm256<0><<<dim3(V / 256, BL / 256, 1), blk5, SMEM, stream>>>(p);
}

// Round 6
// 1083.354 us; speedup vs baseline: 1.4567x; 1.0683x over previous
//
#include <hip/hip_runtime.h>
#include <cstdint>

typedef unsigned short ushort_t;
typedef __bf16 bf16x8 __attribute__((ext_vector_type(8)));
typedef float f32x4 __attribute__((ext_vector_type(4)));
typedef ushort_t us8 __attribute__((ext_vector_type(8)));

// ---------- helpers ----------
__device__ __forceinline__ ushort_t f2bf(float f) {
  union { float f; unsigned int u; } v; v.f = f;
  unsigned int u = v.u;
  unsigned int r = (u + 0x7fffu + ((u >> 16) & 1u)) >> 16;
  return (ushort_t)r;
}
__device__ __forceinline__ float bf2f(ushort_t u) {
  union { unsigned int u; float f; } v; v.u = ((unsigned int)u) << 16; return v.f;
}

#define GLOAD16(gp, lp)                                                              \
  __builtin_amdgcn_global_load_lds(                                                  \
      reinterpret_cast<const __attribute__((address_space(1))) unsigned int*>(       \
          reinterpret_cast<uintptr_t>(gp)),                                          \
      reinterpret_cast<__attribute__((address_space(3))) unsigned int*>(             \
          reinterpret_cast<uintptr_t>(lp)),                                          \
      16, 0, 0)

// EPI: 0 = outf = acc + bias                     (out)
//      8 = outb = bf16(acc + bias)               (logits)
//      1 = outb = bf16(acc+bias); outb2 = bf16(relu^2)    (H1b + H2b)
//      2 = outb = bf16(acc * 2*sqrt(auxb))       (g1)
//      4 = outb = bf16(relu(bf2f(auxb) - ss0*acc)^2); K-limit  (x2)
//      5 = outf = auxf - ss2*acc; K-limit        (x3)
//      6 = split-K partial, full-matrix f32      (H3, G4, X3 stage 1)
//      7 = split-K partial, compact-tri grid, 256x256 tiles   (S1, S2 stage 1)
struct GemmP {
  const ushort_t* A; const ushort_t* B;
  int M, N, K;
  long long sA, sB;
  float* outf;   long long sOutF;
  ushort_t* outb; long long sOutB;
  ushort_t* outb2;
  const float* bias;
  const float* auxf; long long sAuxF;   // sAuxF doubles as aux (f32 or bf16) stride
  const ushort_t* auxb;
  const float* steps;
  float* part; int ksplit, Kc, Tt;
};

// ---------- 256x256 GEMM: 8 waves, BK=32, 3-buffer counted-vmcnt pipeline ----------
// LDS slot-XOR swizzle (T2, rule #21): within each 16-row x 32-col (1KB) chunk,
// 16B slot s' in LDS holds global slot s' ^ sigma(row), sigma(r) = (r>>1)&3.
// Applied via pre-swizzled GLOBAL source (linear gload_lds dest) + swizzled ds_read.
template <int EPI>
__global__ __launch_bounds__(512, 2) void gemm256(GemmP p) {
  const int nwg = gridDim.x * gridDim.y;
  const int orig = blockIdx.y * gridDim.x + blockIdx.x;
  const int xcd = orig & 7, loc = orig >> 3;
  const int q8 = nwg >> 3, r8 = nwg & 7;
  const int wg = (xcd < r8) ? (xcd * (q8 + 1) + loc) : (r8 * (q8 + 1) + (xcd - r8) * q8 + loc);
  int mt, nt;
  if (EPI == 7) {            // compact lower-tri tile index -> (mt, nt)
    int t_ = wg;
    mt = (int)((sqrtf(8.f * t_ + 1.f) - 1.f) * 0.5f);
    while ((mt + 1) * (mt + 2) / 2 <= t_) mt++;
    while (mt * (mt + 1) / 2 > t_) mt--;
    nt = t_ - mt * (mt + 1) / 2;
  } else {
    nt = wg % gridDim.x; mt = wg / gridDim.x;
  }
  const int m0 = mt * 256, n0 = nt * 256;

  int bz = blockIdx.z, ks = 0;
  if (EPI == 6 || EPI == 7) { bz = blockIdx.z / p.ksplit; ks = blockIdx.z % p.ksplit; }

  const ushort_t* A = p.A + (size_t)bz * p.sA;
  const ushort_t* B = p.B + (size_t)bz * p.sB;

  int kbeg = 0, kend = p.K;
  if (EPI == 6 || EPI == 7) { kbeg = ks * p.Kc; kend = kbeg + p.Kc; }
  else if (EPI == 4) kend = min(p.K, m0 + 256);

  extern __shared__ ushort_t smem[];      // 3*(8K+8K) elems = 96KB
  ushort_t* sA = smem;
  ushort_t* sB = smem + 3 * 8192;

  const int tid = threadIdx.x;
  const int wid = tid >> 6, lane = tid & 63;
  const int wm = wid >> 2, wn = wid & 3;

  f32x4 acc[8][4];
#pragma unroll
  for (int i = 0; i < 8; i++)
#pragma unroll
    for (int j = 0; j < 4; j++) acc[i][j] = f32x4{0.f, 0.f, 0.f, 0.f};

  // staging: chunk = 16 rows x 32 cols = 1KB. Wave w stages A-chunks {w, w+8},
  // B-chunks {w, w+8}. Source col pre-swizzled so linear LDS dest lands swizzled.
  const int lr = lane >> 2;
  const int lcsw = (((lane & 3) ^ ((lr >> 1) & 3)) * 8);
  const int rT0 = wid * 16 + lr;
  const int rT1 = 128 + wid * 16 + lr;
  const ushort_t* gA0 = A + (size_t)(m0 + rT0) * p.K + lcsw;
  const ushort_t* gA1 = A + (size_t)(m0 + rT1) * p.K + lcsw;
  const ushort_t* gB0 = B + (size_t)(n0 + rT0) * p.K + lcsw;
  const ushort_t* gB1 = B + (size_t)(n0 + rT1) * p.K + lcsw;
  ushort_t* lA0 = &sA[wid * 512];
  ushort_t* lA1 = &sA[(8 + wid) * 512];
  ushort_t* lB0 = &sB[wid * 512];
  ushort_t* lB1 = &sB[(8 + wid) * 512];

  // ds_read offsets (loop-invariant): frag i of A at chunk (wm*8+i), row fr,
  // swizzled 16B slot (q ^ sigma(fr)).
  const int fr = lane & 15;
  const int q = lane >> 4;
  const int slot = (q ^ ((fr >> 1) & 3)) * 8;
  int offA[8], offB[4];
#pragma unroll
  for (int i = 0; i < 8; i++) offA[i] = (wm * 8 + i) * 512 + fr * 32 + slot;
#pragma unroll
  for (int j = 0; j < 4; j++) offB[j] = (wn * 4 + j) * 512 + fr * 32 + slot;

  const int nIter = (kend - kbeg) >> 5;
  auto stage = [&](int t, int buf) {
    const int kk = kbeg + t * 32;
    const int o = buf * 8192;
    GLOAD16(gA0 + kk, lA0 + o);
    GLOAD16(gA1 + kk, lA1 + o);
    GLOAD16(gB0 + kk, lB0 + o);
    GLOAD16(gB1 + kk, lB1 + o);
  };
  stage(0, 0);
  if (nIter > 1) stage(1, 1);

  for (int t = 0; t < nIter; ++t) {
    if (t + 1 < nIter) { asm volatile("s_waitcnt vmcnt(4)" ::: "memory"); }
    else               { asm volatile("s_waitcnt vmcnt(0)" ::: "memory"); }
    __builtin_amdgcn_s_barrier();
    __builtin_amdgcn_sched_barrier(0);
    if (t + 2 < nIter) stage(t + 2, (t + 2) % 3);
    const int co = (t % 3) * 8192;
    bf16x8 av[8], bv[4];
#pragma unroll
    for (int j = 0; j < 4; j++) bv[j] = *reinterpret_cast<const bf16x8*>(&sB[co + offB[j]]);
#pragma unroll
    for (int i = 0; i < 8; i++) {
      av[i] = *reinterpret_cast<const bf16x8*>(&sA[co + offA[i]]);
#pragma unroll
      for (int j = 0; j < 4; j++)
        acc[i][j] = __builtin_amdgcn_mfma_f32_16x16x32_bf16(av[i], bv[j], acc[i][j], 0, 0, 0);
    }
  }

  const int fq = q;
  float ss = 0.f;
  if (EPI == 4) ss = p.steps[0];
  float* outf = p.outf ? p.outf + (size_t)bz * p.sOutF : nullptr;
  ushort_t* outb = p.outb ? p.outb + (size_t)bz * p.sOutB : nullptr;
  ushort_t* outb2 = p.outb2;
  const ushort_t* auxb = p.auxb ? p.auxb + (size_t)bz * p.sAuxF : nullptr;
  float* partT = nullptr;
  if (EPI == 6) partT = p.part + (size_t)blockIdx.z * p.M * p.N;
  if (EPI == 7) partT = p.part + ((size_t)blockIdx.z * p.Tt + wg) * 65536;

#pragma unroll
  for (int i = 0; i < 8; i++) {
#pragma unroll
    for (int j = 0; j < 4; j++) {
#pragma unroll
      for (int r2 = 0; r2 < 4; r2++) {
        int lrow = wm * 128 + i * 16 + fq * 4 + r2;
        int lcol = wn * 64 + j * 16 + fr;
        int row = m0 + lrow, col = n0 + lcol;
        size_t g = (size_t)row * p.N + col;
        float v = acc[i][j][r2];
        if (EPI == 0) {
          outf[g] = v + (p.bias ? p.bias[col] : 0.f);
        } else if (EPI == 8) {
          outb[g] = f2bf(v + p.bias[col]);
        } else if (EPI == 1) {
          v += p.bias[col];
          outb[g] = f2bf(v);
          float rl = fmaxf(v, 0.f);
          outb2[g] = f2bf(rl * rl);
        } else if (EPI == 2) {
          outb[g] = f2bf(v * 2.f * sqrtf(bf2f(auxb[g])));
        } else if (EPI == 4) {
          float x1 = bf2f(auxb[g]) - ss * v;
          float rl = fmaxf(x1, 0.f);
          outb[g] = f2bf(rl * rl);
        } else if (EPI == 6) {
          partT[g] = v;
        } else if (EPI == 7) {
          partT[lrow * 256 + lcol] = v;
        }
      }
    }
  }
}

// ---------- 128x128 GEMM (proven R4 pipeline) -- kept for x3 (EPI 5) ----------
template <int EPI>
__global__ __launch_bounds__(256) void gemm_bt(GemmP p) {
  const int nwg = gridDim.x * gridDim.y;
  const int orig = blockIdx.y * gridDim.x + blockIdx.x;
  const int xcd = orig & 7, loc = orig >> 3;
  const int q = nwg >> 3, r = nwg & 7;
  const int wg = (xcd < r) ? (xcd * (q + 1) + loc) : (r * (q + 1) + (xcd - r) * q + loc);
  const int nt = wg % gridDim.x, mt = wg / gridDim.x;
  const int m0 = mt * 128, n0 = nt * 128;
  const int bz = blockIdx.z;

  const ushort_t* A = p.A + (size_t)bz * p.sA;
  const ushort_t* B = p.B + (size_t)bz * p.sB;

  int kend = p.K;
  if (EPI == 5) kend = min(p.K, m0 + 128);

  __shared__ ushort_t sA[3 * 128 * 32];
  __shared__ ushort_t sB[3 * 128 * 32];

  const int tid = threadIdx.x;
  const int wid = tid >> 6, lane = tid & 63;
  const int wm = wid >> 1, wn = wid & 1;

  f32x4 acc[4][4];
#pragma unroll
  for (int i = 0; i < 4; i++)
#pragma unroll
    for (int j = 0; j < 4; j++) acc[i][j] = f32x4{0.f, 0.f, 0.f, 0.f};

  const int lr = lane >> 2;
  const int lc = (lane & 3) * 8;
  const int rA0 = wid * 16 + lr;
  const int rA1 = 64 + wid * 16 + lr;
  const ushort_t* gA0 = A + (size_t)(m0 + rA0) * p.K + lc;
  const ushort_t* gA1 = A + (size_t)(m0 + rA1) * p.K + lc;
  const ushort_t* gB0 = B + (size_t)(n0 + rA0) * p.K + lc;
  const ushort_t* gB1 = B + (size_t)(n0 + rA1) * p.K + lc;
  ushort_t* lA0 = &sA[wid * 512];
  ushort_t* lA1 = &sA[(4 + wid) * 512];
  ushort_t* lB0 = &sB[wid * 512];
  ushort_t* lB1 = &sB[(4 + wid) * 512];

  const int fr = lane & 15;
  const int kb = (lane >> 4) * 8;

  const int nIter = kend >> 5;
  auto stage = [&](int t, int buf) {
    const int kk = t * 32;
    const int o = buf * 4096;
    GLOAD16(gA0 + kk, lA0 + o);
    GLOAD16(gA1 + kk, lA1 + o);
    GLOAD16(gB0 + kk, lB0 + o);
    GLOAD16(gB1 + kk, lB1 + o);
  };
  stage(0, 0);
  if (nIter > 1) stage(1, 1);

  for (int t = 0; t < nIter; ++t) {
    if (t + 1 < nIter) { asm volatile("s_waitcnt vmcnt(4)" ::: "memory"); }
    else               { asm volatile("s_waitcnt vmcnt(0)" ::: "memory"); }
    __builtin_amdgcn_s_barrier();
    __builtin_amdgcn_sched_barrier(0);
    if (t + 2 < nIter) stage(t + 2, (t + 2) % 3);
    const int co = (t % 3) * 4096;
    bf16x8 av[4], bv[4];
#pragma unroll
    for (int i = 0; i < 4; i++) {
      av[i] = *reinterpret_cast<const bf16x8*>(&sA[co + (wm * 64 + i * 16 + fr) * 32 + kb]);
      bv[i] = *reinterpret_cast<const bf16x8*>(&sB[co + (wn * 64 + i * 16 + fr) * 32 + kb]);
    }
#pragma unroll
    for (int i = 0; i < 4; i++)
#pragma unroll
      for (int j = 0; j < 4; j++)
        acc[i][j] = __builtin_amdgcn_mfma_f32_16x16x32_bf16(av[i], bv[j], acc[i][j], 0, 0, 0);
  }

  const int fq = lane >> 4;
  float ss = (EPI == 5) ? p.steps[2] : 0.f;
  float* outf = p.outf ? p.outf + (size_t)bz * p.sOutF : nullptr;
  const float* auxf = p.auxf ? p.auxf + (size_t)bz * p.sAuxF : nullptr;

#pragma unroll
  for (int i = 0; i < 4; i++) {
#pragma unroll
    for (int j = 0; j < 4; j++) {
#pragma unroll
      for (int r2 = 0; r2 < 4; r2++) {
        int row = m0 + wm * 64 + i * 16 + fq * 4 + r2;
        int col = n0 + wn * 64 + j * 16 + fr;
        size_t g = (size_t)row * p.N + col;
        float v = acc[i][j][r2];
        if (EPI == 5) {
          outf[g] = auxf[g] - ss * v;
        } else {
          outf[g] = v + (p.bias ? p.bias[col] : 0.f);
        }
      }
    }
  }
}

// ---------- split-K combines ----------
__global__ __launch_bounds__(256) void k_comb(const float* part, const float* bias, float* out,
                                              int N, size_t MN, int S) {
  size_t e = ((size_t)blockIdx.x * 256 + threadIdx.x) * 4;
  if (e >= MN) return;
  float4 s = *(const float4*)(part + e);
  for (int p_ = 1; p_ < S; p_++) {
    float4 v = *(const float4*)(part + (size_t)p_ * MN + e);
    s.x += v.x; s.y += v.y; s.z += v.z; s.w += v.w;
  }
  if (bias) {
    int col = (int)(e % (size_t)N);
    s.x += bias[col]; s.y += bias[col + 1]; s.z += bias[col + 2]; s.w += bias[col + 3];
  }
  *(float4*)(out + e) = s;
}

// 256x256 compact-tri combine: S_bf16 = tril(sum_s part[s], -1)
__global__ __launch_bounds__(256) void k_combtri(const float* part, ushort_t* out, int Tt, int S,
                                                 int L) {
  int t = blockIdx.x, bz = blockIdx.y;
  int mt = (int)((sqrtf(8.f * t + 1.f) - 1.f) * 0.5f);
  while ((mt + 1) * (mt + 2) / 2 <= t) mt++;
  while (mt * (mt + 1) / 2 > t) mt--;
  int nt = t - mt * (mt + 1) / 2;
  const float* pb = part + ((size_t)bz * S * Tt + t) * 65536;
  ushort_t* ob = out + (size_t)bz * L * L;
  for (int e4 = threadIdx.x; e4 < 16384; e4 += 256) {
    int e = e4 * 4;
    float4 s = *(const float4*)(pb + e);
    for (int p_ = 1; p_ < S; p_++) {
      float4 v = *(const float4*)(pb + (size_t)p_ * Tt * 65536 + e);
      s.x += v.x; s.y += v.y; s.z += v.z; s.w += v.w;
    }
    int lr = e >> 8, lc2 = e & 255;
    int row = mt * 256 + lr, col = nt * 256 + lc2;
    ushort4 o;
    o.x = (col < row) ? f2bf(s.x) : (ushort_t)0;
    o.y = (col + 1 < row) ? f2bf(s.y) : (ushort_t)0;
    o.z = (col + 2 < row) ? f2bf(s.z) : (ushort_t)0;
    o.w = (col + 3 < row) ? f2bf(s.w) : (ushort_t)0;
    *(ushort4*)(&ob[(size_t)row * L + col]) = o;
  }
}

// ---------- auxiliary kernels ----------
__global__ __launch_bounds__(256) void k_conv(const float* in, ushort_t* out, size_t n) {
  size_t i = ((size_t)blockIdx.x * 256 + threadIdx.x) * 4;
  if (i >= n) return;
  float4 v = *(const float4*)(in + i);
  out[i] = f2bf(v.x); out[i + 1] = f2bf(v.y); out[i + 2] = f2bf(v.z); out[i + 3] = f2bf(v.w);
}

__global__ __launch_bounds__(256) void k_tconv(const float* in, ushort_t* out, int R, int C) {
  __shared__ float t[32][33];
  int c0 = blockIdx.x * 32, r0 = blockIdx.y * 32;
  int tx = threadIdx.x & 31, ty = threadIdx.x >> 5;
#pragma unroll
  for (int i = ty; i < 32; i += 8) t[i][tx] = in[(size_t)(r0 + i) * C + c0 + tx];
  __syncthreads();
#pragma unroll
  for (int i = ty; i < 32; i += 8) out[(size_t)(c0 + i) * R + r0 + tx] = f2bf(t[tx][i]);
}

// fused weight prep: one f32 read -> straight bf16 copy + transposed bf16 copy
__global__ __launch_bounds__(256) void k_wprep(const float* in, ushort_t* outS, ushort_t* outT,
                                               int R, int C) {
  __shared__ float t[32][33];
  int c0 = blockIdx.x * 32, r0 = blockIdx.y * 32;
  int tx = threadIdx.x & 31, ty = threadIdx.x >> 5;
#pragma unroll
  for (int i = ty; i < 32; i += 8) {
    float v = in[(size_t)(r0 + i) * C + c0 + tx];
    t[i][tx] = v;
    outS[(size_t)(r0 + i) * C + c0 + tx] = f2bf(v);
  }
  __syncthreads();
#pragma unroll
  for (int i = ty; i < 32; i += 8) out:
  ;
#pragma unroll
  for (int i = ty; i < 32; i += 8) outT[(size_t)(c0 + i) * R + r0 + tx] = f2bf(t[tx][i]);
}

__global__ __launch_bounds__(256) void k_tb2b(const ushort_t* in, ushort_t* out, int L, int C) {
  __shared__ ushort_t t[32][33];
  int b = blockIdx.z;
  const ushort_t* ib = in + (size_t)b * L * C;
  ushort_t* ob = out + (size_t)b * C * L;
  int c0 = blockIdx.x * 32, l0 = blockIdx.y * 32;
  int tx = threadIdx.x & 31, ty = threadIdx.x >> 5;
#pragma unroll
  for (int i = ty; i < 32; i += 8) t[i][tx] = ib[(size_t)(l0 + i) * C + c0 + tx];
  __syncthreads();
#pragma unroll
  for (int i = ty; i < 32; i += 8) ob[(size_t)(c0 + i) * L + l0 + tx] = t[tx][i];
}

__device__ __forceinline__ void blockRed2(float& a, float& b, float* red) {
#pragma unroll
  for (int o = 32; o; o >>= 1) { a += __shfl_down(a, o); b += __shfl_down(b, o); }
  int w = threadIdx.x >> 6;
  if ((threadIdx.x & 63) == 0) { red[w] = a; red[4 + w] = b; }
  __syncthreads();
  a = red[0] + red[1] + red[2] + red[3];
  b = red[4] + red[5] + red[6] + red[7];
  __syncthreads();
}

// fused split-K combine + LN forward (H3 path): h3 = sum_s part[s] + b2; LN; h4b
__global__ __launch_bounds__(256) void k_lncomb(const float* part, const float* bias,
                                                const float* sc, const float* bi, float* nout,
                                                float* rstd, ushort_t* yb, size_t MN, int D,
                                                int S) {
  __shared__ float red[8];
  int row = blockIdx.x;
  int d = threadIdx.x * 4;          // D = 1024 = 256*4
  size_t g = (size_t)row * D + d;
  float4 v = *(const float4*)(part + g);
  for (int s_ = 1; s_ < S; s_++) {
    float4 w = *(const float4*)(part + (size_t)s_ * MN + g);
    v.x += w.x; v.y += w.y; v.z += w.z; v.w += w.w;
  }
  float4 bb = *(const float4*)(bias + d);
  v.x += bb.x; v.y += bb.y; v.z += bb.z; v.w += bb.w;
  float s1 = v.x + v.y + v.z + v.w;
  float s2 = v.x * v.x + v.y * v.y + v.z * v.z + v.w * v.w;
  blockRed2(s1, s2, red);
  float mu = s1 / D;
  float var = s2 / D - mu * mu;
  float rs = rsqrtf(var + 1e-6f);
  float4 nv;
  nv.x = (v.x - mu) * rs; nv.y = (v.y - mu) * rs; nv.z = (v.z - mu) * rs; nv.w = (v.w - mu) * rs;
  *(float4*)(nout + g) = nv;
  float4 scv = *(const float4*)(sc + d);
  float4 biv = *(const float4*)(bi + d);
  ushort4 o;
  o.x = f2bf(nv.x * scv.x + biv.x);
  o.y = f2bf(nv.y * scv.y + biv.y);
  o.z = f2bf(nv.z * scv.z + biv.z);
  o.w = f2bf(nv.w * scv.w + biv.w);
  *(ushort4*)(yb + g) = o;
  if (threadIdx.x == 0) rstd[row] = rs;
}

__global__ __launch_bounds__(256) void k_lnfwd2(const float* X, const float* fs, const float* fb,
                                                ushort_t* yb, int D) {
  __shared__ float red[8];
  int row = blockIdx.x;
  const float* x = X + (size_t)row * D;
  float s = 0.f, s2 = 0.f;
  for (int d = threadIdx.x; d < D; d += 256) { float v = x[d]; s += v; s2 += v * v; }
  blockRed2(s, s2, red);
  float mu = s / D;
  float var = s2 / D - mu * mu;
  float rs = rsqrtf(var + 1e-6f);
  for (int d = threadIdx.x; d < D; d += 256) {
    size_t g = (size_t)row * D + d;
    float nv = (x[d] - mu) * rs;
    yb[g] = f2bf(nv * fs[g] + fb[g]);
  }
}

__global__ __launch_bounds__(256) void k_lnbwd(const float* G, const float* nn, const float* rstd,
                                               const float* sc, ushort_t* g3b, float* gsc, int D) {
  __shared__ float red[8];
  int row = blockIdx.x;
  const float* g = G + (size_t)row * D;
  const float* n_ = nn + (size_t)row * D;
  float sa = 0.f, sb = 0.f;
  for (int d = threadIdx.x; d < D; d += 256) {
    float dn = g[d] * sc[d];
    sa += dn; sb += dn * n_[d];
  }
  blockRed2(sa, sb, red);
  float a = sa / D, b = sb / D, rs = rstd[row];
  for (int d = threadIdx.x; d < D; d += 256) {
    size_t gi = (size_t)row * D + d;
    float dn = g[d] * sc[d];
    g3b[gi] = f2bf(rs * (dn - a - n_[d] * b));
    gsc[gi] = g[d] * n_[d];
  }
}

__global__ __launch_bounds__(256) void k_wsum(const float* w, float* o, int n) {
  __shared__ float red[4];
  float s = 0.f;
  for (int i = threadIdx.x; i < n; i += 256) s += w[i];
#pragma unroll
  for (int d = 32; d; d >>= 1) s += __shfl_down(s, d);
  if ((threadIdx.x & 63) == 0) red[threadIdx.x >> 6] = s;
  __syncthreads();
  if (threadIdx.x == 0) o[0] = fmaxf(red[0] + red[1] + red[2] + red[3], 1e-8f);
}

// register-staged fused softmax-grad: V=8192, 256 thr, 32 elem/thread in VGPRs.
// One global pass over logits(bf16) + labels(f32); vectorized 16B loads/stores.
__global__ __launch_bounds__(256) void k_softgrad(const ushort_t* logits, const float* labels,
                                                  const float* w, const float* wsum,
                                                  ushort_t* dlb, int V) {
  __shared__ float red[8];
  const int row = blockIdx.x;
  const int tid = threadIdx.x;
  const ushort_t* l = logits + (size_t)row * V + tid * 32;
  const float* y = labels + (size_t)row * V + tid * 32;
  float lv[32], yv[32];
#pragma unroll
  for (int i = 0; i < 4; i++) {
    us8 u = *reinterpret_cast<const us8*>(l + i * 8);
#pragma unroll
    for (int j = 0; j < 8; j++) lv[i * 8 + j] = bf2f(u[j]);
  }
#pragma unroll
  for (int i = 0; i < 8; i++) {
    float4 v = *reinterpret_cast<const float4*>(y + i * 4);
    yv[i * 4] = v.x; yv[i * 4 + 1] = v.y; yv[i * 4 + 2] = v.z; yv[i * 4 + 3] = v.w;
  }
  float m = lv[0], t = yv[0];
#pragma unroll
  for (int i = 1; i < 32; i++) { m = fmaxf(m, lv[i]); t += yv[i]; }
  // block reduce: max(m) and sum(t)
#pragma unroll
  for (int o = 32; o; o >>= 1) { m = fmaxf(m, __shfl_down(m, o)); t += __shfl_down(t, o); }
  int wv = tid >> 6;
  if ((tid & 63) == 0) { red[wv] = m; red[4 + wv] = t; }
  __syncthreads();
  m = fmaxf(fmaxf(red[0], red[1]), fmaxf(red[2], red[3]));
  t = red[4] + red[5] + red[6] + red[7];
  __syncthreads();
  float s = 0.f;
#pragma unroll
  for (int i = 0; i < 32; i++) { lv[i] = expf(lv[i] - m); s += lv[i]; }
#pragma unroll
  for (int o = 32; o; o >>= 1) s += __shfl_down(s, o);
  if ((tid & 63) == 0) red[wv] = s;
  __syncthreads();
  s = red[0] + red[1] + red[2] + red[3];
  float c = w[row] / wsum[0];
  float ci = c * t / s;
  ushort_t* dl = dlb + (size_t)row * V + tid * 32;
#pragma unroll
  for (int i = 0; i < 4; i++) {
    us8 o;
#pragma unroll
    for (int j = 0; j < 8; j++) o[j] = f2bf(ci * lv[i * 8 + j] - c * yv[i * 8 + j]);
    *reinterpret_cast<us8*>(dl + i * 8) = o;
  }
}

__global__ __launch_bounds__(256) void k_scanpart(const float* gs, const float* gb, float* ps,
                                                  float* pb, int L, int D) {
  int d = blockIdx.x * 256 + threadIdx.x;
  int seg = blockIdx.y, b = blockIdx.z;
  const int SEGL = L / 16;
  size_t base = ((size_t)b * L + seg * SEGL) * D + d;
  float s1 = 0.f, s2 = 0.f;
  for (int i = 0; i < SEGL; i++) { s1 += gs[base + (size_t)i * D]; s2 += gb[base + (size_t)i * D]; }
  size_t pi = ((size_t)b * 16 + seg) * D + d;
  ps[pi] = s1; pb[pi] = s2;
}

__global__ __launch_bounds__(256) void k_scanapply(const float* gs, const float* gb,
                                                   const float* ps, const float* pb,
                                                   const float* sc, const float* bi,
                                                   const float* steps, float* fs, float* fb,
                                                   int L, int D) {
  int d = blockIdx.x * 256 + threadIdx.x;
  int seg = blockIdx.y, b = blockIdx.z;
  const int SEGL = L / 16;
  float ss = steps[3];
  float rs_ = 0.f, rb_ = 0.f;
  for (int s = 0; s < seg; s++) {
    size_t pi = ((size_t)b * 16 + s) * D + d;
    rs_ += ps[pi]; rb_ += pb[pi];
  }
  float s0 = sc[d], b0 = bi[d];
  size_t base = ((size_t)b * L + seg * SEGL) * D + d;
  for (int i = 0; i < SEGL; i++) {
    size_t g = base + (size_t)i * D;
    fs[g] = s0 - ss * rs_;
    fb[g] = b0 - ss * rb_;
    rs_ += gs[g]; rb_ += gb[g];
  }
}

// ---------- orchestration ----------
extern "C" void kernel_launch(void* const* d_in, const int* in_sizes, int n_in, void* d_out,
                              int out_size, void* d_ws, size_t ws_size, hipStream_t stream) {
  const float* x        = (const float*)d_in[0];
  const float* labels   = (const float*)d_in[1];
  const float* weights  = (const float*)d_in[2];
  const float* W1       = (const float*)d_in[3];
  const float* b1       = (const float*)d_in[4];
  const float* W2       = (const float*)d_in[5];
  const float* b2       = (const float*)d_in[6];
  const float* ln_scale = (const float*)d_in[7];
  const float* ln_bias  = (const float*)d_in[8];
  const float* Wu       = (const float*)d_in[9];
  const float* bu       = (const float*)d_in[10];
  const float* steps    = (const float*)d_in[11];

  const int BL = in_sizes[2];   // 4096
  const int D  = in_sizes[7];   // 1024
  const int F  = in_sizes[4];   // 4096
  const int V  = in_sizes[10];  // 8192
  const int Bb = 2, L = BL / Bb;
  const int T2t = (L / 256) * (L / 256 + 1) / 2;   // 36 live 256-tri tiles
  const unsigned SMEM = 3 * 8192 * 2 * 2;          // 96 KB dynamic LDS

  char* ws = (char*)d_ws;
  size_t off = 0;
  auto take = [&](size_t b) { char* p = ws + off; off = (off + b + 255) & ~(size_t)255; return p; };

  ushort_t* xb   = (ushort_t*)take((size_t)BL * D * 2);
  ushort_t* w1t  = (ushort_t*)take((size_t)F * D * 2);
  ushort_t* w2t  = (ushort_t*)take((size_t)D * F * 2);
  ushort_t* w2b  = (ushort_t*)take((size_t)F * D * 2);
  ushort_t* wut  = (ushort_t*)take((size_t)V * D * 2);
  ushort_t* wub  = (ushort_t*)take((size_t)D * V * 2);
  ushort_t* H1b  = (ushort_t*)take((size_t)BL * F * 2);
  ushort_t* H2b  = (ushort_t*)take((size_t)BL * F * 2);
  float*    nbuf = (float*)take((size_t)BL * D * 4);
  float*    rstd = (float*)take((size_t)BL * 4);
  ushort_t* h4b  = (ushort_t*)take((size_t)BL * D * 2);
  float*    wsumb= (float*)take(256);
  float*    G4   = (float*)take((size_t)BL * D * 4);   // also g_bias
  float*    gsc  = (float*)take((size_t)BL * D * 4);   // g_scale
  ushort_t* g3b  = (ushort_t*)take((size_t)BL * D * 2);
  ushort_t* g3t  = (ushort_t*)take((size_t)BL * D * 2);
  float*    fs   = (float*)take((size_t)BL * D * 4);
  float*    fb   = (float*)take((size_t)BL * D * 4);
  ushort_t* x4b  = (ushort_t*)take((size_t)BL * D * 2);
  float*    psc  = (float*)take((size_t)Bb * 16 * D * 4);
  float*    pbi  = (float*)take((size_t)Bb * 16 * D * 4);
  // poolA (134MB): logitsb bf16 / split-K partials -> later {g1b, g1t, S1b, x2b}
  char* poolA = take((size_t)BL * V * 4);
  ushort_t* logitsb = (ushort_t*)poolA;
  float*    partA  = (float*)poolA;
  ushort_t* g1b = (ushort_t*)poolA;
  ushort_t* g1t = (ushort_t*)(poolA + (size_t)BL * F * 2);
  ushort_t* S1b = (ushort_t*)(poolA + (size_t)BL * F * 4);
  ushort_t* x2b = (ushort_t*)(poolA + (size_t)BL * F * 4 + (size_t)Bb * L * L * 2);
  // poolB (64MB): dlb bf16 -> later {S2b, X3, x3}; head hosts S1 partials (36MB)
  char* poolB = take((size_t)BL * V * 2);
  ushort_t* dlb = (ushort_t*)poolB;
  float*    partS1 = (float*)poolB;
  ushort_t* S2b = (ushort_t*)poolB;
  float*    X3  = (float*)(poolB + (size_t)Bb * L * L * 2);
  float*    x3  = (float*)(poolB + (size_t)Bb * L * L * 2 + (size_t)BL * D * 4);

  dim3 blk(256), blk5(512);
  const size_t MN_D = (size_t)BL * D;

  k_conv<<<dim3((unsigned)((size_t)BL * D / 1024)), blk, 0, stream>>>(x, xb, (size_t)BL * D);
  k_tconv<<<dim3(F / 32, D / 32), blk, 0, stream>>>(W1, w1t, D, F);
  k_wprep<<<dim3(D / 32, F / 32), blk, 0, stream>>>(W2, w2b, w2t, F, D);   // straight + (D,F)T
  k_wprep<<<dim3(V / 32, D / 32), blk, 0, stream>>>(Wu, wub, wut, D, V);   // straight + (V,D)T

  GemmP p;
  auto clr = [&]() { p = GemmP{}; };

  // 1) H1b = bf16(x@W1+b1) ; H2b = bf16(relu^2)
  clr(); p.A = xb; p.B = w1t; p.M = BL; p.N = F; p.K = D;
  p.outb = H1b; p.outb2 = H2b; p.bias = b1;
  gemm256<1><<<dim3(F / 256, BL / 256, 1), blk5, SMEM, stream>>>(p);
  // 2) H3 partials [split-K 4] -> fused combine+LN fwd
  clr(); p.A = H2b; p.B = w2t; p.M = BL; p.N = D; p.K = F;
  p.part = partA; p.ksplit = 4; p.Kc = F / 4;
  gemm256<6><<<dim3(D / 256, BL / 256, 4), blk5, SMEM, stream>>>(p);
  k_lncomb<<<dim3(BL), blk, 0, stream>>>(partA, b2, ln_scale, ln_bias, nbuf, rstd, h4b, MN_D, D, 4);
  // 4) logits = bf16(h4@Wu + bu)
  clr(); p.A = h4b; p.B = wut; p.M = BL; p.N = V; p.K = D; p.outb = logitsb; p.bias = bu;
  gemm256<8><<<dim3(V / 256, BL / 256, 1), blk5, SMEM, stream>>>(p);
  // 5) fused softmax grad (register-staged)
  k_wsum<<<dim3(1), blk, 0, stream>>>(weights, wsumb, BL);
  k_softgrad<<<dim3(BL), blk, 0, stream>>>(logitsb, labels, weights, wsumb, dlb, V);
  // 6) G4 = dlogits @ Wu^T   [split-K 4]
  clr(); p.A = dlb; p.B = wub; p.M = BL; p.N = D; p.K = V;
  p.part = partA; p.ksplit = 4; p.Kc = V / 4;
  gemm256<6><<<dim3(D / 256, BL / 256, 4), blk5, SMEM, stream>>>(p);
  k_comb<<<dim3((unsigned)(MN_D / 1024)), blk, 0, stream>>>(partA, nullptr, G4, D, MN_D, 4);
  // 7) LN bwd -> g3, g_scale
  k_lnbwd<<<dim3(BL), blk, 0, stream>>>(G4, nbuf, rstd, ln_scale, g3b, gsc, D);
  // 8) g1 = (g3 @ W2^T) * 2*sqrt(H2)
  clr(); p.A = g3b; p.B = w2b; p.M = BL; p.N = F; p.K = D; p.outb = g1b; p.auxb = H2b;
  gemm256<2><<<dim3(F / 256, BL / 256, 1), blk5, SMEM, stream>>>(p);
  // 9) transposes for attention V-operands
  k_tb2b<<<dim3(F / 32, L / 32, Bb), blk, 0, stream>>>(g1b, g1t, L, F);
  k_tb2b<<<dim3(D / 32, L / 32, Bb), blk, 0, stream>>>(g3b, g3t, L, D);
  // 10) S1 = tril(x x^T, -1)   [split-K 2, compact-tri, partials in poolB]
  clr(); p.A = xb; p.B = xb; p.M = L; p.N = L; p.K = D;
  p.sA = (long long)L * D; p.sB = (long long)L * D;
  p.part = partS1; p.ksplit = 2; p.Kc = D / 2; p.Tt = T2t;
  gemm256<7><<<dim3(T2t, 1, Bb * 2), blk5, SMEM, stream>>>(p);
  k_combtri<<<dim3(T2t, Bb), blk, 0, stream>>>(partS1, S1b, T2t, 2, L);
  // 11) x2 = relu(H1 - ss0 * S1@g1)^2   [K-limited, aux = bf16 H1b]
  clr(); p.A = S1b; p.B = g1t; p.M = L; p.N = F; p.K = L;
  p.sA = (long long)L * L; p.sB = (long long)F * L;
  p.outb = x2b; p.sOutB = (long long)L * F; p.auxb = H1b; p.sAuxF = (long long)L * F;
  p.steps = steps;
  gemm256<4><<<dim3(F / 256, L / 256, Bb), blk5, SMEM, stream>>>(p);
  // 12) X3 = x2@W2 + b2   [split-K 4]
  clr(); p.A = x2b; p.B = w2t; p.M = BL; p.N = D; p.K = F;
  p.part = partA; p.ksplit = 4; p.Kc = F / 4;
  gemm256<6><<<dim3(D / 256, BL / 256, 4), blk5, SMEM, stream>>>(p);
  k_comb<<<dim3((unsigned)(MN_D / 1024)), blk, 0, stream>>>(partA, b2, X3, D, MN_D, 4);
  // 13) S2 = tril(x2 H2^T, -1)   [split-K 4, compact-tri]
  clr(); p.A = x2b; p.B = H2b; p.M = L; p.N = L; p.K = F;
  p.sA = (long long)L * F; p.sB = (long long)L * F;
  p.part = partA; p.ksplit = 4; p.Kc = F / 4; p.Tt = T2t;
  gemm256<7><<<dim3(T2t, 1, Bb * 4), blk5, SMEM, stream>>>(p);
  k_combtri<<<dim3(T2t, Bb), blk, 0, stream>>>(partA, S2b, T2t, 4, L);
  // 14) x3 = X3 - ss2 * S2@g3   [K-limited, 128^2 kernel for grid size]
  clr(); p.A = S2b; p.B = g3t; p.M = L; p.N = D; p.K = L;
  p.sA = (long long)L * L; p.sB = (long long)D * L;
  p.outf = x3; p.sOutF = (long long)L * D; p.auxf = X3; p.sAuxF = (long long)L * D; p.steps = steps;
  gemm_bt<5><<<dim3(D / 128, L / 128, Bb), blk, 0, stream>>>(p);
  // 15) exclusive cumsums -> fast_scale / fast_bias
  k_scanpart<<<dim3(D / 256, 16, Bb), blk, 0, stream>>>(gsc, G4, psc, pbi, L, D);
  k_scanapply<<<dim3(D / 256, 16, Bb), blk, 0, stream>>>(gsc, G4, psc, pbi, ln_scale, ln_bias,
                                                         steps, fs, fb, L, D);
  // 16) x4 = LN(x3)*fast_scale + fast_bias
  k_lnfwd2<<<dim3(BL), blk, 0, stream>>>(x3, fs, fb, x4b, D);
  // 17) out = x4@Wu + bu
  clr(); p.A = x4b; p.B = wut; p.M = BL; p.N = V; p.K = D; p.outf = (float*)d_out; p.bias = bu;
  gemm256<0><<<dim3(V / 256, BL / 256, 1), blk5, SMEM, stream>>>(p);
}

// Round 7
// 1083.290 us; speedup vs baseline: 1.4568x; 1.0001x over previous
//
#include <hip/hip_runtime.h>
#include <cstdint>

typedef unsigned short ushort_t;
typedef __bf16 bf16x8 __attribute__((ext_vector_type(8)));
typedef float f32x4 __attribute__((ext_vector_type(4)));
typedef ushort_t us8 __attribute__((ext_vector_type(8)));

// ---------- helpers ----------
__device__ __forceinline__ ushort_t f2bf(float f) {
  union { float f; unsigned int u; } v; v.f = f;
  unsigned int u = v.u;
  unsigned int r = (u + 0x7fffu + ((u >> 16) & 1u)) >> 16;
  return (ushort_t)r;
}
__device__ __forceinline__ float bf2f(ushort_t u) {
  union { unsigned int u; float f; } v; v.u = ((unsigned int)u) << 16; return v.f;
}

#define GLOAD16(gp, lp)                                                              \
  __builtin_amdgcn_global_load_lds(                                                  \
      reinterpret_cast<const __attribute__((address_space(1))) unsigned int*>(       \
          reinterpret_cast<uintptr_t>(gp)),                                          \
      reinterpret_cast<__attribute__((address_space(3))) unsigned int*>(             \
          reinterpret_cast<uintptr_t>(lp)),                                          \
      16, 0, 0)

// EPI: 0 = outf = acc + bias                     (out)
//      8 = outb = bf16(acc + bias)               (logits)
//      1 = outb = bf16(acc+bias); outb2 = bf16(relu^2)    (H1b + H2b)
//      2 = outb = bf16(acc * 2*sqrt(auxb))       (g1)
//      4 = outb = bf16(relu(bf2f(auxb) - ss0*acc)^2); K-limit  (x2)
//      5 = outf = auxf - ss2*acc; K-limit        (x3, 128^2 kernel)
//      6 = split-K partial, full-matrix f32      (H3, G4, X3 stage 1)
//      7 = split-K partial, compact-tri grid, 256x256 tiles   (S1, S2 stage 1)
struct GemmP {
  const ushort_t* A; const ushort_t* B;
  int M, N, K;
  long long sA, sB;
  float* outf;   long long sOutF;
  ushort_t* outb; long long sOutB;
  ushort_t* outb2;
  const float* bias;
  const float* auxf; long long sAuxF;   // sAuxF doubles as aux (f32 or bf16) stride
  const ushort_t* auxb;
  const float* steps;
  float* part; int ksplit, Kc, Tt;
};

// ---------- 256x256 GEMM: 8 waves, BK=64, 2-phase issue-early pipeline ----------
// Catalog "minimum 2-phase": per iter {STAGE(t+1) first; ds_read(t); MFMA with
// setprio; vmcnt(0)+barrier}. Loads span the whole ~2500-cyc compute phase.
// LDS slot-XOR swizzle (T2, rule #21): within each 16-row x 32-col (1KB) chunk,
// 16B slot s' holds global slot s' ^ sigma(row), sigma(r)=(r>>1)&3, applied via
// pre-swizzled GLOBAL source (linear gload_lds dest) + swizzled ds_read.
template <int EPI>
__global__ __launch_bounds__(512, 2) void gemm256(GemmP p) {
  const int nwg = gridDim.x * gridDim.y;
  const int orig = blockIdx.y * gridDim.x + blockIdx.x;
  const int xcd = orig & 7, loc = orig >> 3;
  const int q8 = nwg >> 3, r8 = nwg & 7;
  const int wg = (xcd < r8) ? (xcd * (q8 + 1) + loc) : (r8 * (q8 + 1) + (xcd - r8) * q8 + loc);
  int mt, nt;
  if (EPI == 7) {            // compact lower-tri tile index -> (mt, nt)
    int t_ = wg;
    mt = (int)((sqrtf(8.f * t_ + 1.f) - 1.f) * 0.5f);
    while ((mt + 1) * (mt + 2) / 2 <= t_) mt++;
    while (mt * (mt + 1) / 2 > t_) mt--;
    nt = t_ - mt * (mt + 1) / 2;
  } else {
    nt = wg % gridDim.x; mt = wg / gridDim.x;
  }
  const int m0 = mt * 256, n0 = nt * 256;

  int bz = blockIdx.z, ks = 0;
  if (EPI == 6 || EPI == 7) { bz = blockIdx.z / p.ksplit; ks = blockIdx.z % p.ksplit; }

  const ushort_t* A = p.A + (size_t)bz * p.sA;
  const ushort_t* B = p.B + (size_t)bz * p.sB;

  int kbeg = 0, kend = p.K;
  if (EPI == 6 || EPI == 7) { kbeg = ks * p.Kc; kend = kbeg + p.Kc; }
  else if (EPI == 4) kend = min(p.K, m0 + 256);

  extern __shared__ ushort_t smem[];      // 2 bufs x (32KB A + 32KB B) = 128KB
  ushort_t* sA = smem;
  ushort_t* sB = smem + 2 * 16384;

  const int tid = threadIdx.x;
  const int wid = tid >> 6, lane = tid & 63;
  const int wm = wid >> 2, wn = wid & 3;

  f32x4 acc[8][4];
#pragma unroll
  for (int i = 0; i < 8; i++)
#pragma unroll
    for (int j = 0; j < 4; j++) acc[i][j] = f32x4{0.f, 0.f, 0.f, 0.f};

  // staging: chunk = 16 rows x 32 cols = 1KB (64 lanes x 16B). Per kh-half of
  // BK=64, wave w stages A-chunks {w, w+8} and B-chunks {w, w+8}. Source col
  // pre-swizzled so linear LDS dest lands swizzled.
  const int lr = lane >> 2;
  const int lcsw = (((lane & 3) ^ ((lr >> 1) & 3)) * 8);
  const int rT0 = wid * 16 + lr;
  const int rT1 = 128 + wid * 16 + lr;
  const ushort_t* gA0 = A + (size_t)(m0 + rT0) * p.K + lcsw;
  const ushort_t* gA1 = A + (size_t)(m0 + rT1) * p.K + lcsw;
  const ushort_t* gB0 = B + (size_t)(n0 + rT0) * p.K + lcsw;
  const ushort_t* gB1 = B + (size_t)(n0 + rT1) * p.K + lcsw;
  ushort_t* lA0 = &sA[wid * 512];
  ushort_t* lA1 = &sA[(8 + wid) * 512];
  ushort_t* lB0 = &sB[wid * 512];
  ushort_t* lB1 = &sB[(8 + wid) * 512];

  // ds_read offsets (loop-invariant, within one kh-half of 8192 elems)
  const int fr = lane & 15;
  const int q = lane >> 4;
  const int slot = (q ^ ((fr >> 1) & 3)) * 8;
  int offA[8], offB[4];
#pragma unroll
  for (int i = 0; i < 8; i++) offA[i] = (wm * 8 + i) * 512 + fr * 32 + slot;
#pragma unroll
  for (int j = 0; j < 4; j++) offB[j] = (wn * 4 + j) * 512 + fr * 32 + slot;

  const int nIter = (kend - kbeg) >> 6;    // BK = 64
  auto stage = [&](int t, int buf) {
    const int kk = kbeg + t * 64;
    const int o = buf * 16384;
#pragma unroll
    for (int kh = 0; kh < 2; kh++) {
      const int gk = kk + kh * 32, lo = o + kh * 8192;
      GLOAD16(gA0 + gk, lA0 + lo);
      GLOAD16(gA1 + gk, lA1 + lo);
      GLOAD16(gB0 + gk, lB0 + lo);
      GLOAD16(gB1 + gk, lB1 + lo);
    }
  };
  stage(0, 0);
  asm volatile("s_waitcnt vmcnt(0)" ::: "memory");
  __builtin_amdgcn_s_barrier();

  int cur = 0;
  for (int t = 0; t < nIter; ++t) {
    if (t + 1 < nIter) stage(t + 1, cur ^ 1);   // loads fly across the whole compute
    __builtin_amdgcn_sched_barrier(0);          // keep stage issue ahead of reads
    const int co = cur * 16384;
#pragma unroll
    for (int kh = 0; kh < 2; kh++) {
      const int ko = co + kh * 8192;
      bf16x8 av[8], bv[4];
#pragma unroll
      for (int j = 0; j < 4; j++) bv[j] = *reinterpret_cast<const bf16x8*>(&sB[ko + offB[j]]);
#pragma unroll
      for (int i = 0; i < 8; i++) av[i] = *reinterpret_cast<const bf16x8*>(&sA[ko + offA[i]]);
      __builtin_amdgcn_s_setprio(1);
#pragma unroll
      for (int i = 0; i < 8; i++)
#pragma unroll
        for (int j = 0; j < 4; j++)
          acc[i][j] = __builtin_amdgcn_mfma_f32_16x16x32_bf16(av[i], bv[j], acc[i][j], 0, 0, 0);
      __builtin_amdgcn_s_setprio(0);
    }
    if (t + 1 < nIter) {
      asm volatile("s_waitcnt vmcnt(0)" ::: "memory");   // staged tile resident
      __builtin_amdgcn_s_barrier();                      // + all reads of cur done
    }
    cur ^= 1;
  }

  const int fq = q;
  float ss = 0.f;
  if (EPI == 4) ss = p.steps[0];
  float* outf = p.outf ? p.outf + (size_t)bz * p.sOutF : nullptr;
  ushort_t* outb = p.outb ? p.outb + (size_t)bz * p.sOutB : nullptr;
  ushort_t* outb2 = p.outb2;
  const ushort_t* auxb = p.auxb ? p.auxb + (size_t)bz * p.sAuxF : nullptr;
  float* partT = nullptr;
  if (EPI == 6) partT = p.part + (size_t)blockIdx.z * p.M * p.N;
  if (EPI == 7) partT = p.part + ((size_t)blockIdx.z * p.Tt + wg) * 65536;

#pragma unroll
  for (int i = 0; i < 8; i++) {
#pragma unroll
    for (int j = 0; j < 4; j++) {
#pragma unroll
      for (int r2 = 0; r2 < 4; r2++) {
        int lrow = wm * 128 + i * 16 + fq * 4 + r2;
        int lcol = wn * 64 + j * 16 + fr;
        int row = m0 + lrow, col = n0 + lcol;
        size_t g = (size_t)row * p.N + col;
        float v = acc[i][j][r2];
        if (EPI == 0) {
          outf[g] = v + (p.bias ? p.bias[col] : 0.f);
        } else if (EPI == 8) {
          outb[g] = f2bf(v + p.bias[col]);
        } else if (EPI == 1) {
          v += p.bias[col];
          outb[g] = f2bf(v);
          float rl = fmaxf(v, 0.f);
          outb2[g] = f2bf(rl * rl);
        } else if (EPI == 2) {
          outb[g] = f2bf(v * 2.f * sqrtf(bf2f(auxb[g])));
        } else if (EPI == 4) {
          float x1 = bf2f(auxb[g]) - ss * v;
          float rl = fmaxf(x1, 0.f);
          outb[g] = f2bf(rl * rl);
        } else if (EPI == 6) {
          partT[g] = v;
        } else if (EPI == 7) {
          partT[lrow * 256 + lcol] = v;
        }
      }
    }
  }
}

// ---------- 128x128 GEMM (proven R4 pipeline) -- kept for x3 (EPI 5) ----------
template <int EPI>
__global__ __launch_bounds__(256) void gemm_bt(GemmP p) {
  const int nwg = gridDim.x * gridDim.y;
  const int orig = blockIdx.y * gridDim.x + blockIdx.x;
  const int xcd = orig & 7, loc = orig >> 3;
  const int q = nwg >> 3, r = nwg & 7;
  const int wg = (xcd < r) ? (xcd * (q + 1) + loc) : (r * (q + 1) + (xcd - r) * q + loc);
  const int nt = wg % gridDim.x, mt = wg / gridDim.x;
  const int m0 = mt * 128, n0 = nt * 128;
  const int bz = blockIdx.z;

  const ushort_t* A = p.A + (size_t)bz * p.sA;
  const ushort_t* B = p.B + (size_t)bz * p.sB;

  int kend = p.K;
  if (EPI == 5) kend = min(p.K, m0 + 128);

  __shared__ ushort_t sA[3 * 128 * 32];
  __shared__ ushort_t sB[3 * 128 * 32];

  const int tid = threadIdx.x;
  const int wid = tid >> 6, lane = tid & 63;
  const int wm = wid >> 1, wn = wid & 1;

  f32x4 acc[4][4];
#pragma unroll
  for (int i = 0; i < 4; i++)
#pragma unroll
    for (int j = 0; j < 4; j++) acc[i][j] = f32x4{0.f, 0.f, 0.f, 0.f};

  const int lr = lane >> 2;
  const int lc = (lane & 3) * 8;
  const int rA0 = wid * 16 + lr;
  const int rA1 = 64 + wid * 16 + lr;
  const ushort_t* gA0 = A + (size_t)(m0 + rA0) * p.K + lc;
  const ushort_t* gA1 = A + (size_t)(m0 + rA1) * p.K + lc;
  const ushort_t* gB0 = B + (size_t)(n0 + rA0) * p.K + lc;
  const ushort_t* gB1 = B + (size_t)(n0 + rA1) * p.K + lc;
  ushort_t* lA0 = &sA[wid * 512];
  ushort_t* lA1 = &sA[(4 + wid) * 512];
  ushort_t* lB0 = &sB[wid * 512];
  ushort_t* lB1 = &sB[(4 + wid) * 512];

  const int fr = lane & 15;
  const int kb = (lane >> 4) * 8;

  const int nIter = kend >> 5;
  auto stage = [&](int t, int buf) {
    const int kk = t * 32;
    const int o = buf * 4096;
    GLOAD16(gA0 + kk, lA0 + o);
    GLOAD16(gA1 + kk, lA1 + o);
    GLOAD16(gB0 + kk, lB0 + o);
    GLOAD16(gB1 + kk, lB1 + o);
  };
  stage(0, 0);
  if (nIter > 1) stage(1, 1);

  for (int t = 0; t < nIter; ++t) {
    if (t + 1 < nIter) { asm volatile("s_waitcnt vmcnt(4)" ::: "memory"); }
    else               { asm volatile("s_waitcnt vmcnt(0)" ::: "memory"); }
    __builtin_amdgcn_s_barrier();
    __builtin_amdgcn_sched_barrier(0);
    if (t + 2 < nIter) stage(t + 2, (t + 2) % 3);
    const int co = (t % 3) * 4096;
    bf16x8 av[4], bv[4];
#pragma unroll
    for (int i = 0; i < 4; i++) {
      av[i] = *reinterpret_cast<const bf16x8*>(&sA[co + (wm * 64 + i * 16 + fr) * 32 + kb]);
      bv[i] = *reinterpret_cast<const bf16x8*>(&sB[co + (wn * 64 + i * 16 + fr) * 32 + kb]);
    }
#pragma unroll
    for (int i = 0; i < 4; i++)
#pragma unroll
      for (int j = 0; j < 4; j++)
        acc[i][j] = __builtin_amdgcn_mfma_f32_16x16x32_bf16(av[i], bv[j], acc[i][j], 0, 0, 0);
  }

  const int fq = lane >> 4;
  float ss = (EPI == 5) ? p.steps[2] : 0.f;
  float* outf = p.outf ? p.outf + (size_t)bz * p.sOutF : nullptr;
  const float* auxf = p.auxf ? p.auxf + (size_t)bz * p.sAuxF : nullptr;

#pragma unroll
  for (int i = 0; i < 4; i++) {
#pragma unroll
    for (int j = 0; j < 4; j++) {
#pragma unroll
      for (int r2 = 0; r2 < 4; r2++) {
        int row = m0 + wm * 64 + i * 16 + fq * 4 + r2;
        int col = n0 + wn * 64 + j * 16 + fr;
        size_t g = (size_t)row * p.N + col;
        float v = acc[i][j][r2];
        if (EPI == 5) {
          outf[g] = auxf[g] - ss * v;
        } else {
          outf[g] = v + (p.bias ? p.bias[col] : 0.f);
        }
      }
    }
  }
}

// ---------- split-K combines ----------
__global__ __launch_bounds__(256) void k_comb(const float* part, const float* bias, float* out,
                                              int N, size_t MN, int S) {
  size_t e = ((size_t)blockIdx.x * 256 + threadIdx.x) * 4;
  if (e >= MN) return;
  float4 s = *(const float4*)(part + e);
  for (int p_ = 1; p_ < S; p_++) {
    float4 v = *(const float4*)(part + (size_t)p_ * MN + e);
    s.x += v.x; s.y += v.y; s.z += v.z; s.w += v.w;
  }
  if (bias) {
    int col = (int)(e % (size_t)N);
    s.x += bias[col]; s.y += bias[col + 1]; s.z += bias[col + 2]; s.w += bias[col + 3];
  }
  *(float4*)(out + e) = s;
}

// 256x256 compact-tri combine: S_bf16 = tril(sum_s part[s], -1)
__global__ __launch_bounds__(256) void k_combtri(const float* part, ushort_t* out, int Tt, int S,
                                                 int L) {
  int t = blockIdx.x, bz = blockIdx.y;
  int mt = (int)((sqrtf(8.f * t + 1.f) - 1.f) * 0.5f);
  while ((mt + 1) * (mt + 2) / 2 <= t) mt++;
  while (mt * (mt + 1) / 2 > t) mt--;
  int nt = t - mt * (mt + 1) / 2;
  const float* pb = part + ((size_t)bz * S * Tt + t) * 65536;
  ushort_t* ob = out + (size_t)bz * L * L;
  for (int e4 = threadIdx.x; e4 < 16384; e4 += 256) {
    int e = e4 * 4;
    float4 s = *(const float4*)(pb + e);
    for (int p_ = 1; p_ < S; p_++) {
      float4 v = *(const float4*)(pb + (size_t)p_ * Tt * 65536 + e);
      s.x += v.x; s.y += v.y; s.z += v.z; s.w += v.w;
    }
    int lr = e >> 8, lc2 = e & 255;
    int row = mt * 256 + lr, col = nt * 256 + lc2;
    ushort4 o;
    o.x = (col < row) ? f2bf(s.x) : (ushort_t)0;
    o.y = (col + 1 < row) ? f2bf(s.y) : (ushort_t)0;
    o.z = (col + 2 < row) ? f2bf(s.z) : (ushort_t)0;
    o.w = (col + 3 < row) ? f2bf(s.w) : (ushort_t)0;
    *(ushort4*)(&ob[(size_t)row * L + col]) = o;
  }
}

// ---------- auxiliary kernels ----------
__global__ __launch_bounds__(256) void k_conv(const float* in, ushort_t* out, size_t n) {
  size_t i = ((size_t)blockIdx.x * 256 + threadIdx.x) * 4;
  if (i >= n) return;
  float4 v = *(const float4*)(in + i);
  out[i] = f2bf(v.x); out[i + 1] = f2bf(v.y); out[i + 2] = f2bf(v.z); out[i + 3] = f2bf(v.w);
}

__global__ __launch_bounds__(256) void k_tconv(const float* in, ushort_t* out, int R, int C) {
  __shared__ float t[32][33];
  int c0 = blockIdx.x * 32, r0 = blockIdx.y * 32;
  int tx = threadIdx.x & 31, ty = threadIdx.x >> 5;
#pragma unroll
  for (int i = ty; i < 32; i += 8) t[i][tx] = in[(size_t)(r0 + i) * C + c0 + tx];
  __syncthreads();
#pragma unroll
  for (int i = ty; i < 32; i += 8) out[(size_t)(c0 + i) * R + r0 + tx] = f2bf(t[tx][i]);
}

// fused weight prep: one f32 read -> straight bf16 copy + transposed bf16 copy
__global__ __launch_bounds__(256) void k_wprep(const float* in, ushort_t* outS, ushort_t* outT,
                                               int R, int C) {
  __shared__ float t[32][33];
  int c0 = blockIdx.x * 32, r0 = blockIdx.y * 32;
  int tx = threadIdx.x & 31, ty = threadIdx.x >> 5;
#pragma unroll
  for (int i = ty; i < 32; i += 8) {
    float v = in[(size_t)(r0 + i) * C + c0 + tx];
    t[i][tx] = v;
    outS[(size_t)(r0 + i) * C + c0 + tx] = f2bf(v);
  }
  __syncthreads();
#pragma unroll
  for (int i = ty; i < 32; i += 8) outT[(size_t)(c0 + i) * R + r0 + tx] = f2bf(t[tx][i]);
}

__global__ __launch_bounds__(256) void k_tb2b(const ushort_t* in, ushort_t* out, int L, int C) {
  __shared__ ushort_t t[32][33];
  int b = blockIdx.z;
  const ushort_t* ib = in + (size_t)b * L * C;
  ushort_t* ob = out + (size_t)b * C * L;
  int c0 = blockIdx.x * 32, l0 = blockIdx.y * 32;
  int tx = threadIdx.x & 31, ty = threadIdx.x >> 5;
#pragma unroll
  for (int i = ty; i < 32; i += 8) t[i][tx] = ib[(size_t)(l0 + i) * C + c0 + tx];
  __syncthreads();
#pragma unroll
  for (int i = ty; i < 32; i += 8) ob[(size_t)(c0 + i) * L + l0 + tx] = t[tx][i];
}

__device__ __forceinline__ void blockRed2(float& a, float& b, float* red) {
#pragma unroll
  for (int o = 32; o; o >>= 1) { a += __shfl_down(a, o); b += __shfl_down(b, o); }
  int w = threadIdx.x >> 6;
  if ((threadIdx.x & 63) == 0) { red[w] = a; red[4 + w] = b; }
  __syncthreads();
  a = red[0] + red[1] + red[2] + red[3];
  b = red[4] + red[5] + red[6] + red[7];
  __syncthreads();
}

// fused split-K combine + LN forward (H3 path): h3 = sum_s part[s] + b2; LN; h4b
__global__ __launch_bounds__(256) void k_lncomb(const float* part, const float* bias,
                                                const float* sc, const float* bi, float* nout,
                                                float* rstd, ushort_t* yb, size_t MN, int D,
                                                int S) {
  __shared__ float red[8];
  int row = blockIdx.x;
  int d = threadIdx.x * 4;          // D = 1024 = 256*4
  size_t g = (size_t)row * D + d;
  float4 v = *(const float4*)(part + g);
  for (int s_ = 1; s_ < S; s_++) {
    float4 w = *(const float4*)(part + (size_t)s_ * MN + g);
    v.x += w.x; v.y += w.y; v.z += w.z; v.w += w.w;
  }
  float4 bb = *(const float4*)(bias + d);
  v.x += bb.x; v.y += bb.y; v.z += bb.z; v.w += bb.w;
  float s1 = v.x + v.y + v.z + v.w;
  float s2 = v.x * v.x + v.y * v.y + v.z * v.z + v.w * v.w;
  blockRed2(s1, s2, red);
  float mu = s1 / D;
  float var = s2 / D - mu * mu;
  float rs = rsqrtf(var + 1e-6f);
  float4 nv;
  nv.x = (v.x - mu) * rs; nv.y = (v.y - mu) * rs; nv.z = (v.z - mu) * rs; nv.w = (v.w - mu) * rs;
  *(float4*)(nout + g) = nv;
  float4 scv = *(const float4*)(sc + d);
  float4 biv = *(const float4*)(bi + d);
  ushort4 o;
  o.x = f2bf(nv.x * scv.x + biv.x);
  o.y = f2bf(nv.y * scv.y + biv.y);
  o.z = f2bf(nv.z * scv.z + biv.z);
  o.w = f2bf(nv.w * scv.w + biv.w);
  *(ushort4*)(yb + g) = o;
  if (threadIdx.x == 0) rstd[row] = rs;
}

__global__ __launch_bounds__(256) void k_lnfwd2(const float* X, const float* fs, const float* fb,
                                                ushort_t* yb, int D) {
  __shared__ float red[8];
  int row = blockIdx.x;
  const float* x = X + (size_t)row * D;
  float s = 0.f, s2 = 0.f;
  for (int d = threadIdx.x; d < D; d += 256) { float v = x[d]; s += v; s2 += v * v; }
  blockRed2(s, s2, red);
  float mu = s / D;
  float var = s2 / D - mu * mu;
  float rs = rsqrtf(var + 1e-6f);
  for (int d = threadIdx.x; d < D; d += 256) {
    size_t g = (size_t)row * D + d;
    float nv = (x[d] - mu) * rs;
    yb[g] = f2bf(nv * fs[g] + fb[g]);
  }
}

__global__ __launch_bounds__(256) void k_lnbwd(const float* G, const float* nn, const float* rstd,
                                               const float* sc, ushort_t* g3b, float* gsc, int D) {
  __shared__ float red[8];
  int row = blockIdx.x;
  const float* g = G + (size_t)row * D;
  const float* n_ = nn + (size_t)row * D;
  float sa = 0.f, sb = 0.f;
  for (int d = threadIdx.x; d < D; d += 256) {
    float dn = g[d] * sc[d];
    sa += dn; sb += dn * n_[d];
  }
  blockRed2(sa, sb, red);
  float a = sa / D, b = sb / D, rs = rstd[row];
  for (int d = threadIdx.x; d < D; d += 256) {
    size_t gi = (size_t)row * D + d;
    float dn = g[d] * sc[d];
    g3b[gi] = f2bf(rs * (dn - a - n_[d] * b));
    gsc[gi] = g[d] * n_[d];
  }
}

__global__ __launch_bounds__(256) void k_wsum(const float* w, float* o, int n) {
  __shared__ float red[4];
  float s = 0.f;
  for (int i = threadIdx.x; i < n; i += 256) s += w[i];
#pragma unroll
  for (int d = 32; d; d >>= 1) s += __shfl_down(s, d);
  if ((threadIdx.x & 63) == 0) red[threadIdx.x >> 6] = s;
  __syncthreads();
  if (threadIdx.x == 0) o[0] = fmaxf(red[0] + red[1] + red[2] + red[3], 1e-8f);
}

// register-staged fused softmax-grad: V=8192, 256 thr, 32 elem/thread in VGPRs.
__global__ __launch_bounds__(256) void k_softgrad(const ushort_t* logits, const float* labels,
                                                  const float* w, const float* wsum,
                                                  ushort_t* dlb, int V) {
  __shared__ float red[8];
  const int row = blockIdx.x;
  const int tid = threadIdx.x;
  const ushort_t* l = logits + (size_t)row * V + tid * 32;
  const float* y = labels + (size_t)row * V + tid * 32;
  float lv[32], yv[32];
#pragma unroll
  for (int i = 0; i < 4; i++) {
    us8 u = *reinterpret_cast<const us8*>(l + i * 8);
#pragma unroll
    for (int j = 0; j < 8; j++) lv[i * 8 + j] = bf2f(u[j]);
  }
#pragma unroll
  for (int i = 0; i < 8; i++) {
    float4 v = *reinterpret_cast<const float4*>(y + i * 4);
    yv[i * 4] = v.x; yv[i * 4 + 1] = v.y; yv[i * 4 + 2] = v.z; yv[i * 4 + 3] = v.w;
  }
  float m = lv[0], t = yv[0];
#pragma unroll
  for (int i = 1; i < 32; i++) { m = fmaxf(m, lv[i]); t += yv[i]; }
#pragma unroll
  for (int o = 32; o; o >>= 1) { m = fmaxf(m, __shfl_down(m, o)); t += __shfl_down(t, o); }
  int wv = tid >> 6;
  if ((tid & 63) == 0) { red[wv] = m; red[4 + wv] = t; }
  __syncthreads();
  m = fmaxf(fmaxf(red[0], red[1]), fmaxf(red[2], red[3]));
  t = red[4] + red[5] + red[6] + red[7];
  __syncthreads();
  float s = 0.f;
#pragma unroll
  for (int i = 0; i < 32; i++) { lv[i] = expf(lv[i] - m); s += lv[i]; }
#pragma unroll
  for (int o = 32; o; o >>= 1) s += __shfl_down(s, o);
  if ((tid & 63) == 0) red[wv] = s;
  __syncthreads();
  s = red[0] + red[1] + red[2] + red[3];
  float c = w[row] / wsum[0];
  float ci = c * t / s;
  ushort_t* dl = dlb + (size_t)row * V + tid * 32;
#pragma unroll
  for (int i = 0; i < 4; i++) {
    us8 o;
#pragma unroll
    for (int j = 0; j < 8; j++) o[j] = f2bf(ci * lv[i * 8 + j] - c * yv[i * 8 + j]);
    *reinterpret_cast<us8*>(dl + i * 8) = o;
  }
}

__global__ __launch_bounds__(256) void k_scanpart(const float* gs, const float* gb, float* ps,
                                                  float* pb, int L, int D) {
  int d = blockIdx.x * 256 + threadIdx.x;
  int seg = blockIdx.y, b = blockIdx.z;
  const int SEGL = L / 16;
  size_t base = ((size_t)b * L + seg * SEGL) * D + d;
  float s1 = 0.f, s2 = 0.f;
  for (int i = 0; i < SEGL; i++) { s1 += gs[base + (size_t)i * D]; s2 += gb[base + (size_t)i * D]; }
  size_t pi = ((size_t)b * 16 + seg) * D + d;
  ps[pi] = s1; pb[pi] = s2;
}

__global__ __launch_bounds__(256) void k_scanapply(const float* gs, const float* gb,
                                                   const float* ps, const float* pb,
                                                   const float* sc, const float* bi,
                                                   const float* steps, float* fs, float* fb,
                                                   int L, int D) {
  int d = blockIdx.x * 256 + threadIdx.x;
  int seg = blockIdx.y, b = blockIdx.z;
  const int SEGL = L / 16;
  float ss = steps[3];
  float rs_ = 0.f, rb_ = 0.f;
  for (int s = 0; s < seg; s++) {
    size_t pi = ((size_t)b * 16 + s) * D + d;
    rs_ += ps[pi]; rb_ += pb[pi];
  }
  float s0 = sc[d], b0 = bi[d];
  size_t base = ((size_t)b * L + seg * SEGL) * D + d;
  for (int i = 0; i < SEGL; i++) {
    size_t g = base + (size_t)i * D;
    fs[g] = s0 - ss * rs_;
    fb[g] = b0 - ss * rb_;
    rs_ += gs[g]; rb_ += gb[g];
  }
}

// ---------- orchestration ----------
extern "C" void kernel_launch(void* const* d_in, const int* in_sizes, int n_in, void* d_out,
                              int out_size, void* d_ws, size_t ws_size, hipStream_t stream) {
  const float* x        = (const float*)d_in[0];
  const float* labels   = (const float*)d_in[1];
  const float* weights  = (const float*)d_in[2];
  const float* W1       = (const float*)d_in[3];
  const float* b1       = (const float*)d_in[4];
  const float* W2       = (const float*)d_in[5];
  const float* b2       = (const float*)d_in[6];
  const float* ln_scale = (const float*)d_in[7];
  const float* ln_bias  = (const float*)d_in[8];
  const float* Wu       = (const float*)d_in[9];
  const float* bu       = (const float*)d_in[10];
  const float* steps    = (const float*)d_in[11];

  const int BL = in_sizes[2];   // 4096
  const int D  = in_sizes[7];   // 1024
  const int F  = in_sizes[4];   // 4096
  const int V  = in_sizes[10];  // 8192
  const int Bb = 2, L = BL / Bb;
  const int T2t = (L / 256) * (L / 256 + 1) / 2;   // 36 live 256-tri tiles
  const unsigned SMEM = 2 * 16384 * 2 * 2;         // 128 KB dynamic LDS

  char* ws = (char*)d_ws;
  size_t off = 0;
  auto take = [&](size_t b) { char* p = ws + off; off = (off + b + 255) & ~(size_t)255; return p; };

  ushort_t* xb   = (ushort_t*)take((size_t)BL * D * 2);
  ushort_t* w1t  = (ushort_t*)take((size_t)F * D * 2);
  ushort_t* w2t  = (ushort_t*)take((size_t)D * F * 2);
  ushort_t* w2b  = (ushort_t*)take((size_t)F * D * 2);
  ushort_t* wut  = (ushort_t*)take((size_t)V * D * 2);
  ushort_t* wub  = (ushort_t*)take((size_t)D * V * 2);
  ushort_t* H1b  = (ushort_t*)take((size_t)BL * F * 2);
  ushort_t* H2b  = (ushort_t*)take((size_t)BL * F * 2);
  float*    nbuf = (float*)take((size_t)BL * D * 4);
  float*    rstd = (float*)take((size_t)BL * 4);
  ushort_t* h4b  = (ushort_t*)take((size_t)BL * D * 2);
  float*    wsumb= (float*)take(256);
  float*    G4   = (float*)take((size_t)BL * D * 4);   // also g_bias
  float*    gsc  = (float*)take((size_t)BL * D * 4);   // g_scale
  ushort_t* g3b  = (ushort_t*)take((size_t)BL * D * 2);
  ushort_t* g3t  = (ushort_t*)take((size_t)BL * D * 2);
  float*    fs   = (float*)take((size_t)BL * D * 4);
  float*    fb   = (float*)take((size_t)BL * D * 4);
  ushort_t* x4b  = (ushort_t*)take((size_t)BL * D * 2);
  float*    psc  = (float*)take((size_t)Bb * 16 * D * 4);
  float*    pbi  = (float*)take((size_t)Bb * 16 * D * 4);
  // poolA (134MB): logitsb bf16 / split-K partials -> later {g1b, g1t, S1b, x2b}
  char* poolA = take((size_t)BL * V * 4);
  ushort_t* logitsb = (ushort_t*)poolA;
  float*    partA  = (float*)poolA;
  ushort_t* g1b = (ushort_t*)poolA;
  ushort_t* g1t = (ushort_t*)(poolA + (size_t)BL * F * 2);
  ushort_t* S1b = (ushort_t*)(poolA + (size_t)BL * F * 4);
  ushort_t* x2b = (ushort_t*)(poolA + (size_t)BL * F * 4 + (size_t)Bb * L * L * 2);
  // poolB (64MB): dlb bf16 -> later {S2b, X3, x3}; head hosts S1 partials (36MB)
  char* poolB = take((size_t)BL * V * 2);
  ushort_t* dlb = (ushort_t*)poolB;
  float*    partS1 = (float*)poolB;
  ushort_t* S2b = (ushort_t*)poolB;
  float*    X3  = (float*)(poolB + (size_t)Bb * L * L * 2);
  float*    x3  = (float*)(poolB + (size_t)Bb * L * L * 2 + (size_t)BL * D * 4);

  dim3 blk(256), blk5(512);
  const size_t MN_D = (size_t)BL * D;

  k_conv<<<dim3((unsigned)((size_t)BL * D / 1024)), blk, 0, stream>>>(x, xb, (size_t)BL * D);
  k_tconv<<<dim3(F / 32, D / 32), blk, 0, stream>>>(W1, w1t, D, F);
  k_wprep<<<dim3(D / 32, F / 32), blk, 0, stream>>>(W2, w2b, w2t, F, D);   // straight + (D,F)T
  k_wprep<<<dim3(V / 32, D / 32), blk, 0, stream>>>(Wu, wub, wut, D, V);   // straight + (V,D)T

  GemmP p;
  auto clr = [&]() { p = GemmP{}; };

  // 1) H1b = bf16(x@W1+b1) ; H2b = bf16(relu^2)
  clr(); p.A = xb; p.B = w1t; p.M = BL; p.N = F; p.K = D;
  p.outb = H1b; p.outb2 = H2b; p.bias = b1;
  gemm256<1><<<dim3(F / 256, BL / 256, 1), blk5, SMEM, stream>>>(p);
  // 2) H3 partials [split-K 4] -> fused combine+LN fwd
  clr(); p.A = H2b; p.B = w2t; p.M = BL; p.N = D; p.K = F;
  p.part = partA; p.ksplit = 4; p.Kc = F / 4;
  gemm256<6><<<dim3(D / 256, BL / 256, 4), blk5, SMEM, stream>>>(p);
  k_lncomb<<<dim3(BL), blk, 0, stream>>>(partA, b2, ln_scale, ln_bias, nbuf, rstd, h4b, MN_D, D, 4);
  // 4) logits = bf16(h4@Wu + bu)
  clr(); p.A = h4b; p.B = wut; p.M = BL; p.N = V; p.K = D; p.outb = logitsb; p.bias = bu;
  gemm256<8><<<dim3(V / 256, BL / 256, 1), blk5, SMEM, stream>>>(p);
  // 5) fused softmax grad (register-staged)
  k_wsum<<<dim3(1), blk, 0, stream>>>(weights, wsumb, BL);
  k_softgrad<<<dim3(BL), blk, 0, stream>>>(logitsb, labels, weights, wsumb, dlb, V);
  // 6) G4 = dlogits @ Wu^T   [split-K 4]
  clr(); p.A = dlb; p.B = wub; p.M = BL; p.N = D; p.K = V;
  p.part = partA; p.ksplit = 4; p.Kc = V / 4;
  gemm256<6><<<dim3(D / 256, BL / 256, 4), blk5, SMEM, stream>>>(p);
  k_comb<<<dim3((unsigned)(MN_D / 1024)), blk, 0, stream>>>(partA, nullptr, G4, D, MN_D, 4);
  // 7) LN bwd -> g3, g_scale
  k_lnbwd<<<dim3(BL), blk, 0, stream>>>(G4, nbuf, rstd, ln_scale, g3b, gsc, D);
  // 8) g1 = (g3 @ W2^T) * 2*sqrt(H2)
  clr(); p.A = g3b; p.B = w2b; p.M = BL; p.N = F; p.K = D; p.outb = g1b; p.auxb = H2b;
  gemm256<2><<<dim3(F / 256, BL / 256, 1), blk5, SMEM, stream>>>(p);
  // 9) transposes for attention V-operands
  k_tb2b<<<dim3(F / 32, L / 32, Bb), blk, 0, stream>>>(g1b, g1t, L, F);
  k_tb2b<<<dim3(D / 32, L / 32, Bb), blk, 0, stream>>>(g3b, g3t, L, D);
  // 10) S1 = tril(x x^T, -1)   [split-K 2, compact-tri, partials in poolB]
  clr(); p.A = xb; p.B = xb; p.M = L; p.N = L; p.K = D;
  p.sA = (long long)L * D; p.sB = (long long)L * D;
  p.part = partS1; p.ksplit = 2; p.Kc = D / 2; p.Tt = T2t;
  gemm256<7><<<dim3(T2t, 1, Bb * 2), blk5, SMEM, stream>>>(p);
  k_combtri<<<dim3(T2t, Bb), blk, 0, stream>>>(partS1, S1b, T2t, 2, L);
  // 11) x2 = relu(H1 - ss0 * S1@g1)^2   [K-limited, aux = bf16 H1b]
  clr(); p.A = S1b; p.B = g1t; p.M = L; p.N = F; p.K = L;
  p.sA = (long long)L * L; p.sB = (long long)F * L;
  p.outb = x2b; p.sOutB = (long long)L * F; p.auxb = H1b; p.sAuxF = (long long)L * F;
  p.steps = steps;
  gemm256<4><<<dim3(F / 256, L / 256, Bb), blk5, SMEM, stream>>>(p);
  // 12) X3 = x2@W2 + b2   [split-K 4]
  clr(); p.A = x2b; p.B = w2t; p.M = BL; p.N = D; p.K = F;
  p.part = partA; p.ksplit = 4; p.Kc = F / 4;
  gemm256<6><<<dim3(D / 256, BL / 256, 4), blk5, SMEM, stream>>>(p);
  k_comb<<<dim3((unsigned)(MN_D / 1024)), blk, 0, stream>>>(partA, b2, X3, D, MN_D, 4);
  // 13) S2 = tril(x2 H2^T, -1)   [split-K 4, compact-tri]
  clr(); p.A = x2b; p.B = H2b; p.M = L; p.N = L; p.K = F;
  p.sA = (long long)L * F; p.sB = (long long)L * F;
  p.part = partA; p.ksplit = 4; p.Kc = F / 4; p.Tt = T2t;
  gemm256<7><<<dim3(T2t, 1, Bb * 4), blk5, SMEM, stream>>>(p);
  k_combtri<<<dim3(T2t, Bb), blk, 0, stream>>>(partA, S2b, T2t, 4, L);
  // 14) x3 = X3 - ss2 * S2@g3   [K-limited, 128^2 kernel for grid size]
  clr(); p.A = S2b; p.B = g3t; p.M = L; p.N = D; p.K = L;
  p.sA = (long long)L * L; p.sB = (long long)D * L;
  p.outf = x3; p.sOutF = (long long)L * D; p.auxf = X3; p.sAuxF = (long long)L * D; p.steps = steps;
  gemm_bt<5><<<dim3(D / 128, L / 128, Bb), blk, 0, stream>>>(p);
  // 15) exclusive cumsums -> fast_scale / fast_bias
  k_scanpart<<<dim3(D / 256, 16, Bb), blk, 0, stream>>>(gsc, G4, psc, pbi, L, D);
  k_scanapply<<<dim3(D / 256, 16, Bb), blk, 0, stream>>>(gsc, G4, psc, pbi, ln_scale, ln_bias,
                                                         steps, fs, fb, L, D);
  // 16) x4 = LN(x3)*fast_scale + fast_bias
  k_lnfwd2<<<dim3(BL), blk, 0, stream>>>(x3, fs, fb, x4b, D);
  // 17) out = x4@Wu + bu
  clr(); p.A = x4b; p.B = wut; p.M = BL; p.N = V; p.K = D; p.outf = (float*)d_out; p.bias = bu;
  gemm256<0><<<dim3(V / 256, BL / 256, 1), blk5, SMEM, stream>>>(p);
}

// Round 8
// 1074.691 us; speedup vs baseline: 1.4685x; 1.0080x over previous
//
#include <hip/hip_runtime.h>
#include <cstdint>

typedef unsigned short ushort_t;
typedef __bf16 bf16x8 __attribute__((ext_vector_type(8)));
typedef float f32x4 __attribute__((ext_vector_type(4)));
typedef ushort_t us8 __attribute__((ext_vector_type(8)));

// ---------- helpers ----------
__device__ __forceinline__ ushort_t f2bf(float f) {
  union { float f; unsigned int u; } v; v.f = f;
  unsigned int u = v.u;
  unsigned int r = (u + 0x7fffu + ((u >> 16) & 1u)) >> 16;
  return (ushort_t)r;
}
__device__ __forceinline__ float bf2f(ushort_t u) {
  union { unsigned int u; float f; } v; v.u = ((unsigned int)u) << 16; return v.f;
}

#define GLOAD16(gp, lp)                                                              \
  __builtin_amdgcn_global_load_lds(                                                  \
      reinterpret_cast<const __attribute__((address_space(1))) unsigned int*>(       \
          reinterpret_cast<uintptr_t>(gp)),                                          \
      reinterpret_cast<__attribute__((address_space(3))) unsigned int*>(             \
          reinterpret_cast<uintptr_t>(lp)),                                          \
      16, 0, 0)

// EPI: 0 = outf = acc + bias                     (out)
//      8 = outb = bf16(acc + bias)               (logits)
//      1 = outb = bf16(acc+bias); outb2 = bf16(relu^2)    (H1b + H2b)
//      2 = outb = bf16(acc * 2*sqrt(auxb))       (g1)
//      4 = outb = bf16(relu(bf2f(auxb) - ss0*acc)^2); K-limit  (x2)
//      5 = outf = auxf - ss2*acc; K-limit        (x3, 128^2 kernel)
//      6 = split-K partial, full-matrix f32      (H3, G4, X3 stage 1)
//      7 = split-K partial, compact-tri grid, 256x256 tiles   (S1, S2 stage 1)
struct GemmP {
  const ushort_t* A; const ushort_t* B;
  int M, N, K;
  long long sA, sB;
  float* outf;   long long sOutF;
  ushort_t* outb; long long sOutB;
  ushort_t* outb2;
  const float* bias;
  const float* auxf; long long sAuxF;   // sAuxF doubles as aux (f32 or bf16) stride
  const ushort_t* auxb;
  const float* steps;
  float* part; int ksplit, Kc, Tt;
};

// ---------- 256x256 GEMM: 8 waves, BK=64, 4-phase counted-vmcnt pipeline (T3+T4) ----
// Per K-tile, 4 phases; each phase: {ds_read subtile; stage 2 gloads; barrier;
// lgkmcnt(0); setprio(1); 16 MFMA; setprio(0); [vmcnt(4) at phases 1,3]; barrier}.
// Stage order per tile t (into buf t+1): ph0=A-kh0, ph1=B-kh0, ph2=A-kh1, ph3=B-kh1.
// Steady-state count at ph1/ph3 ends: 8 outstanding, vmcnt(4) retires exactly the
// 2 units the next 2 phases need; next tile's loads stay in flight ACROSS barriers.
// LDS slot-XOR swizzle (T2, rule #21) unchanged from R5 (bank-conflict = 0 measured).
template <int EPI>
__global__ __launch_bounds__(512, 2) void gemm256(GemmP p) {
  const int nwg = gridDim.x * gridDim.y;
  const int orig = blockIdx.y * gridDim.x + blockIdx.x;
  const int xcd = orig & 7, loc = orig >> 3;
  const int q8 = nwg >> 3, r8 = nwg & 7;
  const int wg = (xcd < r8) ? (xcd * (q8 + 1) + loc) : (r8 * (q8 + 1) + (xcd - r8) * q8 + loc);
  int mt, nt;
  if (EPI == 7) {            // compact lower-tri tile index -> (mt, nt)
    int t_ = wg;
    mt = (int)((sqrtf(8.f * t_ + 1.f) - 1.f) * 0.5f);
    while ((mt + 1) * (mt + 2) / 2 <= t_) mt++;
    while (mt * (mt + 1) / 2 > t_) mt--;
    nt = t_ - mt * (mt + 1) / 2;
  } else {
    nt = wg % gridDim.x; mt = wg / gridDim.x;
  }
  const int m0 = mt * 256, n0 = nt * 256;

  int bz = blockIdx.z, ks = 0;
  if (EPI == 6 || EPI == 7) { bz = blockIdx.z / p.ksplit; ks = blockIdx.z % p.ksplit; }

  const ushort_t* A = p.A + (size_t)bz * p.sA;
  const ushort_t* B = p.B + (size_t)bz * p.sB;

  int kbeg = 0, kend = p.K;
  if (EPI == 6 || EPI == 7) { kbeg = ks * p.Kc; kend = kbeg + p.Kc; }
  else if (EPI == 4) kend = min(p.K, m0 + 256);

  extern __shared__ ushort_t smem[];      // 2 bufs x (32KB A + 32KB B) = 128KB
  ushort_t* sA = smem;
  ushort_t* sB = smem + 2 * 16384;

  const int tid = threadIdx.x;
  const int wid = tid >> 6, lane = tid & 63;
  const int wm = wid >> 2, wn = wid & 3;

  f32x4 acc[8][4];
#pragma unroll
  for (int i = 0; i < 8; i++)
#pragma unroll
    for (int j = 0; j < 4; j++) acc[i][j] = f32x4{0.f, 0.f, 0.f, 0.f};

  // staging: chunk = 16 rows x 32 cols = 1KB (64 lanes x 16B). Per kh-half,
  // wave w stages A-chunks {w, w+8} and B-chunks {w, w+8}. Source col
  // pre-swizzled so linear gload_lds dest lands swizzled.
  const int lr = lane >> 2;
  const int lcsw = (((lane & 3) ^ ((lr >> 1) & 3)) * 8);
  const int rT0 = wid * 16 + lr;
  const int rT1 = 128 + wid * 16 + lr;
  const ushort_t* gA0 = A + (size_t)(m0 + rT0) * p.K + lcsw;
  const ushort_t* gA1 = A + (size_t)(m0 + rT1) * p.K + lcsw;
  const ushort_t* gB0 = B + (size_t)(n0 + rT0) * p.K + lcsw;
  const ushort_t* gB1 = B + (size_t)(n0 + rT1) * p.K + lcsw;
  ushort_t* lA0 = &sA[wid * 512];
  ushort_t* lA1 = &sA[(8 + wid) * 512];
  ushort_t* lB0 = &sB[wid * 512];
  ushort_t* lB1 = &sB[(8 + wid) * 512];

  // ds_read offsets (loop-invariant, within one 8192-elem kh-half)
  const int fr = lane & 15;
  const int q = lane >> 4;
  const int slot = (q ^ ((fr >> 1) & 3)) * 8;
  int offA[8], offB[4];
#pragma unroll
  for (int i = 0; i < 8; i++) offA[i] = (wm * 8 + i) * 512 + fr * 32 + slot;
#pragma unroll
  for (int j = 0; j < 4; j++) offB[j] = (wn * 4 + j) * 512 + fr * 32 + slot;

  const int nT = (kend - kbeg) >> 6;    // BK = 64
  auto stageA2 = [&](int kk, int o) {   // A both row-halves, one kh -> 2 gloads
    GLOAD16(gA0 + kk, lA0 + o);
    GLOAD16(gA1 + kk, lA1 + o);
  };
  auto stageB2 = [&](int kk, int o) {
    GLOAD16(gB0 + kk, lB0 + o);
    GLOAD16(gB1 + kk, lB1 + o);
  };

  // prologue: tile 0 in wait-order {A-kh0, B-kh0, A-kh1, B-kh1} = 8 loads;
  // vmcnt(4) retires A-kh0,B-kh0 (phases 0-1), leaves kh1 units in flight.
  stageA2(kbeg, 0);
  stageB2(kbeg, 0);
  stageA2(kbeg + 32, 8192);
  stageB2(kbeg + 32, 8192);
  asm volatile("s_waitcnt vmcnt(4)" ::: "memory");
  __builtin_amdgcn_s_barrier();

  for (int t = 0; t < nT; ++t) {
    const int co = (t & 1) * 16384;
    const int no = co ^ 16384;
    const bool pre = (t + 1 < nT);
    const int kn = kbeg + (t + 1) * 64;
    bf16x8 av[4], bv[4];

    // ---- phase 0: kh0, rowfrags 0-3, read B(kh0); stage A-kh0(t+1) ----
#pragma unroll
    for (int j = 0; j < 4; j++) bv[j] = *reinterpret_cast<const bf16x8*>(&sB[co + offB[j]]);
#pragma unroll
    for (int i = 0; i < 4; i++) av[i] = *reinterpret_cast<const bf16x8*>(&sA[co + offA[i]]);
    if (pre) stageA2(kn, no);
    __builtin_amdgcn_s_barrier();
    asm volatile("s_waitcnt lgkmcnt(0)" ::: "memory");
    __builtin_amdgcn_sched_barrier(0);
    __builtin_amdgcn_s_setprio(1);
#pragma unroll
    for (int i = 0; i < 4; i++)
#pragma unroll
      for (int j = 0; j < 4; j++)
        acc[i][j] = __builtin_amdgcn_mfma_f32_16x16x32_bf16(av[i], bv[j], acc[i][j], 0, 0, 0);
    __builtin_amdgcn_s_setprio(0);
    __builtin_amdgcn_s_barrier();

    // ---- phase 1: kh0, rowfrags 4-7 (bv reused); stage B-kh0(t+1); vmcnt ----
#pragma unroll
    for (int i = 0; i < 4; i++) av[i] = *reinterpret_cast<const bf16x8*>(&sA[co + offA[4 + i]]);
    if (pre) stageB2(kn, no);
    __builtin_amdgcn_s_barrier();
    asm volatile("s_waitcnt lgkmcnt(0)" ::: "memory");
    __builtin_amdgcn_sched_barrier(0);
    __builtin_amdgcn_s_setprio(1);
#pragma unroll
    for (int i = 0; i < 4; i++)
#pragma unroll
      for (int j = 0; j < 4; j++)
        acc[4 + i][j] = __builtin_amdgcn_mfma_f32_16x16x32_bf16(av[i], bv[j], acc[4 + i][j], 0, 0, 0);
    __builtin_amdgcn_s_setprio(0);
    if (pre) { asm volatile("s_waitcnt vmcnt(4)" ::: "memory"); }   // retire kh1(t); t+1 stays in flight
    else     { asm volatile("s_waitcnt vmcnt(0)" ::: "memory"); }
    __builtin_amdgcn_s_barrier();

    // ---- phase 2: kh1, rowfrags 0-3, read B(kh1); stage A-kh1(t+1) ----
    const int c1 = co + 8192;
#pragma unroll
    for (int j = 0; j < 4; j++) bv[j] = *reinterpret_cast<const bf16x8*>(&sB[c1 + offB[j]]);
#pragma unroll
    for (int i = 0; i < 4; i++) av[i] = *reinterpret_cast<const bf16x8*>(&sA[c1 + offA[i]]);
    if (pre) stageA2(kn + 32, no + 8192);
    __builtin_amdgcn_s_barrier();
    asm volatile("s_waitcnt lgkmcnt(0)" ::: "memory");
    __builtin_amdgcn_sched_barrier(0);
    __builtin_amdgcn_s_setprio(1);
#pragma unroll
    for (int i = 0; i < 4; i++)
#pragma unroll
      for (int j = 0; j < 4; j++)
        acc[i][j] = __builtin_amdgcn_mfma_f32_16x16x32_bf16(av[i], bv[j], acc[i][j], 0, 0, 0);
    __builtin_amdgcn_s_setprio(0);
    __builtin_amdgcn_s_barrier();

    // ---- phase 3: kh1, rowfrags 4-7; stage B-kh1(t+1); vmcnt(4) ----
#pragma unroll
    for (int i = 0; i < 4; i++) av[i] = *reinterpret_cast<const bf16x8*>(&sA[c1 + offA[4 + i]]);
    if (pre) stageB2(kn + 32, no + 8192);
    __builtin_amdgcn_s_barrier();
    asm volatile("s_waitcnt lgkmcnt(0)" ::: "memory");
    __builtin_amdgcn_sched_barrier(0);
    __builtin_amdgcn_s_setprio(1);
#pragma unroll
    for (int i = 0; i < 4; i++)
#pragma unroll
      for (int j = 0; j < 4; j++)
        acc[4 + i][j] = __builtin_amdgcn_mfma_f32_16x16x32_bf16(av[i], bv[j], acc[4 + i][j], 0, 0, 0);
    __builtin_amdgcn_s_setprio(0);
    if (pre) { asm volatile("s_waitcnt vmcnt(4)" ::: "memory"); }   // retire A/B-kh0(t+1) for next tile
    __builtin_amdgcn_s_barrier();
  }

  const int fq = q;
  float ss = 0.f;
  if (EPI == 4) ss = p.steps[0];
  float* outf = p.outf ? p.outf + (size_t)bz * p.sOutF : nullptr;
  ushort_t* outb = p.outb ? p.outb + (size_t)bz * p.sOutB : nullptr;
  ushort_t* outb2 = p.outb2;
  const ushort_t* auxb = p.auxb ? p.auxb + (size_t)bz * p.sAuxF : nullptr;
  float* partT = nullptr;
  if (EPI == 6) partT = p.part + (size_t)blockIdx.z * p.M * p.N;
  if (EPI == 7) partT = p.part + ((size_t)blockIdx.z * p.Tt + wg) * 65536;

#pragma unroll
  for (int i = 0; i < 8; i++) {
#pragma unroll
    for (int j = 0; j < 4; j++) {
#pragma unroll
      for (int r2 = 0; r2 < 4; r2++) {
        int lrow = wm * 128 + i * 16 + fq * 4 + r2;
        int lcol = wn * 64 + j * 16 + fr;
        int row = m0 + lrow, col = n0 + lcol;
        size_t g = (size_t)row * p.N + col;
        float v = acc[i][j][r2];
        if (EPI == 0) {
          outf[g] = v + (p.bias ? p.bias[col] : 0.f);
        } else if (EPI == 8) {
          outb[g] = f2bf(v + p.bias[col]);
        } else if (EPI == 1) {
          v += p.bias[col];
          outb[g] = f2bf(v);
          float rl = fmaxf(v, 0.f);
          outb2[g] = f2bf(rl * rl);
        } else if (EPI == 2) {
          outb[g] = f2bf(v * 2.f * sqrtf(bf2f(auxb[g])));
        } else if (EPI == 4) {
          float x1 = bf2f(auxb[g]) - ss * v;
          float rl = fmaxf(x1, 0.f);
          outb[g] = f2bf(rl * rl);
        } else if (EPI == 6) {
          partT[g] = v;
        } else if (EPI == 7) {
          partT[lrow * 256 + lcol] = v;
        }
      }
    }
  }
}

// ---------- 128x128 GEMM (proven R4 pipeline) -- kept for x3 (EPI 5) ----------
template <int EPI>
__global__ __launch_bounds__(256) void gemm_bt(GemmP p) {
  const int nwg = gridDim.x * gridDim.y;
  const int orig = blockIdx.y * gridDim.x + blockIdx.x;
  const int xcd = orig & 7, loc = orig >> 3;
  const int q = nwg >> 3, r = nwg & 7;
  const int wg = (xcd < r) ? (xcd * (q + 1) + loc) : (r * (q + 1) + (xcd - r) * q + loc);
  const int nt = wg % gridDim.x, mt = wg / gridDim.x;
  const int m0 = mt * 128, n0 = nt * 128;
  const int bz = blockIdx.z;

  const ushort_t* A = p.A + (size_t)bz * p.sA;
  const ushort_t* B = p.B + (size_t)bz * p.sB;

  int kend = p.K;
  if (EPI == 5) kend = min(p.K, m0 + 128);

  __shared__ ushort_t sA[3 * 128 * 32];
  __shared__ ushort_t sB[3 * 128 * 32];

  const int tid = threadIdx.x;
  const int wid = tid >> 6, lane = tid & 63;
  const int wm = wid >> 1, wn = wid & 1;

  f32x4 acc[4][4];
#pragma unroll
  for (int i = 0; i < 4; i++)
#pragma unroll
    for (int j = 0; j < 4; j++) acc[i][j] = f32x4{0.f, 0.f, 0.f, 0.f};

  const int lr = lane >> 2;
  const int lc = (lane & 3) * 8;
  const int rA0 = wid * 16 + lr;
  const int rA1 = 64 + wid * 16 + lr;
  const ushort_t* gA0 = A + (size_t)(m0 + rA0) * p.K + lc;
  const ushort_t* gA1 = A + (size_t)(m0 + rA1) * p.K + lc;
  const ushort_t* gB0 = B + (size_t)(n0 + rA0) * p.K + lc;
  const ushort_t* gB1 = B + (size_t)(n0 + rA1) * p.K + lc;
  ushort_t* lA0 = &sA[wid * 512];
  ushort_t* lA1 = &sA[(4 + wid) * 512];
  ushort_t* lB0 = &sB[wid * 512];
  ushort_t* lB1 = &sB[(4 + wid) * 512];

  const int fr = lane & 15;
  const int kb = (lane >> 4) * 8;

  const int nIter = kend >> 5;
  auto stage = [&](int t, int buf) {
    const int kk = t * 32;
    const int o = buf * 4096;
    GLOAD16(gA0 + kk, lA0 + o);
    GLOAD16(gA1 + kk, lA1 + o);
    GLOAD16(gB0 + kk, lB0 + o);
    GLOAD16(gB1 + kk, lB1 + o);
  };
  stage(0, 0);
  if (nIter > 1) stage(1, 1);

  for (int t = 0; t < nIter; ++t) {
    if (t + 1 < nIter) { asm volatile("s_waitcnt vmcnt(4)" ::: "memory"); }
    else               { asm volatile("s_waitcnt vmcnt(0)" ::: "memory"); }
    __builtin_amdgcn_s_barrier();
    __builtin_amdgcn_sched_barrier(0);
    if (t + 2 < nIter) stage(t + 2, (t + 2) % 3);
    const int co = (t % 3) * 4096;
    bf16x8 av[4], bv[4];
#pragma unroll
    for (int i = 0; i < 4; i++) {
      av[i] = *reinterpret_cast<const bf16x8*>(&sA[co + (wm * 64 + i * 16 + fr) * 32 + kb]);
      bv[i] = *reinterpret_cast<const bf16x8*>(&sB[co + (wn * 64 + i * 16 + fr) * 32 + kb]);
    }
#pragma unroll
    for (int i = 0; i < 4; i++)
#pragma unroll
      for (int j = 0; j < 4; j++)
        acc[i][j] = __builtin_amdgcn_mfma_f32_16x16x32_bf16(av[i], bv[j], acc[i][j], 0, 0, 0);
  }

  const int fq = lane >> 4;
  float ss = (EPI == 5) ? p.steps[2] : 0.f;
  float* outf = p.outf ? p.outf + (size_t)bz * p.sOutF : nullptr;
  const float* auxf = p.auxf ? p.auxf + (size_t)bz * p.sAuxF : nullptr;

#pragma unroll
  for (int i = 0; i < 4; i++) {
#pragma unroll
    for (int j = 0; j < 4; j++) {
#pragma unroll
      for (int r2 = 0; r2 < 4; r2++) {
        int row = m0 + wm * 64 + i * 16 + fq * 4 + r2;
        int col = n0 + wn * 64 + j * 16 + fr;
        size_t g = (size_t)row * p.N + col;
        float v = acc[i][j][r2];
        if (EPI == 5) {
          outf[g] = auxf[g] - ss * v;
        } else {
          outf[g] = v + (p.bias ? p.bias[col] : 0.f);
        }
      }
    }
  }
}

// ---------- split-K combines ----------
__global__ __launch_bounds__(256) void k_comb(const float* part, const float* bias, float* out,
                                              int N, size_t MN, int S) {
  size_t e = ((size_t)blockIdx.x * 256 + threadIdx.x) * 4;
  if (e >= MN) return;
  float4 s = *(const float4*)(part + e);
  for (int p_ = 1; p_ < S; p_++) {
    float4 v = *(const float4*)(part + (size_t)p_ * MN + e);
    s.x += v.x; s.y += v.y; s.z += v.z; s.w += v.w;
  }
  if (bias) {
    int col = (int)(e % (size_t)N);
    s.x += bias[col]; s.y += bias[col + 1]; s.z += bias[col + 2]; s.w += bias[col + 3];
  }
  *(float4*)(out + e) = s;
}

// 256x256 compact-tri combine: S_bf16 = tril(sum_s part[s], -1)
__global__ __launch_bounds__(256) void k_combtri(const float* part, ushort_t* out, int Tt, int S,
                                                 int L) {
  int t = blockIdx.x, bz = blockIdx.y;
  int mt = (int)((sqrtf(8.f * t + 1.f) - 1.f) * 0.5f);
  while ((mt + 1) * (mt + 2) / 2 <= t) mt++;
  while (mt * (mt + 1) / 2 > t) mt--;
  int nt = t - mt * (mt + 1) / 2;
  const float* pb = part + ((size_t)bz * S * Tt + t) * 65536;
  ushort_t* ob = out + (size_t)bz * L * L;
  for (int e4 = threadIdx.x; e4 < 16384; e4 += 256) {
    int e = e4 * 4;
    float4 s = *(const float4*)(pb + e);
    for (int p_ = 1; p_ < S; p_++) {
      float4 v = *(const float4*)(pb + (size_t)p_ * Tt * 65536 + e);
      s.x += v.x; s.y += v.y; s.z += v.z; s.w += v.w;
    }
    int lr = e >> 8, lc2 = e & 255;
    int row = mt * 256 + lr, col = nt * 256 + lc2;
    ushort4 o;
    o.x = (col < row) ? f2bf(s.x) : (ushort_t)0;
    o.y = (col + 1 < row) ? f2bf(s.y) : (ushort_t)0;
    o.z = (col + 2 < row) ? f2bf(s.z) : (ushort_t)0;
    o.w = (col + 3 < row) ? f2bf(s.w) : (ushort_t)0;
    *(ushort4*)(&ob[(size_t)row * L + col]) = o;
  }
}

// ---------- auxiliary kernels ----------
__global__ __launch_bounds__(256) void k_conv(const float* in, ushort_t* out, size_t n) {
  size_t i = ((size_t)blockIdx.x * 256 + threadIdx.x) * 4;
  if (i >= n) return;
  float4 v = *(const float4*)(in + i);
  out[i] = f2bf(v.x); out[i + 1] = f2bf(v.y); out[i + 2] = f2bf(v.z); out[i + 3] = f2bf(v.w);
}

__global__ __launch_bounds__(256) void k_tconv(const float* in, ushort_t* out, int R, int C) {
  __shared__ float t[32][33];
  int c0 = blockIdx.x * 32, r0 = blockIdx.y * 32;
  int tx = threadIdx.x & 31, ty = threadIdx.x >> 5;
#pragma unroll
  for (int i = ty; i < 32; i += 8) t[i][tx] = in[(size_t)(r0 + i) * C + c0 + tx];
  __syncthreads();
#pragma unroll
  for (int i = ty; i < 32; i += 8) out[(size_t)(c0 + i) * R + r0 + tx] = f2bf(t[tx][i]);
}

// fused weight prep: one f32 read -> straight bf16 copy + transposed bf16 copy
__global__ __launch_bounds__(256) void k_wprep(const float* in, ushort_t* outS, ushort_t* outT,
                                               int R, int C) {
  __shared__ float t[32][33];
  int c0 = blockIdx.x * 32, r0 = blockIdx.y * 32;
  int tx = threadIdx.x & 31, ty = threadIdx.x >> 5;
#pragma unroll
  for (int i = ty; i < 32; i += 8) {
    float v = in[(size_t)(r0 + i) * C + c0 + tx];
    t[i][tx] = v;
    outS[(size_t)(r0 + i) * C + c0 + tx] = f2bf(v);
  }
  __syncthreads();
#pragma unroll
  for (int i = ty; i < 32; i += 8) outT[(size_t)(c0 + i) * R + r0 + tx] = f2bf(t[tx][i]);
}

__global__ __launch_bounds__(256) void k_tb2b(const ushort_t* in, ushort_t* out, int L, int C) {
  __shared__ ushort_t t[32][33];
  int b = blockIdx.z;
  const ushort_t* ib = in + (size_t)b * L * C;
  ushort_t* ob = out + (size_t)b * C * L;
  int c0 = blockIdx.x * 32, l0 = blockIdx.y * 32;
  int tx = threadIdx.x & 31, ty = threadIdx.x >> 5;
#pragma unroll
  for (int i = ty; i < 32; i += 8) t[i][tx] = ib[(size_t)(l0 + i) * C + c0 + tx];
  __syncthreads();
#pragma unroll
  for (int i = ty; i < 32; i += 8) ob[(size_t)(c0 + i) * L + l0 + tx] = t[tx][i];
}

__device__ __forceinline__ void blockRed2(float& a, float& b, float* red) {
#pragma unroll
  for (int o = 32; o; o >>= 1) { a += __shfl_down(a, o); b += __shfl_down(b, o); }
  int w = threadIdx.x >> 6;
  if ((threadIdx.x & 63) == 0) { red[w] = a; red[4 + w] = b; }
  __syncthreads();
  a = red[0] + red[1] + red[2] + red[3];
  b = red[4] + red[5] + red[6] + red[7];
  __syncthreads();
}

// fused split-K combine + LN forward (H3 path): h3 = sum_s part[s] + b2; LN; h4b
__global__ __launch_bounds__(256) void k_lncomb(const float* part, const float* bias,
                                                const float* sc, const float* bi, float* nout,
                                                float* rstd, ushort_t* yb, size_t MN, int D,
                                                int S) {
  __shared__ float red[8];
  int row = blockIdx.x;
  int d = threadIdx.x * 4;          // D = 1024 = 256*4
  size_t g = (size_t)row * D + d;
  float4 v = *(const float4*)(part + g);
  for (int s_ = 1; s_ < S; s_++) {
    float4 w = *(const float4*)(part + (size_t)s_ * MN + g);
    v.x += w.x; v.y += w.y; v.z += w.z; v.w += w.w;
  }
  float4 bb = *(const float4*)(bias + d);
  v.x += bb.x; v.y += bb.y; v.z += bb.z; v.w += bb.w;
  float s1 = v.x + v.y + v.z + v.w;
  float s2 = v.x * v.x + v.y * v.y + v.z * v.z + v.w * v.w;
  blockRed2(s1, s2, red);
  float mu = s1 / D;
  float var = s2 / D - mu * mu;
  float rs = rsqrtf(var + 1e-6f);
  float4 nv;
  nv.x = (v.x - mu) * rs; nv.y = (v.y - mu) * rs; nv.z = (v.z - mu) * rs; nv.w = (v.w - mu) * rs;
  *(float4*)(nout + g) = nv;
  float4 scv = *(const float4*)(sc + d);
  float4 biv = *(const float4*)(bi + d);
  ushort4 o;
  o.x = f2bf(nv.x * scv.x + biv.x);
  o.y = f2bf(nv.y * scv.y + biv.y);
  o.z = f2bf(nv.z * scv.z + biv.z);
  o.w = f2bf(nv.w * scv.w + biv.w);
  *(ushort4*)(yb + g) = o;
  if (threadIdx.x == 0) rstd[row] = rs;
}

__global__ __launch_bounds__(256) void k_lnfwd2(const float* X, const float* fs, const float* fb,
                                                ushort_t* yb, int D) {
  __shared__ float red[8];
  int row = blockIdx.x;
  const float* x = X + (size_t)row * D;
  float s = 0.f, s2 = 0.f;
  for (int d = threadIdx.x; d < D; d += 256) { float v = x[d]; s += v; s2 += v * v; }
  blockRed2(s, s2, red);
  float mu = s / D;
  float var = s2 / D - mu * mu;
  float rs = rsqrtf(var + 1e-6f);
  for (int d = threadIdx.x; d < D; d += 256) {
    size_t g = (size_t)row * D + d;
    float nv = (x[d] - mu) * rs;
    yb[g] = f2bf(nv * fs[g] + fb[g]);
  }
}

__global__ __launch_bounds__(256) void k_lnbwd(const float* G, const float* nn, const float* rstd,
                                               const float* sc, ushort_t* g3b, float* gsc, int D) {
  __shared__ float red[8];
  int row = blockIdx.x;
  const float* g = G + (size_t)row * D;
  const float* n_ = nn + (size_t)row * D;
  float sa = 0.f, sb = 0.f;
  for (int d = threadIdx.x; d < D; d += 256) {
    float dn = g[d] * sc[d];
    sa += dn; sb += dn * n_[d];
  }
  blockRed2(sa, sb, red);
  float a = sa / D, b = sb / D, rs = rstd[row];
  for (int d = threadIdx.x; d < D; d += 256) {
    size_t gi = (size_t)row * D + d;
    float dn = g[d] * sc[d];
    g3b[gi] = f2bf(rs * (dn - a - n_[d] * b));
    gsc[gi] = g[d] * n_[d];
  }
}

__global__ __launch_bounds__(256) void k_wsum(const float* w, float* o, int n) {
  __shared__ float red[4];
  float s = 0.f;
  for (int i = threadIdx.x; i < n; i += 256) s += w[i];
#pragma unroll
  for (int d = 32; d; d >>= 1) s += __shfl_down(s, d);
  if ((threadIdx.x & 63) == 0) red[threadIdx.x >> 6] = s;
  __syncthreads();
  if (threadIdx.x == 0) o[0] = fmaxf(red[0] + red[1] + red[2] + red[3], 1e-8f);
}

// register-staged fused softmax-grad: V=8192, 256 thr, 32 elem/thread in VGPRs.
__global__ __launch_bounds__(256) void k_softgrad(const ushort_t* logits, const float* labels,
                                                  const float* w, const float* wsum,
                                                  ushort_t* dlb, int V) {
  __shared__ float red[8];
  const int row = blockIdx.x;
  const int tid = threadIdx.x;
  const ushort_t* l = logits + (size_t)row * V + tid * 32;
  const float* y = labels + (size_t)row * V + tid * 32;
  float lv[32], yv[32];
#pragma unroll
  for (int i = 0; i < 4; i++) {
    us8 u = *reinterpret_cast<const us8*>(l + i * 8);
#pragma unroll
    for (int j = 0; j < 8; j++) lv[i * 8 + j] = bf2f(u[j]);
  }
#pragma unroll
  for (int i = 0; i < 8; i++) {
    float4 v = *reinterpret_cast<const float4*>(y + i * 4);
    yv[i * 4] = v.x; yv[i * 4 + 1] = v.y; yv[i * 4 + 2] = v.z; yv[i * 4 + 3] = v.w;
  }
  float m = lv[0], t = yv[0];
#pragma unroll
  for (int i = 1; i < 32; i++) { m = fmaxf(m, lv[i]); t += yv[i]; }
#pragma unroll
  for (int o = 32; o; o >>= 1) { m = fmaxf(m, __shfl_down(m, o)); t += __shfl_down(t, o); }
  int wv = tid >> 6;
  if ((tid & 63) == 0) { red[wv] = m; red[4 + wv] = t; }
  __syncthreads();
  m = fmaxf(fmaxf(red[0], red[1]), fmaxf(red[2], red[3]));
  t = red[4] + red[5] + red[6] + red[7];
  __syncthreads();
  float s = 0.f;
#pragma unroll
  for (int i = 0; i < 32; i++) { lv[i] = expf(lv[i] - m); s += lv[i]; }
#pragma unroll
  for (int o = 32; o; o >>= 1) s += __shfl_down(s, o);
  if ((tid & 63) == 0) red[wv] = s;
  __syncthreads();
  s = red[0] + red[1] + red[2] + red[3];
  float c = w[row] / wsum[0];
  float ci = c * t / s;
  ushort_t* dl = dlb + (size_t)row * V + tid * 32;
#pragma unroll
  for (int i = 0; i < 4; i++) {
    us8 o;
#pragma unroll
    for (int j = 0; j < 8; j++) o[j] = f2bf(ci * lv[i * 8 + j] - c * yv[i * 8 + j]);
    *reinterpret_cast<us8*>(dl + i * 8) = o;
  }
}

__global__ __launch_bounds__(256) void k_scanpart(const float* gs, const float* gb, float* ps,
                                                  float* pb, int L, int D) {
  int d = blockIdx.x * 256 + threadIdx.x;
  int seg = blockIdx.y, b = blockIdx.z;
  const int SEGL = L / 16;
  size_t base = ((size_t)b * L + seg * SEGL) * D + d;
  float s1 = 0.f, s2 = 0.f;
  for (int i = 0; i < SEGL; i++) { s1 += gs[base + (size_t)i * D]; s2 += gb[base + (size_t)i * D]; }
  size_t pi = ((size_t)b * 16 + seg) * D + d;
  ps[pi] = s1; pb[pi] = s2;
}

__global__ __launch_bounds__(256) void k_scanapply(const float* gs, const float* gb,
                                                   const float* ps, const float* pb,
                                                   const float* sc, const float* bi,
                                                   const float* steps, float* fs, float* fb,
                                                   int L, int D) {
  int d = blockIdx.x * 256 + threadIdx.x;
  int seg = blockIdx.y, b = blockIdx.z;
  const int SEGL = L / 16;
  float ss = steps[3];
  float rs_ = 0.f, rb_ = 0.f;
  for (int s = 0; s < seg; s++) {
    size_t pi = ((size_t)b * 16 + s) * D + d;
    rs_ += ps[pi]; rb_ += pb[pi];
  }
  float s0 = sc[d], b0 = bi[d];
  size_t base = ((size_t)b * L + seg * SEGL) * D + d;
  for (int i = 0; i < SEGL; i++) {
    size_t g = base + (size_t)i * D;
    fs[g] = s0 - ss * rs_;
    fb[g] = b0 - ss * rb_;
    rs_ += gs[g]; rb_ += gb[g];
  }
}

// ---------- orchestration ----------
extern "C" void kernel_launch(void* const* d_in, const int* in_sizes, int n_in, void* d_out,
                              int out_size, void* d_ws, size_t ws_size, hipStream_t stream) {
  const float* x        = (const float*)d_in[0];
  const float* labels   = (const float*)d_in[1];
  const float* weights  = (const float*)d_in[2];
  const float* W1       = (const float*)d_in[3];
  const float* b1       = (const float*)d_in[4];
  const float* W2       = (const float*)d_in[5];
  const float* b2       = (const float*)d_in[6];
  const float* ln_scale = (const float*)d_in[7];
  const float* ln_bias  = (const float*)d_in[8];
  const float* Wu       = (const float*)d_in[9];
  const float* bu       = (const float*)d_in[10];
  const float* steps    = (const float*)d_in[11];

  const int BL = in_sizes[2];   // 4096
  const int D  = in_sizes[7];   // 1024
  const int F  = in_sizes[4];   // 4096
  const int V  = in_sizes[10];  // 8192
  const int Bb = 2, L = BL / Bb;
  const int T2t = (L / 256) * (L / 256 + 1) / 2;   // 36 live 256-tri tiles
  const unsigned SMEM = 2 * 16384 * 2 * 2;         // 128 KB dynamic LDS

  char* ws = (char*)d_ws;
  size_t off = 0;
  auto take = [&](size_t b) { char* p = ws + off; off = (off + b + 255) & ~(size_t)255; return p; };

  ushort_t* xb   = (ushort_t*)take((size_t)BL * D * 2);
  ushort_t* w1t  = (ushort_t*)take((size_t)F * D * 2);
  ushort_t* w2t  = (ushort_t*)take((size_t)D * F * 2);
  ushort_t* w2b  = (ushort_t*)take((size_t)F * D * 2);
  ushort_t* wut  = (ushort_t*)take((size_t)V * D * 2);
  ushort_t* wub  = (ushort_t*)take((size_t)D * V * 2);
  ushort_t* H1b  = (ushort_t*)take((size_t)BL * F * 2);
  ushort_t* H2b  = (ushort_t*)take((size_t)BL * F * 2);
  float*    nbuf = (float*)take((size_t)BL * D * 4);
  float*    rstd = (float*)take((size_t)BL * 4);
  ushort_t* h4b  = (ushort_t*)take((size_t)BL * D * 2);
  float*    wsumb= (float*)take(256);
  float*    G4   = (float*)take((size_t)BL * D * 4);   // also g_bias
  float*    gsc  = (float*)take((size_t)BL * D * 4);   // g_scale
  ushort_t* g3b  = (ushort_t*)take((size_t)BL * D * 2);
  ushort_t* g3t  = (ushort_t*)take((size_t)BL * D * 2);
  float*    fs   = (float*)take((size_t)BL * D * 4);
  float*    fb   = (float*)take((size_t)BL * D * 4);
  ushort_t* x4b  = (ushort_t*)take((size_t)BL * D * 2);
  float*    psc  = (float*)take((size_t)Bb * 16 * D * 4);
  float*    pbi  = (float*)take((size_t)Bb * 16 * D * 4);
  // poolA (134MB): logitsb bf16 / split-K partials -> later {g1b, g1t, S1b, x2b}
  char* poolA = take((size_t)BL * V * 4);
  ushort_t* logitsb = (ushort_t*)poolA;
  float*    partA  = (float*)poolA;
  ushort_t* g1b = (ushort_t*)poolA;
  ushort_t* g1t = (ushort_t*)(poolA + (size_t)BL * F * 2);
  ushort_t* S1b = (ushort_t*)(poolA + (size_t)BL * F * 4);
  ushort_t* x2b = (ushort_t*)(poolA + (size_t)BL * F * 4 + (size_t)Bb * L * L * 2);
  // poolB (64MB): dlb bf16 -> later {S2b, X3, x3}; head hosts S1 partials (36MB)
  char* poolB = take((size_t)BL * V * 2);
  ushort_t* dlb = (ushort_t*)poolB;
  float*    partS1 = (float*)poolB;
  ushort_t* S2b = (ushort_t*)poolB;
  float*    X3  = (float*)(poolB + (size_t)Bb * L * L * 2);
  float*    x3  = (float*)(poolB + (size_t)Bb * L * L * 2 + (size_t)BL * D * 4);

  dim3 blk(256), blk5(512);
  const size_t MN_D = (size_t)BL * D;

  k_conv<<<dim3((unsigned)((size_t)BL * D / 1024)), blk, 0, stream>>>(x, xb, (size_t)BL * D);
  k_tconv<<<dim3(F / 32, D / 32), blk, 0, stream>>>(W1, w1t, D, F);
  k_wprep<<<dim3(D / 32, F / 32), blk, 0, stream>>>(W2, w2b, w2t, F, D);   // straight + (D,F)T
  k_wprep<<<dim3(V / 32, D / 32), blk, 0, stream>>>(Wu, wub, wut, D, V);   // straight + (V,D)T

  GemmP p;
  auto clr = [&]() { p = GemmP{}; };

  // 1) H1b = bf16(x@W1+b1) ; H2b = bf16(relu^2)
  clr(); p.A = xb; p.B = w1t; p.M = BL; p.N = F; p.K = D;
  p.outb = H1b; p.outb2 = H2b; p.bias = b1;
  gemm256<1><<<dim3(F / 256, BL / 256, 1), blk5, SMEM, stream>>>(p);
  // 2) H3 partials [split-K 4] -> fused combine+LN fwd
  clr(); p.A = H2b; p.B = w2t; p.M = BL; p.N = D; p.K = F;
  p.part = partA; p.ksplit = 4; p.Kc = F / 4;
  gemm256<6><<<dim3(D / 256, BL / 256, 4), blk5, SMEM, stream>>>(p);
  k_lncomb<<<dim3(BL), blk, 0, stream>>>(partA, b2, ln_scale, ln_bias, nbuf, rstd, h4b, MN_D, D, 4);
  // 4) logits = bf16(h4@Wu + bu)
  clr(); p.A = h4b; p.B = wut; p.M = BL; p.N = V; p.K = D; p.outb = logitsb; p.bias = bu;
  gemm256<8><<<dim3(V / 256, BL / 256, 1), blk5, SMEM, stream>>>(p);
  // 5) fused softmax grad (register-staged)
  k_wsum<<<dim3(1), blk, 0, stream>>>(weights, wsumb, BL);
  k_softgrad<<<dim3(BL), blk, 0, stream>>>(logitsb, labels, weights, wsumb, dlb, V);
  // 6) G4 = dlogits @ Wu^T   [split-K 4]
  clr(); p.A = dlb; p.B = wub; p.M = BL; p.N = D; p.K = V;
  p.part = partA; p.ksplit = 4; p.Kc = V / 4;
  gemm256<6><<<dim3(D / 256, BL / 256, 4), blk5, SMEM, stream>>>(p);
  k_comb<<<dim3((unsigned)(MN_D / 1024)), blk, 0, stream>>>(partA, nullptr, G4, D, MN_D, 4);
  // 7) LN bwd -> g3, g_scale
  k_lnbwd<<<dim3(BL), blk, 0, stream>>>(G4, nbuf, rstd, ln_scale, g3b, gsc, D);
  // 8) g1 = (g3 @ W2^T) * 2*sqrt(H2)
  clr(); p.A = g3b; p.B = w2b; p.M = BL; p.N = F; p.K = D; p.outb = g1b; p.auxb = H2b;
  gemm256<2><<<dim3(F / 256, BL / 256, 1), blk5, SMEM, stream>>>(p);
  // 9) transposes for attention V-operands
  k_tb2b<<<dim3(F / 32, L / 32, Bb), blk, 0, stream>>>(g1b, g1t, L, F);
  k_tb2b<<<dim3(D / 32, L / 32, Bb), blk, 0, stream>>>(g3b, g3t, L, D);
  // 10) S1 = tril(x x^T, -1)   [split-K 2, compact-tri, partials in poolB]
  clr(); p.A = xb; p.B = xb; p.M = L; p.N = L; p.K = D;
  p.sA = (long long)L * D; p.sB = (long long)L * D;
  p.part = partS1; p.ksplit = 2; p.Kc = D / 2; p.Tt = T2t;
  gemm256<7><<<dim3(T2t, 1, Bb * 2), blk5, SMEM, stream>>>(p);
  k_combtri<<<dim3(T2t, Bb), blk, 0, stream>>>(partS1, S1b, T2t, 2, L);
  // 11) x2 = relu(H1 - ss0 * S1@g1)^2   [K-limited, aux = bf16 H1b]
  clr(); p.A = S1b; p.B = g1t; p.M = L; p.N = F; p.K = L;
  p.sA = (long long)L * L; p.sB = (long long)F * L;
  p.outb = x2b; p.sOutB = (long long)L * F; p.auxb = H1b; p.sAuxF = (long long)L * F;
  p.steps = steps;
  gemm256<4><<<dim3(F / 256, L / 256, Bb), blk5, SMEM, stream>>>(p);
  // 12) X3 = x2@W2 + b2   [split-K 4]
  clr(); p.A = x2b; p.B = w2t; p.M = BL; p.N = D; p.K = F;
  p.part = partA; p.ksplit = 4; p.Kc = F / 4;
  gemm256<6><<<dim3(D / 256, BL / 256, 4), blk5, SMEM, stream>>>(p);
  k_comb<<<dim3((unsigned)(MN_D / 1024)), blk, 0, stream>>>(partA, b2, X3, D, MN_D, 4);
  // 13) S2 = tril(x2 H2^T, -1)   [split-K 4, compact-tri]
  clr(); p.A = x2b; p.B = H2b; p.M = L; p.N = L; p.K = F;
  p.sA = (long long)L * F; p.sB = (long long)L * F;
  p.part = partA; p.ksplit = 4; p.Kc = F / 4; p.Tt = T2t;
  gemm256<7><<<dim3(T2t, 1, Bb * 4), blk5, SMEM, stream>>>(p);
  k_combtri<<<dim3(T2t, Bb), blk, 0, stream>>>(partA, S2b, T2t, 4, L);
  // 14) x3 = X3 - ss2 * S2@g3   [K-limited, 128^2 kernel for grid size]
  clr(); p.A = S2b; p.B = g3t; p.M = L; p.N = D; p.K = L;
  p.sA = (long long)L * L; p.sB = (long long)D * L;
  p.outf = x3; p.sOutF = (long long)L * D; p.auxf = X3; p.sAuxF = (long long)L * D; p.steps = steps;
  gemm_bt<5><<<dim3(D / 128, L / 128, Bb), blk, 0, stream>>>(p);
  // 15) exclusive cumsums -> fast_scale / fast_bias
  k_scanpart<<<dim3(D / 256, 16, Bb), blk, 0, stream>>>(gsc, G4, psc, pbi, L, D);
  k_scanapply<<<dim3(D / 256, 16, Bb), blk, 0, stream>>>(gsc, G4, psc, pbi, ln_scale, ln_bias,
                                                         steps, fs, fb, L, D);
  // 16) x4 = LN(x3)*fast_scale + fast_bias
  k_lnfwd2<<<dim3(BL), blk, 0, stream>>>(x3, fs, fb, x4b, D);
  // 17) out = x4@Wu + bu
  clr(); p.A = x4b; p.B = wut; p.M = BL; p.N = V; p.K = D; p.outf = (float*)d_out; p.bias = bu;
  gemm256<0><<<dim3(V / 256, BL / 256, 1), blk5, SMEM, stream>>>(p);
}

// Round 9
// 1036.448 us; speedup vs baseline: 1.5226x; 1.0369x over previous
//
#include <hip/hip_runtime.h>
#include <cstdint>

typedef unsigned short ushort_t;
typedef __bf16 bf16x8 __attribute__((ext_vector_type(8)));
typedef float f32x4 __attribute__((ext_vector_type(4)));
typedef ushort_t us8 __attribute__((ext_vector_type(8)));

// ---------- helpers ----------
__device__ __forceinline__ ushort_t f2bf(float f) {
  union { float f; unsigned int u; } v; v.f = f;
  unsigned int u = v.u;
  unsigned int r = (u + 0x7fffu + ((u >> 16) & 1u)) >> 16;
  return (ushort_t)r;
}
__device__ __forceinline__ float bf2f(ushort_t u) {
  union { unsigned int u; float f; } v; v.u = ((unsigned int)u) << 16; return v.f;
}

#define GLOAD16(gp, lp)                                                              \
  __builtin_amdgcn_global_load_lds(                                                  \
      reinterpret_cast<const __attribute__((address_space(1))) unsigned int*>(       \
          reinterpret_cast<uintptr_t>(gp)),                                          \
      reinterpret_cast<__attribute__((address_space(3))) unsigned int*>(             \
          reinterpret_cast<uintptr_t>(lp)),                                          \
      16, 0, 0)

// EPI: 0 = outf = acc + bias                     (out)
//      8 = outb = bf16(acc + bias)               (logits)
//      1 = outb = bf16(acc+bias); outb2 = bf16(relu^2)    (H1b + H2b)
//      2 = outb = bf16(acc * 2*sqrt(auxb))       (g1)
//      4 = outb = bf16(relu(bf2f(auxb) - ss0*acc)^2); K-limit  (x2)
//      5 = outf = auxf - ss2*acc; K-limit        (x3, 128^2 kernel)
//      6 = split-K partial, full-matrix f32      (H3, G4, X3 stage 1)
//      7 = split-K partial, compact-tri grid, 256x256 tiles   (S1, S2 stage 1)
struct GemmP {
  const ushort_t* A; const ushort_t* B;
  int M, N, K;
  long long sA, sB;
  float* outf;   long long sOutF;
  ushort_t* outb; long long sOutB;
  ushort_t* outb2;
  const float* bias;
  const float* auxf; long long sAuxF;   // sAuxF doubles as aux (f32 or bf16) stride
  const ushort_t* auxb;
  const float* steps;
  float* part; int ksplit, Kc, Tt;
};

// ---------- 256x256 GEMM: 8 waves, BK=32, 4-buffer depth-3 MLP pipeline ----------
// Diagnosis (R8): dispatches run at exactly FETCH+WRITE / 1.2 TB/s -> HBM-latency
// (MLP) bound: barrier-locked phases kept only ~2 gloads in flight per wave.
// Fix: 4 LDS buffers, prefetch distance 3, ONE barrier per K-tile. Steady state:
// iter t computes T(t) (resident), issues T(t+3); outstanding {T+1,T+2,T+3}=12
// loads; end-of-iter vmcnt(8) retires T(t+1) only -> 8-12 loads ALWAYS in flight.
// Buffer recycle: T(t+3) -> buf((t+3)%4) held T(t-1) whose reads finished before
// iter-(t-1)'s closing barrier. Own-wave vmcnt + barrier publishes T(t+1) to all.
// LDS slot-XOR swizzle (T2, rule #21) unchanged (bank-conflict = 0 measured).
template <int EPI>
__global__ __launch_bounds__(512, 2) void gemm256(GemmP p) {
  const int nwg = gridDim.x * gridDim.y;
  const int orig = blockIdx.y * gridDim.x + blockIdx.x;
  const int xcd = orig & 7, loc = orig >> 3;
  const int q8 = nwg >> 3, r8 = nwg & 7;
  const int wg = (xcd < r8) ? (xcd * (q8 + 1) + loc) : (r8 * (q8 + 1) + (xcd - r8) * q8 + loc);
  int mt, nt;
  if (EPI == 7) {            // compact lower-tri tile index -> (mt, nt)
    int t_ = wg;
    mt = (int)((sqrtf(8.f * t_ + 1.f) - 1.f) * 0.5f);
    while ((mt + 1) * (mt + 2) / 2 <= t_) mt++;
    while (mt * (mt + 1) / 2 > t_) mt--;
    nt = t_ - mt * (mt + 1) / 2;
  } else {
    nt = wg % gridDim.x; mt = wg / gridDim.x;
  }
  const int m0 = mt * 256, n0 = nt * 256;

  int bz = blockIdx.z, ks = 0;
  if (EPI == 6 || EPI == 7) { bz = blockIdx.z / p.ksplit; ks = blockIdx.z % p.ksplit; }

  const ushort_t* A = p.A + (size_t)bz * p.sA;
  const ushort_t* B = p.B + (size_t)bz * p.sB;

  int kbeg = 0, kend = p.K;
  if (EPI == 6 || EPI == 7) { kbeg = ks * p.Kc; kend = kbeg + p.Kc; }
  else if (EPI == 4) kend = min(p.K, m0 + 256);

  extern __shared__ ushort_t smem[];      // 4 bufs x (16KB A + 16KB B) = 128KB
  ushort_t* sA = smem;
  ushort_t* sB = smem + 4 * 8192;

  const int tid = threadIdx.x;
  const int wid = tid >> 6, lane = tid & 63;
  const int wm = wid >> 2, wn = wid & 3;

  f32x4 acc[8][4];
#pragma unroll
  for (int i = 0; i < 8; i++)
#pragma unroll
    for (int j = 0; j < 4; j++) acc[i][j] = f32x4{0.f, 0.f, 0.f, 0.f};

  // staging: chunk = 16 rows x 32 cols = 1KB (64 lanes x 16B). Wave w stages
  // A-chunks {w, w+8}, B-chunks {w, w+8}. Source col pre-swizzled so the linear
  // gload_lds dest lands swizzled.
  const int lr = lane >> 2;
  const int lcsw = (((lane & 3) ^ ((lr >> 1) & 3)) * 8);
  const int rT0 = wid * 16 + lr;
  const int rT1 = 128 + wid * 16 + lr;
  const ushort_t* gA0 = A + (size_t)(m0 + rT0) * p.K + lcsw;
  const ushort_t* gA1 = A + (size_t)(m0 + rT1) * p.K + lcsw;
  const ushort_t* gB0 = B + (size_t)(n0 + rT0) * p.K + lcsw;
  const ushort_t* gB1 = B + (size_t)(n0 + rT1) * p.K + lcsw;
  ushort_t* lA0 = &sA[wid * 512];
  ushort_t* lA1 = &sA[(8 + wid) * 512];
  ushort_t* lB0 = &sB[wid * 512];
  ushort_t* lB1 = &sB[(8 + wid) * 512];

  // ds_read offsets (loop-invariant, within one 8192-elem buffer)
  const int fr = lane & 15;
  const int q = lane >> 4;
  const int slot = (q ^ ((fr >> 1) & 3)) * 8;
  int offA[8], offB[4];
#pragma unroll
  for (int i = 0; i < 8; i++) offA[i] = (wm * 8 + i) * 512 + fr * 32 + slot;
#pragma unroll
  for (int j = 0; j < 4; j++) offB[j] = (wn * 4 + j) * 512 + fr * 32 + slot;

  const int nT = (kend - kbeg) >> 5;    // BK = 32
  auto stage4 = [&](int t) {            // tile t -> buf t%4 (4 gloads)
    const int kk = kbeg + t * 32;
    const int o = (t & 3) * 8192;
    GLOAD16(gA0 + kk, lA0 + o);
    GLOAD16(gA1 + kk, lA1 + o);
    GLOAD16(gB0 + kk, lB0 + o);
    GLOAD16(gB1 + kk, lB1 + o);
  };
  // prologue: issue T0,T1,T2; wait T0 resident only (T1,T2 stay in flight)
  stage4(0);
  if (nT > 1) stage4(1);
  if (nT > 2) stage4(2);
  if (nT > 2)      { asm volatile("s_waitcnt vmcnt(8)" ::: "memory"); }
  else if (nT > 1) { asm volatile("s_waitcnt vmcnt(4)" ::: "memory"); }
  else             { asm volatile("s_waitcnt vmcnt(0)" ::: "memory"); }
  __builtin_amdgcn_s_barrier();

  for (int t = 0; t < nT; ++t) {
    const int co = (t & 3) * 8192;
    if (t + 3 < nT) stage4(t + 3);           // keep the HBM queue deep
    __builtin_amdgcn_sched_barrier(0);       // pin stage issue ahead of reads
    bf16x8 av[8], bv[4];
#pragma unroll
    for (int j = 0; j < 4; j++) bv[j] = *reinterpret_cast<const bf16x8*>(&sB[co + offB[j]]);
#pragma unroll
    for (int i = 0; i < 8; i++) av[i] = *reinterpret_cast<const bf16x8*>(&sA[co + offA[i]]);
    __builtin_amdgcn_s_setprio(1);
#pragma unroll
    for (int i = 0; i < 8; i++)
#pragma unroll
      for (int j = 0; j < 4; j++)
        acc[i][j] = __builtin_amdgcn_mfma_f32_16x16x32_bf16(av[i], bv[j], acc[i][j], 0, 0, 0);
    __builtin_amdgcn_s_setprio(0);
    // retire ONLY T(t+1) before publishing; deeper prefetches stay in flight
    if (t + 3 < nT)      { asm volatile("s_waitcnt vmcnt(8)" ::: "memory"); }
    else if (t + 2 < nT) { asm volatile("s_waitcnt vmcnt(4)" ::: "memory"); }
    else if (t + 1 < nT) { asm volatile("s_waitcnt vmcnt(0)" ::: "memory"); }
    __builtin_amdgcn_s_barrier();
  }

  const int fq = q;
  float ss = 0.f;
  if (EPI == 4) ss = p.steps[0];
  float* outf = p.outf ? p.outf + (size_t)bz * p.sOutF : nullptr;
  ushort_t* outb = p.outb ? p.outb + (size_t)bz * p.sOutB : nullptr;
  ushort_t* outb2 = p.outb2;
  const ushort_t* auxb = p.auxb ? p.auxb + (size_t)bz * p.sAuxF : nullptr;
  float* partT = nullptr;
  if (EPI == 6) partT = p.part + (size_t)blockIdx.z * p.M * p.N;
  if (EPI == 7) partT = p.part + ((size_t)blockIdx.z * p.Tt + wg) * 65536;

#pragma unroll
  for (int i = 0; i < 8; i++) {
#pragma unroll
    for (int j = 0; j < 4; j++) {
#pragma unroll
      for (int r2 = 0; r2 < 4; r2++) {
        int lrow = wm * 128 + i * 16 + fq * 4 + r2;
        int lcol = wn * 64 + j * 16 + fr;
        int row = m0 + lrow, col = n0 + lcol;
        size_t g = (size_t)row * p.N + col;
        float v = acc[i][j][r2];
        if (EPI == 0) {
          outf[g] = v + (p.bias ? p.bias[col] : 0.f);
        } else if (EPI == 8) {
          outb[g] = f2bf(v + p.bias[col]);
        } else if (EPI == 1) {
          v += p.bias[col];
          outb[g] = f2bf(v);
          float rl = fmaxf(v, 0.f);
          outb2[g] = f2bf(rl * rl);
        } else if (EPI == 2) {
          outb[g] = f2bf(v * 2.f * sqrtf(bf2f(auxb[g])));
        } else if (EPI == 4) {
          float x1 = bf2f(auxb[g]) - ss * v;
          float rl = fmaxf(x1, 0.f);
          outb[g] = f2bf(rl * rl);
        } else if (EPI == 6) {
          partT[g] = v;
        } else if (EPI == 7) {
          partT[lrow * 256 + lcol] = v;
        }
      }
    }
  }
}

// ---------- 128x128 GEMM (proven R4 pipeline) -- kept for x3 (EPI 5) ----------
template <int EPI>
__global__ __launch_bounds__(256) void gemm_bt(GemmP p) {
  const int nwg = gridDim.x * gridDim.y;
  const int orig = blockIdx.y * gridDim.x + blockIdx.x;
  const int xcd = orig & 7, loc = orig >> 3;
  const int q = nwg >> 3, r = nwg & 7;
  const int wg = (xcd < r) ? (xcd * (q + 1) + loc) : (r * (q + 1) + (xcd - r) * q + loc);
  const int nt = wg % gridDim.x, mt = wg / gridDim.x;
  const int m0 = mt * 128, n0 = nt * 128;
  const int bz = blockIdx.z;

  const ushort_t* A = p.A + (size_t)bz * p.sA;
  const ushort_t* B = p.B + (size_t)bz * p.sB;

  int kend = p.K;
  if (EPI == 5) kend = min(p.K, m0 + 128);

  __shared__ ushort_t sA[4 * 128 * 32];
  __shared__ ushort_t sB[4 * 128 * 32];

  const int tid = threadIdx.x;
  const int wid = tid >> 6, lane = tid & 63;
  const int wm = wid >> 1, wn = wid & 1;

  f32x4 acc[4][4];
#pragma unroll
  for (int i = 0; i < 4; i++)
#pragma unroll
    for (int j = 0; j < 4; j++) acc[i][j] = f32x4{0.f, 0.f, 0.f, 0.f};

  const int lr = lane >> 2;
  const int lc = (lane & 3) * 8;
  const int rA0 = wid * 16 + lr;
  const int rA1 = 64 + wid * 16 + lr;
  const ushort_t* gA0 = A + (size_t)(m0 + rA0) * p.K + lc;
  const ushort_t* gA1 = A + (size_t)(m0 + rA1) * p.K + lc;
  const ushort_t* gB0 = B + (size_t)(n0 + rA0) * p.K + lc;
  const ushort_t* gB1 = B + (size_t)(n0 + rA1) * p.K + lc;
  ushort_t* lA0 = &sA[wid * 512];
  ushort_t* lA1 = &sA[(4 + wid) * 512];
  ushort_t* lB0 = &sB[wid * 512];
  ushort_t* lB1 = &sB[(4 + wid) * 512];

  const int fr = lane & 15;
  const int kb = (lane >> 4) * 8;

  const int nIter = kend >> 5;
  auto stage = [&](int t) {
    const int kk = t * 32;
    const int o = (t & 3) * 4096;
    GLOAD16(gA0 + kk, lA0 + o);
    GLOAD16(gA1 + kk, lA1 + o);
    GLOAD16(gB0 + kk, lB0 + o);
    GLOAD16(gB1 + kk, lB1 + o);
  };
  stage(0);
  if (nIter > 1) stage(1);
  if (nIter > 2) stage(2);
  if (nIter > 2)      { asm volatile("s_waitcnt vmcnt(8)" ::: "memory"); }
  else if (nIter > 1) { asm volatile("s_waitcnt vmcnt(4)" ::: "memory"); }
  else                { asm volatile("s_waitcnt vmcnt(0)" ::: "memory"); }
  __builtin_amdgcn_s_barrier();

  for (int t = 0; t < nIter; ++t) {
    const int co = (t & 3) * 4096;
    if (t + 3 < nIter) stage(t + 3);
    __builtin_amdgcn_sched_barrier(0);
    bf16x8 av[4], bv[4];
#pragma unroll
    for (int i = 0; i < 4; i++) {
      av[i] = *reinterpret_cast<const bf16x8*>(&sA[co + (wm * 64 + i * 16 + fr) * 32 + kb]);
      bv[i] = *reinterpret_cast<const bf16x8*>(&sB[co + (wn * 64 + i * 16 + fr) * 32 + kb]);
    }
    __builtin_amdgcn_s_setprio(1);
#pragma unroll
    for (int i = 0; i < 4; i++)
#pragma unroll
      for (int j = 0; j < 4; j++)
        acc[i][j] = __builtin_amdgcn_mfma_f32_16x16x32_bf16(av[i], bv[j], acc[i][j], 0, 0, 0);
    __builtin_amdgcn_s_setprio(0);
    if (t + 3 < nIter)      { asm volatile("s_waitcnt vmcnt(8)" ::: "memory"); }
    else if (t + 2 < nIter) { asm volatile("s_waitcnt vmcnt(4)" ::: "memory"); }
    else if (t + 1 < nIter) { asm volatile("s_waitcnt vmcnt(0)" ::: "memory"); }
    __builtin_amdgcn_s_barrier();
  }

  const int fq = lane >> 4;
  float ss = (EPI == 5) ? p.steps[2] : 0.f;
  float* outf = p.outf ? p.outf + (size_t)bz * p.sOutF : nullptr;
  const float* auxf = p.auxf ? p.auxf + (size_t)bz * p.sAuxF : nullptr;

#pragma unroll
  for (int i = 0; i < 4; i++) {
#pragma unroll
    for (int j = 0; j < 4; j++) {
#pragma unroll
      for (int r2 = 0; r2 < 4; r2++) {
        int row = m0 + wm * 64 + i * 16 + fq * 4 + r2;
        int col = n0 + wn * 64 + j * 16 + fr;
        size_t g = (size_t)row * p.N + col;
        float v = acc[i][j][r2];
        if (EPI == 5) {
          outf[g] = auxf[g] - ss * v;
        } else {
          outf[g] = v + (p.bias ? p.bias[col] : 0.f);
        }
      }
    }
  }
}

// ---------- split-K combines ----------
__global__ __launch_bounds__(256) void k_comb(const float* part, const float* bias, float* out,
                                              int N, size_t MN, int S) {
  size_t e = ((size_t)blockIdx.x * 256 + threadIdx.x) * 4;
  if (e >= MN) return;
  float4 s = *(const float4*)(part + e);
  for (int p_ = 1; p_ < S; p_++) {
    float4 v = *(const float4*)(part + (size_t)p_ * MN + e);
    s.x += v.x; s.y += v.y; s.z += v.z; s.w += v.w;
  }
  if (bias) {
    int col = (int)(e % (size_t)N);
    s.x += bias[col]; s.y += bias[col + 1]; s.z += bias[col + 2]; s.w += bias[col + 3];
  }
  *(float4*)(out + e) = s;
}

// 256x256 compact-tri combine: S_bf16 = tril(sum_s part[s], -1)
__global__ __launch_bounds__(256) void k_combtri(const float* part, ushort_t* out, int Tt, int S,
                                                 int L) {
  int t = blockIdx.x, bz = blockIdx.y;
  int mt = (int)((sqrtf(8.f * t + 1.f) - 1.f) * 0.5f);
  while ((mt + 1) * (mt + 2) / 2 <= t) mt++;
  while (mt * (mt + 1) / 2 > t) mt--;
  int nt = t - mt * (mt + 1) / 2;
  const float* pb = part + ((size_t)bz * S * Tt + t) * 65536;
  ushort_t* ob = out + (size_t)bz * L * L;
  for (int e4 = threadIdx.x; e4 < 16384; e4 += 256) {
    int e = e4 * 4;
    float4 s = *(const float4*)(pb + e);
    for (int p_ = 1; p_ < S; p_++) {
      float4 v = *(const float4*)(pb + (size_t)p_ * Tt * 65536 + e);
      s.x += v.x; s.y += v.y; s.z += v.z; s.w += v.w;
    }
    int lr = e >> 8, lc2 = e & 255;
    int row = mt * 256 + lr, col = nt * 256 + lc2;
    ushort4 o;
    o.x = (col < row) ? f2bf(s.x) : (ushort_t)0;
    o.y = (col + 1 < row) ? f2bf(s.y) : (ushort_t)0;
    o.z = (col + 2 < row) ? f2bf(s.z) : (ushort_t)0;
    o.w = (col + 3 < row) ? f2bf(s.w) : (ushort_t)0;
    *(ushort4*)(&ob[(size_t)row * L + col]) = o;
  }
}

// ---------- auxiliary kernels ----------
__global__ __launch_bounds__(256) void k_conv(const float* in, ushort_t* out, size_t n) {
  size_t i = ((size_t)blockIdx.x * 256 + threadIdx.x) * 4;
  if (i >= n) return;
  float4 v = *(const float4*)(in + i);
  out[i] = f2bf(v.x); out[i + 1] = f2bf(v.y); out[i + 2] = f2bf(v.z); out[i + 3] = f2bf(v.w);
}

__global__ __launch_bounds__(256) void k_tconv(const float* in, ushort_t* out, int R, int C) {
  __shared__ float t[32][33];
  int c0 = blockIdx.x * 32, r0 = blockIdx.y * 32;
  int tx = threadIdx.x & 31, ty = threadIdx.x >> 5;
#pragma unroll
  for (int i = ty; i < 32; i += 8) t[i][tx] = in[(size_t)(r0 + i) * C + c0 + tx];
  __syncthreads();
#pragma unroll
  for (int i = ty; i < 32; i += 8) out[(size_t)(c0 + i) * R + r0 + tx] = f2bf(t[tx][i]);
}

// fused weight prep: one f32 read -> straight bf16 copy + transposed bf16 copy
__global__ __launch_bounds__(256) void k_wprep(const float* in, ushort_t* outS, ushort_t* outT,
                                               int R, int C) {
  __shared__ float t[32][33];
  int c0 = blockIdx.x * 32, r0 = blockIdx.y * 32;
  int tx = threadIdx.x & 31, ty = threadIdx.x >> 5;
#pragma unroll
  for (int i = ty; i < 32; i += 8) {
    float v = in[(size_t)(r0 + i) * C + c0 + tx];
    t[i][tx] = v;
    outS[(size_t)(r0 + i) * C + c0 + tx] = f2bf(v);
  }
  __syncthreads();
#pragma unroll
  for (int i = ty; i < 32; i += 8) outT[(size_t)(c0 + i) * R + r0 + tx] = f2bf(t[tx][i]);
}

__global__ __launch_bounds__(256) void k_tb2b(const ushort_t* in, ushort_t* out, int L, int C) {
  __shared__ ushort_t t[32][33];
  int b = blockIdx.z;
  const ushort_t* ib = in + (size_t)b * L * C;
  ushort_t* ob = out + (size_t)b * C * L;
  int c0 = blockIdx.x * 32, l0 = blockIdx.y * 32;
  int tx = threadIdx.x & 31, ty = threadIdx.x >> 5;
#pragma unroll
  for (int i = ty; i < 32; i += 8) t[i][tx] = ib[(size_t)(l0 + i) * C + c0 + tx];
  __syncthreads();
#pragma unroll
  for (int i = ty; i < 32; i += 8) ob[(size_t)(c0 + i) * L + l0 + tx] = t[tx][i];
}

__device__ __forceinline__ void blockRed2(float& a, float& b, float* red) {
#pragma unroll
  for (int o = 32; o; o >>= 1) { a += __shfl_down(a, o); b += __shfl_down(b, o); }
  int w = threadIdx.x >> 6;
  if ((threadIdx.x & 63) == 0) { red[w] = a; red[4 + w] = b; }
  __syncthreads();
  a = red[0] + red[1] + red[2] + red[3];
  b = red[4] + red[5] + red[6] + red[7];
  __syncthreads();
}

// fused split-K combine + LN forward (H3 path): h3 = sum_s part[s] + b2; LN; h4b
__global__ __launch_bounds__(256) void k_lncomb(const float* part, const float* bias,
                                                const float* sc, const float* bi, float* nout,
                                                float* rstd, ushort_t* yb, size_t MN, int D,
                                                int S) {
  __shared__ float red[8];
  int row = blockIdx.x;
  int d = threadIdx.x * 4;          // D = 1024 = 256*4
  size_t g = (size_t)row * D + d;
  float4 v = *(const float4*)(part + g);
  for (int s_ = 1; s_ < S; s_++) {
    float4 w = *(const float4*)(part + (size_t)s_ * MN + g);
    v.x += w.x; v.y += w.y; v.z += w.z; v.w += w.w;
  }
  float4 bb = *(const float4*)(bias + d);
  v.x += bb.x; v.y += bb.y; v.z += bb.z; v.w += bb.w;
  float s1 = v.x + v.y + v.z + v.w;
  float s2 = v.x * v.x + v.y * v.y + v.z * v.z + v.w * v.w;
  blockRed2(s1, s2, red);
  float mu = s1 / D;
  float var = s2 / D - mu * mu;
  float rs = rsqrtf(var + 1e-6f);
  float4 nv;
  nv.x = (v.x - mu) * rs; nv.y = (v.y - mu) * rs; nv.z = (v.z - mu) * rs; nv.w = (v.w - mu) * rs;
  *(float4*)(nout + g) = nv;
  float4 scv = *(const float4*)(sc + d);
  float4 biv = *(const float4*)(bi + d);
  ushort4 o;
  o.x = f2bf(nv.x * scv.x + biv.x);
  o.y = f2bf(nv.y * scv.y + biv.y);
  o.z = f2bf(nv.z * scv.z + biv.z);
  o.w = f2bf(nv.w * scv.w + biv.w);
  *(ushort4*)(yb + g) = o;
  if (threadIdx.x == 0) rstd[row] = rs;
}

__global__ __launch_bounds__(256) void k_lnfwd2(const float* X, const float* fs, const float* fb,
                                                ushort_t* yb, int D) {
  __shared__ float red[8];
  int row = blockIdx.x;
  const float* x = X + (size_t)row * D;
  float s = 0.f, s2 = 0.f;
  for (int d = threadIdx.x; d < D; d += 256) { float v = x[d]; s += v; s2 += v * v; }
  blockRed2(s, s2, red);
  float mu = s / D;
  float var = s2 / D - mu * mu;
  float rs = rsqrtf(var + 1e-6f);
  for (int d = threadIdx.x; d < D; d += 256) {
    size_t g = (size_t)row * D + d;
    float nv = (x[d] - mu) * rs;
    yb[g] = f2bf(nv * fs[g] + fb[g]);
  }
}

__global__ __launch_bounds__(256) void k_lnbwd(const float* G, const float* nn, const float* rstd,
                                               const float* sc, ushort_t* g3b, float* gsc, int D) {
  __shared__ float red[8];
  int row = blockIdx.x;
  const float* g = G + (size_t)row * D;
  const float* n_ = nn + (size_t)row * D;
  float sa = 0.f, sb = 0.f;
  for (int d = threadIdx.x; d < D; d += 256) {
    float dn = g[d] * sc[d];
    sa += dn; sb += dn * n_[d];
  }
  blockRed2(sa, sb, red);
  float a = sa / D, b = sb / D, rs = rstd[row];
  for (int d = threadIdx.x; d < D; d += 256) {
    size_t gi = (size_t)row * D + d;
    float dn = g[d] * sc[d];
    g3b[gi] = f2bf(rs * (dn - a - n_[d] * b));
    gsc[gi] = g[d] * n_[d];
  }
}

__global__ __launch_bounds__(256) void k_wsum(const float* w, float* o, int n) {
  __shared__ float red[4];
  float s = 0.f;
  for (int i = threadIdx.x; i < n; i += 256) s += w[i];
#pragma unroll
  for (int d = 32; d; d >>= 1) s += __shfl_down(s, d);
  if ((threadIdx.x & 63) == 0) red[threadIdx.x >> 6] = s;
  __syncthreads();
  if (threadIdx.x == 0) o[0] = fmaxf(red[0] + red[1] + red[2] + red[3], 1e-8f);
}

// register-staged fused softmax-grad: V=8192, 256 thr, 32 elem/thread in VGPRs.
__global__ __launch_bounds__(256) void k_softgrad(const ushort_t* logits, const float* labels,
                                                  const float* w, const float* wsum,
                                                  ushort_t* dlb, int V) {
  __shared__ float red[8];
  const int row = blockIdx.x;
  const int tid = threadIdx.x;
  const ushort_t* l = logits + (size_t)row * V + tid * 32;
  const float* y = labels + (size_t)row * V + tid * 32;
  float lv[32], yv[32];
#pragma unroll
  for (int i = 0; i < 4; i++) {
    us8 u = *reinterpret_cast<const us8*>(l + i * 8);
#pragma unroll
    for (int j = 0; j < 8; j++) lv[i * 8 + j] = bf2f(u[j]);
  }
#pragma unroll
  for (int i = 0; i < 8; i++) {
    float4 v = *reinterpret_cast<const float4*>(y + i * 4);
    yv[i * 4] = v.x; yv[i * 4 + 1] = v.y; yv[i * 4 + 2] = v.z; yv[i * 4 + 3] = v.w;
  }
  float m = lv[0], t = yv[0];
#pragma unroll
  for (int i = 1; i < 32; i++) { m = fmaxf(m, lv[i]); t += yv[i]; }
#pragma unroll
  for (int o = 32; o; o >>= 1) { m = fmaxf(m, __shfl_down(m, o)); t += __shfl_down(t, o); }
  int wv = tid >> 6;
  if ((tid & 63) == 0) { red[wv] = m; red[4 + wv] = t; }
  __syncthreads();
  m = fmaxf(fmaxf(red[0], red[1]), fmaxf(red[2], red[3]));
  t = red[4] + red[5] + red[6] + red[7];
  __syncthreads();
  float s = 0.f;
#pragma unroll
  for (int i = 0; i < 32; i++) { lv[i] = expf(lv[i] - m); s += lv[i]; }
#pragma unroll
  for (int o = 32; o; o >>= 1) s += __shfl_down(s, o);
  if ((tid & 63) == 0) red[wv] = s;
  __syncthreads();
  s = red[0] + red[1] + red[2] + red[3];
  float c = w[row] / wsum[0];
  float ci = c * t / s;
  ushort_t* dl = dlb + (size_t)row * V + tid * 32;
#pragma unroll
  for (int i = 0; i < 4; i++) {
    us8 o;
#pragma unroll
    for (int j = 0; j < 8; j++) o[j] = f2bf(ci * lv[i * 8 + j] - c * yv[i * 8 + j]);
    *reinterpret_cast<us8*>(dl + i * 8) = o;
  }
}

__global__ __launch_bounds__(256) void k_scanpart(const float* gs, const float* gb, float* ps,
                                                  float* pb, int L, int D) {
  int d = blockIdx.x * 256 + threadIdx.x;
  int seg = blockIdx.y, b = blockIdx.z;
  const int SEGL = L / 16;
  size_t base = ((size_t)b * L + seg * SEGL) * D + d;
  float s1 = 0.f, s2 = 0.f;
  for (int i = 0; i < SEGL; i++) { s1 += gs[base + (size_t)i * D]; s2 += gb[base + (size_t)i * D]; }
  size_t pi = ((size_t)b * 16 + seg) * D + d;
  ps[pi] = s1; pb[pi] = s2;
}

__global__ __launch_bounds__(256) void k_scanapply(const float* gs, const float* gb,
                                                   const float* ps, const float* pb,
                                                   const float* sc, const float* bi,
                                                   const float* steps, float* fs, float* fb,
                                                   int L, int D) {
  int d = blockIdx.x * 256 + threadIdx.x;
  int seg = blockIdx.y, b = blockIdx.z;
  const int SEGL = L / 16;
  float ss = steps[3];
  float rs_ = 0.f, rb_ = 0.f;
  for (int s = 0; s < seg; s++) {
    size_t pi = ((size_t)b * 16 + s) * D + d;
    rs_ += ps[pi]; rb_ += pb[pi];
  }
  float s0 = sc[d], b0 = bi[d];
  size_t base = ((size_t)b * L + seg * SEGL) * D + d;
  for (int i = 0; i < SEGL; i++) {
    size_t g = base + (size_t)i * D;
    fs[g] = s0 - ss * rs_;
    fb[g] = b0 - ss * rb_;
    rs_ += gs[g]; rb_ += gb[g];
  }
}

// ---------- orchestration ----------
extern "C" void kernel_launch(void* const* d_in, const int* in_sizes, int n_in, void* d_out,
                              int out_size, void* d_ws, size_t ws_size, hipStream_t stream) {
  const float* x        = (const float*)d_in[0];
  const float* labels   = (const float*)d_in[1];
  const float* weights  = (const float*)d_in[2];
  const float* W1       = (const float*)d_in[3];
  const float* b1       = (const float*)d_in[4];
  const float* W2       = (const float*)d_in[5];
  const float* b2       = (const float*)d_in[6];
  const float* ln_scale = (const float*)d_in[7];
  const float* ln_bias  = (const float*)d_in[8];
  const float* Wu       = (const float*)d_in[9];
  const float* bu       = (const float*)d_in[10];
  const float* steps    = (const float*)d_in[11];

  const int BL = in_sizes[2];   // 4096
  const int D  = in_sizes[7];   // 1024
  const int F  = in_sizes[4];   // 4096
  const int V  = in_sizes[10];  // 8192
  const int Bb = 2, L = BL / Bb;
  const int T2t = (L / 256) * (L / 256 + 1) / 2;   // 36 live 256-tri tiles
  const unsigned SMEM = 4 * 8192 * 2 * 2;          // 128 KB dynamic LDS

  char* ws = (char*)d_ws;
  size_t off = 0;
  auto take = [&](size_t b) { char* p = ws + off; off = (off + b + 255) & ~(size_t)255; return p; };

  ushort_t* xb   = (ushort_t*)take((size_t)BL * D * 2);
  ushort_t* w1t  = (ushort_t*)take((size_t)F * D * 2);
  ushort_t* w2t  = (ushort_t*)take((size_t)D * F * 2);
  ushort_t* w2b  = (ushort_t*)take((size_t)F * D * 2);
  ushort_t* wut  = (ushort_t*)take((size_t)V * D * 2);
  ushort_t* wub  = (ushort_t*)take((size_t)D * V * 2);
  ushort_t* H1b  = (ushort_t*)take((size_t)BL * F * 2);
  ushort_t* H2b  = (ushort_t*)take((size_t)BL * F * 2);
  float*    nbuf = (float*)take((size_t)BL * D * 4);
  float*    rstd = (float*)take((size_t)BL * 4);
  ushort_t* h4b  = (ushort_t*)take((size_t)BL * D * 2);
  float*    wsumb= (float*)take(256);
  float*    G4   = (float*)take((size_t)BL * D * 4);   // also g_bias
  float*    gsc  = (float*)take((size_t)BL * D * 4);   // g_scale
  ushort_t* g3b  = (ushort_t*)take((size_t)BL * D * 2);
  ushort_t* g3t  = (ushort_t*)take((size_t)BL * D * 2);
  float*    fs   = (float*)take((size_t)BL * D * 4);
  float*    fb   = (float*)take((size_t)BL * D * 4);
  ushort_t* x4b  = (ushort_t*)take((size_t)BL * D * 2);
  float*    psc  = (float*)take((size_t)Bb * 16 * D * 4);
  float*    pbi  = (float*)take((size_t)Bb * 16 * D * 4);
  // poolA (134MB): logitsb bf16 / split-K partials -> later {g1b, g1t, S1b, x2b}
  char* poolA = take((size_t)BL * V * 4);
  ushort_t* logitsb = (ushort_t*)poolA;
  float*    partA  = (float*)poolA;
  ushort_t* g1b = (ushort_t*)poolA;
  ushort_t* g1t = (ushort_t*)(poolA + (size_t)BL * F * 2);
  ushort_t* S1b = (ushort_t*)(poolA + (size_t)BL * F * 4);
  ushort_t* x2b = (ushort_t*)(poolA + (size_t)BL * F * 4 + (size_t)Bb * L * L * 2);
  // poolB (64MB): dlb bf16 -> later {S2b, X3, x3}; head hosts S1 partials (36MB)
  char* poolB = take((size_t)BL * V * 2);
  ushort_t* dlb = (ushort_t*)poolB;
  float*    partS1 = (float*)poolB;
  ushort_t* S2b = (ushort_t*)poolB;
  float*    X3  = (float*)(poolB + (size_t)Bb * L * L * 2);
  float*    x3  = (float*)(poolB + (size_t)Bb * L * L * 2 + (size_t)BL * D * 4);

  dim3 blk(256), blk5(512);
  const size_t MN_D = (size_t)BL * D;

  k_conv<<<dim3((unsigned)((size_t)BL * D / 1024)), blk, 0, stream>>>(x, xb, (size_t)BL * D);
  k_tconv<<<dim3(F / 32, D / 32), blk, 0, stream>>>(W1, w1t, D, F);
  k_wprep<<<dim3(D / 32, F / 32), blk, 0, stream>>>(W2, w2b, w2t, F, D);   // straight + (D,F)T
  k_wprep<<<dim3(V / 32, D / 32), blk, 0, stream>>>(Wu, wub, wut, D, V);   // straight + (V,D)T

  GemmP p;
  auto clr = [&]() { p = GemmP{}; };

  // 1) H1b = bf16(x@W1+b1) ; H2b = bf16(relu^2)
  clr(); p.A = xb; p.B = w1t; p.M = BL; p.N = F; p.K = D;
  p.outb = H1b; p.outb2 = H2b; p.bias = b1;
  gemm256<1><<<dim3(F / 256, BL / 256, 1), blk5, SMEM, stream>>>(p);
  // 2) H3 partials [split-K 4] -> fused combine+LN fwd
  clr(); p.A = H2b; p.B = w2t; p.M = BL; p.N = D; p.K = F;
  p.part = partA; p.ksplit = 4; p.Kc = F / 4;
  gemm256<6><<<dim3(D / 256, BL / 256, 4), blk5, SMEM, stream>>>(p);
  k_lncomb<<<dim3(BL), blk, 0, stream>>>(partA, b2, ln_scale, ln_bias, nbuf, rstd, h4b, MN_D, D, 4);
  // 4) logits = bf16(h4@Wu + bu)
  clr(); p.A = h4b; p.B = wut; p.M = BL; p.N = V; p.K = D; p.outb = logitsb; p.bias = bu;
  gemm256<8><<<dim3(V / 256, BL / 256, 1), blk5, SMEM, stream>>>(p);
  // 5) fused softmax grad (register-staged)
  k_wsum<<<dim3(1), blk, 0, stream>>>(weights, wsumb, BL);
  k_softgrad<<<dim3(BL), blk, 0, stream>>>(logitsb, labels, weights, wsumb, dlb, V);
  // 6) G4 = dlogits @ Wu^T   [split-K 4]
  clr(); p.A = dlb; p.B = wub; p.M = BL; p.N = D; p.K = V;
  p.part = partA; p.ksplit = 4; p.Kc = V / 4;
  gemm256<6><<<dim3(D / 256, BL / 256, 4), blk5, SMEM, stream>>>(p);
  k_comb<<<dim3((unsigned)(MN_D / 1024)), blk, 0, stream>>>(partA, nullptr, G4, D, MN_D, 4);
  // 7) LN bwd -> g3, g_scale
  k_lnbwd<<<dim3(BL), blk, 0, stream>>>(G4, nbuf, rstd, ln_scale, g3b, gsc, D);
  // 8) g1 = (g3 @ W2^T) * 2*sqrt(H2)
  clr(); p.A = g3b; p.B = w2b; p.M = BL; p.N = F; p.K = D; p.outb = g1b; p.auxb = H2b;
  gemm256<2><<<dim3(F / 256, BL / 256, 1), blk5, SMEM, stream>>>(p);
  // 9) transposes for attention V-operands
  k_tb2b<<<dim3(F / 32, L / 32, Bb), blk, 0, stream>>>(g1b, g1t, L, F);
  k_tb2b<<<dim3(D / 32, L / 32, Bb), blk, 0, stream>>>(g3b, g3t, L, D);
  // 10) S1 = tril(x x^T, -1)   [split-K 2, compact-tri, partials in poolB]
  clr(); p.A = xb; p.B = xb; p.M = L; p.N = L; p.K = D;
  p.sA = (long long)L * D; p.sB = (long long)L * D;
  p.part = partS1; p.ksplit = 2; p.Kc = D / 2; p.Tt = T2t;
  gemm256<7><<<dim3(T2t, 1, Bb * 2), blk5, SMEM, stream>>>(p);
  k_combtri<<<dim3(T2t, Bb), blk, 0, stream>>>(partS1, S1b, T2t, 2, L);
  // 11) x2 = relu(H1 - ss0 * S1@g1)^2   [K-limited, aux = bf16 H1b]
  clr(); p.A = S1b; p.B = g1t; p.M = L; p.N = F; p.K = L;
  p.sA = (long long)L * L; p.sB = (long long)F * L;
  p.outb = x2b; p.sOutB = (long long)L * F; p.auxb = H1b; p.sAuxF = (long long)L * F;
  p.steps = steps;
  gemm256<4><<<dim3(F / 256, L / 256, Bb), blk5, SMEM, stream>>>(p);
  // 12) X3 = x2@W2 + b2   [split-K 4]
  clr(); p.A = x2b; p.B = w2t; p.M = BL; p.N = D; p.K = F;
  p.part = partA; p.ksplit = 4; p.Kc = F / 4;
  gemm256<6><<<dim3(D / 256, BL / 256, 4), blk5, SMEM, stream>>>(p);
  k_comb<<<dim3((unsigned)(MN_D / 1024)), blk, 0, stream>>>(partA, b2, X3, D, MN_D, 4);
  // 13) S2 = tril(x2 H2^T, -1)   [split-K 2, compact-tri]
  clr(); p.A = x2b; p.B = H2b; p.M = L; p.N = L; p.K = F;
  p.sA = (long long)L * F; p.sB = (long long)L * F;
  p.part = partA; p.ksplit = 2; p.Kc = F / 2; p.Tt = T2t;
  gemm256<7><<<dim3(T2t, 1, Bb * 2), blk5, SMEM, stream>>>(p);
  k_combtri<<<dim3(T2t, Bb), blk, 0, stream>>>(partA, S2b, T2t, 2, L);
  // 14) x3 = X3 - ss2 * S2@g3   [K-limited, 128^2 kernel for grid size]
  clr(); p.A = S2b; p.B = g3t; p.M = L; p.N = D; p.K = L;
  p.sA = (long long)L * L; p.sB = (long long)D * L;
  p.outf = x3; p.sOutF = (long long)L * D; p.auxf = X3; p.sAuxF = (long long)L * D; p.steps = steps;
  gemm_bt<5><<<dim3(D / 128, L / 128, Bb), blk, 0, stream>>>(p);
  // 15) exclusive cumsums -> fast_scale / fast_bias
  k_scanpart<<<dim3(D / 256, 16, Bb), blk, 0, stream>>>(gsc, G4, psc, pbi, L, D);
  k_scanapply<<<dim3(D / 256, 16, Bb), blk, 0, stream>>>(gsc, G4, psc, pbi, ln_scale, ln_bias,
                                                         steps, fs, fb, L, D);
  // 16) x4 = LN(x3)*fast_scale + fast_bias
  k_lnfwd2<<<dim3(BL), blk, 0, stream>>>(x3, fs, fb, x4b, D);
  // 17) out = x4@Wu + bu
  clr(); p.A = x4b; p.B = wut; p.M = BL; p.N = V; p.K = D; p.outf = (float*)d_out; p.bias = bu;
  gemm256<0><<<dim3(V / 256, BL / 256, 1), blk5, SMEM, stream>>>(p);
}